// Round 3
// baseline (389.166 us; speedup 1.0000x reference)
//
#include <hip/hip_runtime.h>
#include <hip/hip_bf16.h>

#define DEV static __device__ __forceinline__

DEV float wsum(float v) {
  v += __shfl_xor(v, 1);  v += __shfl_xor(v, 2);  v += __shfl_xor(v, 4);
  v += __shfl_xor(v, 8);  v += __shfl_xor(v, 16); v += __shfl_xor(v, 32);
  return v;
}
DEV float wmaxr(float v) {
  v = fmaxf(v, __shfl_xor(v, 1));  v = fmaxf(v, __shfl_xor(v, 2));
  v = fmaxf(v, __shfl_xor(v, 4));  v = fmaxf(v, __shfl_xor(v, 8));
  v = fmaxf(v, __shfl_xor(v, 16)); v = fmaxf(v, __shfl_xor(v, 32));
  return v;
}

// ---------------------------------------------------------------------------
// Generic f32 GEMM: C[M,N] = alpha * A[M,K] @ B (+ D).  64x64 tile, BK=16,
// 256 threads, 4x4 micro-tile. TRANSB: B is [N,K] row-major (use B[n][k]).
// blockIdx.z batches with element strides bsA/bsB/bsC (for per-head GEMMs).
// ---------------------------------------------------------------------------
template <int TRANSB, int ADDD, int EXPALPHA, int OUTBF16>
__global__ __launch_bounds__(256) void gemm_k(
    const float* __restrict__ A, int lda, long long bsA,
    const float* __restrict__ B, int ldb, long long bsB,
    void* __restrict__ Cv, int ldc, long long bsC,
    const float* __restrict__ D, long long ldd,
    const float* __restrict__ alpha_ptr,
    int M, int N, int K)
{
  A += (size_t)blockIdx.z * bsA;
  B += (size_t)blockIdx.z * bsB;
  const int m0 = blockIdx.y * 64, n0 = blockIdx.x * 64;
  const int tid = threadIdx.x;
  __shared__ __attribute__((aligned(16))) float As[16][68];
  __shared__ __attribute__((aligned(16))) float Bs[16][68];
  float acc[4][4] = {};
  const int ty = tid >> 4, tx = tid & 15;
  const int am = tid >> 2, ak = (tid & 3) * 4;  // A (and TRANSB B) load map
  const int bk = tid >> 4, bn = (tid & 15) * 4; // normal B load map

  for (int k0 = 0; k0 < K; k0 += 16) {
    float4 av = make_float4(0.f, 0.f, 0.f, 0.f);
    float4 bv = make_float4(0.f, 0.f, 0.f, 0.f);
    if (m0 + am < M)
      av = *(const float4*)(A + (size_t)(m0 + am) * lda + (k0 + ak));
    if (TRANSB) {
      if (n0 + am < N)
        bv = *(const float4*)(B + (size_t)(n0 + am) * ldb + (k0 + ak));
    } else {
      if (n0 + bn < N)
        bv = *(const float4*)(B + (size_t)(k0 + bk) * ldb + (n0 + bn));
    }
    __syncthreads();
    As[ak + 0][am] = av.x; As[ak + 1][am] = av.y;
    As[ak + 2][am] = av.z; As[ak + 3][am] = av.w;
    if (TRANSB) {
      Bs[ak + 0][am] = bv.x; Bs[ak + 1][am] = bv.y;
      Bs[ak + 2][am] = bv.z; Bs[ak + 3][am] = bv.w;
    } else {
      *(float4*)&Bs[bk][bn] = bv;
    }
    __syncthreads();
#pragma unroll
    for (int kk = 0; kk < 16; ++kk) {
      const float4 a  = *(const float4*)&As[kk][ty * 4];
      const float4 bq = *(const float4*)&Bs[kk][tx * 4];
      acc[0][0] += a.x * bq.x; acc[0][1] += a.x * bq.y; acc[0][2] += a.x * bq.z; acc[0][3] += a.x * bq.w;
      acc[1][0] += a.y * bq.x; acc[1][1] += a.y * bq.y; acc[1][2] += a.y * bq.z; acc[1][3] += a.y * bq.w;
      acc[2][0] += a.z * bq.x; acc[2][1] += a.z * bq.y; acc[2][2] += a.z * bq.z; acc[2][3] += a.z * bq.w;
      acc[3][0] += a.w * bq.x; acc[3][1] += a.w * bq.y; acc[3][2] += a.w * bq.z; acc[3][3] += a.w * bq.w;
    }
  }

  float alpha = 1.f;
  if (EXPALPHA) alpha = __expf(alpha_ptr[0]);
  const size_t cbase = (size_t)blockIdx.z * (size_t)bsC;
#pragma unroll
  for (int i = 0; i < 4; ++i) {
    const int m = m0 + ty * 4 + i;
    if (m >= M) continue;
#pragma unroll
    for (int j = 0; j < 4; ++j) {
      const int nn = n0 + tx * 4 + j;
      if (nn >= N) continue;
      float v = acc[i][j] * alpha;
      if (ADDD) v += D[(size_t)m * ldd + nn];
      if (OUTBF16)
        ((__hip_bfloat16*)Cv)[cbase + (size_t)m * ldc + nn] = __float2bfloat16(v);
      else
        ((float*)Cv)[cbase + (size_t)m * ldc + nn] = v;
    }
  }
}

// L2-normalize rows of x[rows][512] in place. One block (256 thr) per row.
__global__ __launch_bounds__(256) void rownorm_kernel(float* __restrict__ x)
{
  const int r = blockIdx.x, tid = threadIdx.x;
  float* row = x + (size_t)r * 512;
  float2 v = *(float2*)(row + tid * 2);
  float ss = v.x * v.x + v.y * v.y;
  ss = wsum(ss);
  __shared__ float s4[4];
  const int w = tid >> 6, lane = tid & 63;
  if (lane == 0) s4[w] = ss;
  __syncthreads();
  const float sc = rsqrtf(s4[0] + s4[1] + s4[2] + s4[3]);
  v.x *= sc; v.y *= sc;
  *(float2*)(row + tid * 2) = v;
}

// hl[n] = LayerNorm(cls_tok[n][71]) with gamma/beta. One wave per class.
__global__ __launch_bounds__(64) void lnlast_kernel(
    const float* __restrict__ cls, const float* __restrict__ g,
    const float* __restrict__ b, float* __restrict__ hl)
{
  const int n = blockIdx.x, lane = threadIdx.x;
  const float* src = cls + ((size_t)n * 72 + 71) * 512;
  float x[8];
#pragma unroll
  for (int i = 0; i < 8; ++i) x[i] = src[lane + 64 * i];
  float s = 0.f, ss = 0.f;
#pragma unroll
  for (int i = 0; i < 8; ++i) { s += x[i]; ss += x[i] * x[i]; }
  s = wsum(s); ss = wsum(ss);
  const float mean = s * (1.f / 512.f);
  const float rstd = rsqrtf(ss * (1.f / 512.f) - mean * mean + 1e-5f);
  float* dst = hl + (size_t)n * 512;
#pragma unroll
  for (int i = 0; i < 8; ++i) {
    const int j = lane + 64 * i;
    dst[j] = (x[i] - mean) * rstd * g[j] + b[j];
  }
}

// Pass 1: per class, LN each of 77 rows, dot with 8 head-vectors w~, per-head
// softmax over 77 keys, head-average of first P=5, softmax -> attr[n][0..4].
__global__ __launch_bounds__(256) void pass1_kernel(
    const float* __restrict__ ctx, const float* __restrict__ cls,
    const float* __restrict__ g, const float* __restrict__ b,
    const float* __restrict__ wt, float* __restrict__ attr)
{
  const int n = blockIdx.x, tid = threadIdx.x;
  const int w = tid >> 6, lane = tid & 63;
  __shared__ __attribute__((aligned(16))) float wt_s[8][512];
  __shared__ __attribute__((aligned(16))) float g_s[512], b_s[512];
  __shared__ float sc_s[8][80];
  __shared__ float A_s[8][5];
  {
    const float4* src4 = (const float4*)(wt + (size_t)n * 4096);
    float4* dst4 = (float4*)&wt_s[0][0];
    for (int i = tid; i < 1024; i += 256) dst4[i] = src4[i];
    if (tid < 128) ((float4*)g_s)[tid] = ((const float4*)g)[tid];
    else ((float4*)b_s)[tid - 128] = ((const float4*)b)[tid - 128];
  }
  __syncthreads();

  for (int k = w; k < 77; k += 4) {
    const float* src = (k < 5) ? ctx + ((size_t)n * 5 + k) * 512
                               : cls + ((size_t)n * 72 + (k - 5)) * 512;
    float x[8];
#pragma unroll
    for (int i = 0; i < 8; ++i) x[i] = src[lane + 64 * i];
    float s = 0.f, ss = 0.f;
#pragma unroll
    for (int i = 0; i < 8; ++i) { s += x[i]; ss += x[i] * x[i]; }
    s = wsum(s); ss = wsum(ss);
    const float mean = s * (1.f / 512.f);
    const float rstd = rsqrtf(ss * (1.f / 512.f) - mean * mean + 1e-5f);
    float h[8];
#pragma unroll
    for (int i = 0; i < 8; ++i) {
      const int j = lane + 64 * i;
      h[i] = (x[i] - mean) * rstd * g_s[j] + b_s[j];
    }
    float sc[8] = {0.f, 0.f, 0.f, 0.f, 0.f, 0.f, 0.f, 0.f};
#pragma unroll
    for (int hh = 0; hh < 8; ++hh)
#pragma unroll
      for (int i = 0; i < 8; ++i) sc[hh] += h[i] * wt_s[hh][lane + 64 * i];
#pragma unroll
    for (int hh = 0; hh < 8; ++hh) sc[hh] = wsum(sc[hh]);
    if (lane == 0) {
#pragma unroll
      for (int hh = 0; hh < 8; ++hh) sc_s[hh][k] = sc[hh] * 0.125f;
    }
  }
  __syncthreads();

  for (int hh = w; hh < 8; hh += 4) {
    const float v0 = sc_s[hh][lane];
    const float v1 = (lane + 64 < 77) ? sc_s[hh][lane + 64] : -1e30f;
    const float mx = wmaxr(fmaxf(v0, v1));
    const float e0 = __expf(v0 - mx);
    const float e1 = (lane + 64 < 77) ? __expf(v1 - mx) : 0.f;
    const float S = wsum(e0 + e1);
    if (lane < 5) A_s[hh][lane] = e0 / S;
  }
  __syncthreads();

  if (tid == 0) {
    float m[5], mx = -1e30f;
#pragma unroll
    for (int p = 0; p < 5; ++p) {
      float acc = 0.f;
      for (int hh = 0; hh < 8; ++hh) acc += A_s[hh][p];
      m[p] = acc * 0.125f;
      mx = fmaxf(mx, m[p]);
    }
    float e[5], S = 0.f;
#pragma unroll
    for (int p = 0; p < 5; ++p) { e[p] = __expf(m[p] - mx); S += e[p]; }
#pragma unroll
    for (int p = 0; p < 5; ++p) attr[(size_t)n * 8 + p] = e[p] / S;
  }
}

// Pass 2: per class, scale ctx rows by attr, LN, scores vs w~, ONLINE softmax
// accumulating u[h] = sum_k A2[h][k] * h2_k  (flash-style, per wave), then
// deterministic cross-wave combine. Writes u_out[n][8][512].
// NOTE: u_out may alias wt (in-place per class) — this kernel reads ONLY its
// own wt[n] slice, fully, into LDS before its single final write to u_out[n].
__global__ __launch_bounds__(256) void pass2_kernel(
    const float* __restrict__ ctx, const float* __restrict__ cls,
    const float* __restrict__ g, const float* __restrict__ b,
    const float* __restrict__ wt, const float* __restrict__ attr,
    float* __restrict__ u_out)
{
  const int n = blockIdx.x, tid = threadIdx.x;
  const int w = tid >> 6, lane = tid & 63;
  __shared__ __attribute__((aligned(16))) float wt_s[8][512];
  __shared__ __attribute__((aligned(16))) float g_s[512], b_s[512];
  __shared__ __attribute__((aligned(16))) float u_s[8][512];
  __shared__ float wstat[4][8][2];
  __shared__ float attr_s[5];
  __shared__ float Ms[8], Lr[8];
  {
    const float4* src4 = (const float4*)(wt + (size_t)n * 4096);
    float4* dst4 = (float4*)&wt_s[0][0];
    for (int i = tid; i < 1024; i += 256) dst4[i] = src4[i];
    if (tid < 128) ((float4*)g_s)[tid] = ((const float4*)g)[tid];
    else ((float4*)b_s)[tid - 128] = ((const float4*)b)[tid - 128];
    for (int i = tid; i < 4096; i += 256) (&u_s[0][0])[i] = 0.f;
    if (tid < 5) attr_s[tid] = attr[(size_t)n * 8 + tid];
  }
  __syncthreads();

  float u[8][8];
#pragma unroll
  for (int hh = 0; hh < 8; ++hh)
#pragma unroll
    for (int i = 0; i < 8; ++i) u[hh][i] = 0.f;
  float mrun[8], lrun[8];
#pragma unroll
  for (int hh = 0; hh < 8; ++hh) { mrun[hh] = -1e30f; lrun[hh] = 0.f; }

  for (int k = w; k < 77; k += 4) {
    const float* src = (k < 5) ? ctx + ((size_t)n * 5 + k) * 512
                               : cls + ((size_t)n * 72 + (k - 5)) * 512;
    const float c = (k < 5) ? attr_s[k] : 1.f;
    float x[8];
#pragma unroll
    for (int i = 0; i < 8; ++i) x[i] = src[lane + 64 * i] * c;
    float s = 0.f, ss = 0.f;
#pragma unroll
    for (int i = 0; i < 8; ++i) { s += x[i]; ss += x[i] * x[i]; }
    s = wsum(s); ss = wsum(ss);
    const float mean = s * (1.f / 512.f);
    const float rstd = rsqrtf(ss * (1.f / 512.f) - mean * mean + 1e-5f);
    float h[8];
#pragma unroll
    for (int i = 0; i < 8; ++i) {
      const int j = lane + 64 * i;
      h[i] = (x[i] - mean) * rstd * g_s[j] + b_s[j];
    }
    float sc[8] = {0.f, 0.f, 0.f, 0.f, 0.f, 0.f, 0.f, 0.f};
#pragma unroll
    for (int hh = 0; hh < 8; ++hh)
#pragma unroll
      for (int i = 0; i < 8; ++i) sc[hh] += h[i] * wt_s[hh][lane + 64 * i];
#pragma unroll
    for (int hh = 0; hh < 8; ++hh) sc[hh] = wsum(sc[hh]);
#pragma unroll
    for (int hh = 0; hh < 8; ++hh) {
      const float sv = sc[hh] * 0.125f;
      const float nm = fmaxf(mrun[hh], sv);
      const float fac = __expf(mrun[hh] - nm);
      const float es = __expf(sv - nm);
      lrun[hh] = lrun[hh] * fac + es;
      mrun[hh] = nm;
#pragma unroll
      for (int i = 0; i < 8; ++i) u[hh][i] = u[hh][i] * fac + es * h[i];
    }
  }

  if (lane == 0) {
#pragma unroll
    for (int hh = 0; hh < 8; ++hh) {
      wstat[w][hh][0] = mrun[hh];
      wstat[w][hh][1] = lrun[hh];
    }
  }
  __syncthreads();
  if (tid < 8) {
    const float M = fmaxf(fmaxf(wstat[0][tid][0], wstat[1][tid][0]),
                          fmaxf(wstat[2][tid][0], wstat[3][tid][0]));
    float L = 0.f;
    for (int wv = 0; wv < 4; ++wv)
      L += wstat[wv][tid][1] * __expf(wstat[wv][tid][0] - M);
    Ms[tid] = M; Lr[tid] = 1.f / L;
  }
  __syncthreads();
  // deterministic cross-wave combine (no FP atomics)
  for (int wv = 0; wv < 4; ++wv) {
    if (w == wv) {
#pragma unroll
      for (int hh = 0; hh < 8; ++hh) {
        const float f = __expf(mrun[hh] - Ms[hh]);
#pragma unroll
        for (int i = 0; i < 8; ++i) u_s[hh][lane + 64 * i] += u[hh][i] * f;
      }
    }
    __syncthreads();
  }
  float* dst = u_out + (size_t)n * 4096;
  for (int i = tid; i < 4096; i += 256) dst[i] = (&u_s[0][0])[i] * Lr[i >> 9];
}

// ---------------------------------------------------------------------------
extern "C" void kernel_launch(void* const* d_in, const int* in_sizes, int n_in,
                              void* d_out, int out_size, void* d_ws, size_t ws_size,
                              hipStream_t stream)
{
  const float* images = (const float*)d_in[0];   // [256,768]
  const float* W_img  = (const float*)d_in[1];   // [768,512]
  const float* ctx    = (const float*)d_in[2];   // [1000,5,512]
  const float* cls    = (const float*)d_in[3];   // [1000,72,512]
  const float* ln_g   = (const float*)d_in[4];   // [512]
  const float* ln_b   = (const float*)d_in[5];   // [512]
  const float* Wq     = (const float*)d_in[6];   // [512,512]
  const float* Wk     = (const float*)d_in[7];
  const float* Wv     = (const float*)d_in[8];
  const float* Wo     = (const float*)d_in[9];
  const float* tproj  = (const float*)d_in[10];
  const float* lscale = (const float*)d_in[11];  // [1]

  // Compact workspace with stream-order-safe overlays (~21.0 MB peak):
  //   wtu : wt (pass1/pass2 input) -> u (pass2 writes its own n-slice
  //         in place) -> first 512000 floats reused as txt after O-GEMM.
  //   hlO : hl (dead after q-GEMM) -> O
  //   qo2 : q  (dead after wt-GEMM) -> out2
  float* ws   = (float*)d_ws;
  float* wtu  = ws;                 // 4,096,000 f
  float* img  = wtu + 4096000;      //   131,072 f
  float* hlO  = img + 131072;       //   512,000 f
  float* qo2  = hlO + 512000;       //   512,000 f
  float* attr = qo2 + 512000;       //     8,000 f
  float* txt  = wtu;                // alias: wtu dead after O-GEMM
  (void)in_sizes; (void)n_in; (void)out_size; (void)ws_size;

  // 1) image embedding + L2 norm
  gemm_k<0,0,0,0><<<dim3(8,4,1),256,0,stream>>>(images,768,0, W_img,512,0,
      img,512,0, nullptr,0, nullptr, 256,512,768);
  rownorm_kernel<<<256,256,0,stream>>>(img);

  // 2) q = LN(last row) @ Wq  (shared by both transformer passes)
  lnlast_kernel<<<1000,64,0,stream>>>(cls, ln_g, ln_b, hlO);
  gemm_k<0,0,0,0><<<dim3(8,16,1),256,0,stream>>>(hlO,512,0, Wq,512,0,
      qo2,512,0, nullptr,0, nullptr, 1000,512,512);

  // 3) w~[n][h][j] = sum_d Wk[j][h*64+d] * q[n][h*64+d]  (8 batched GEMMs)
  gemm_k<1,0,0,0><<<dim3(8,16,8),256,0,stream>>>(qo2,512,64, Wk,512,64,
      wtu,4096,512, nullptr,0, nullptr, 1000,512,64);

  // 4) pass-1 row sweep -> attr[n][5]
  pass1_kernel<<<1000,256,0,stream>>>(ctx, cls, ln_g, ln_b, wtu, attr);

  // 5) pass-2 row sweep (online softmax) -> u[n][8][512], in place over wt
  pass2_kernel<<<1000,256,0,stream>>>(ctx, cls, ln_g, ln_b, wtu, attr, wtu);

  // 6) O[n][h*64+c] = u[n][h] @ Wv[:,h*64+c]   (hl region reused as O)
  gemm_k<0,0,0,0><<<dim3(1,16,8),256,0,stream>>>(wtu,4096,512, Wv,512,64,
      hlO,512,64, nullptr,0, nullptr, 1000,64,512);

  // 7) out2 = cls_last + O @ Wo ; txt = out2 @ text_proj ; L2 norm
  gemm_k<0,1,0,0><<<dim3(8,16,1),256,0,stream>>>(hlO,512,0, Wo,512,0,
      qo2,512,0, cls + 71*512, 72*512, nullptr, 1000,512,512);
  gemm_k<0,0,0,0><<<dim3(8,16,1),256,0,stream>>>(qo2,512,0, tproj,512,0,
      txt,512,0, nullptr,0, nullptr, 1000,512,512);
  rownorm_kernel<<<1000,256,0,stream>>>(txt);

  // 8) logits = exp(ls) * img @ txt^T   (f32 output — reference output dtype
  //    is float32; writing bf16 here was the round-1/2 failure)
  gemm_k<1,0,1,0><<<dim3(16,4,1),256,0,stream>>>(img,512,0, txt,512,0,
      d_out,1000,0, nullptr,0, lscale, 256,1000,512);
}

// Round 4
// 299.749 us; speedup vs baseline: 1.2983x; 1.2983x over previous
//
#include <hip/hip_runtime.h>
#include <hip/hip_bf16.h>

#define DEV static __device__ __forceinline__

DEV float wsum(float v) {
  v += __shfl_xor(v, 1);  v += __shfl_xor(v, 2);  v += __shfl_xor(v, 4);
  v += __shfl_xor(v, 8);  v += __shfl_xor(v, 16); v += __shfl_xor(v, 32);
  return v;
}
DEV float wmaxr(float v) {
  v = fmaxf(v, __shfl_xor(v, 1));  v = fmaxf(v, __shfl_xor(v, 2));
  v = fmaxf(v, __shfl_xor(v, 4));  v = fmaxf(v, __shfl_xor(v, 8));
  v = fmaxf(v, __shfl_xor(v, 16)); v = fmaxf(v, __shfl_xor(v, 32));
  return v;
}

// ---------------------------------------------------------------------------
// 64x64-tile f32 GEMM (kept for the wt-GEMM whose grid is already 1024).
// ---------------------------------------------------------------------------
template <int TRANSB>
__global__ __launch_bounds__(256) void gemm_k(
    const float* __restrict__ A, int lda, long long bsA,
    const float* __restrict__ B, int ldb, long long bsB,
    float* __restrict__ C, int ldc, long long bsC,
    int M, int N, int K)
{
  A += (size_t)blockIdx.z * bsA;
  B += (size_t)blockIdx.z * bsB;
  const int m0 = blockIdx.y * 64, n0 = blockIdx.x * 64;
  const int tid = threadIdx.x;
  __shared__ __attribute__((aligned(16))) float As[16][68];
  __shared__ __attribute__((aligned(16))) float Bs[16][68];
  float acc[4][4] = {};
  const int ty = tid >> 4, tx = tid & 15;
  const int am = tid >> 2, ak = (tid & 3) * 4;
  const int bk = tid >> 4, bn = (tid & 15) * 4;

  for (int k0 = 0; k0 < K; k0 += 16) {
    float4 av = make_float4(0.f, 0.f, 0.f, 0.f);
    float4 bv = make_float4(0.f, 0.f, 0.f, 0.f);
    if (m0 + am < M)
      av = *(const float4*)(A + (size_t)(m0 + am) * lda + (k0 + ak));
    if (TRANSB) {
      if (n0 + am < N)
        bv = *(const float4*)(B + (size_t)(n0 + am) * ldb + (k0 + ak));
    } else {
      if (n0 + bn < N)
        bv = *(const float4*)(B + (size_t)(k0 + bk) * ldb + (n0 + bn));
    }
    __syncthreads();
    As[ak + 0][am] = av.x; As[ak + 1][am] = av.y;
    As[ak + 2][am] = av.z; As[ak + 3][am] = av.w;
    if (TRANSB) {
      Bs[ak + 0][am] = bv.x; Bs[ak + 1][am] = bv.y;
      Bs[ak + 2][am] = bv.z; Bs[ak + 3][am] = bv.w;
    } else {
      *(float4*)&Bs[bk][bn] = bv;
    }
    __syncthreads();
#pragma unroll
    for (int kk = 0; kk < 16; ++kk) {
      const float4 a  = *(const float4*)&As[kk][ty * 4];
      const float4 bq = *(const float4*)&Bs[kk][tx * 4];
      acc[0][0] += a.x * bq.x; acc[0][1] += a.x * bq.y; acc[0][2] += a.x * bq.z; acc[0][3] += a.x * bq.w;
      acc[1][0] += a.y * bq.x; acc[1][1] += a.y * bq.y; acc[1][2] += a.y * bq.z; acc[1][3] += a.y * bq.w;
      acc[2][0] += a.z * bq.x; acc[2][1] += a.z * bq.y; acc[2][2] += a.z * bq.z; acc[2][3] += a.z * bq.w;
      acc[3][0] += a.w * bq.x; acc[3][1] += a.w * bq.y; acc[3][2] += a.w * bq.z; acc[3][3] += a.w * bq.w;
    }
  }
  const size_t cbase = (size_t)blockIdx.z * (size_t)bsC;
#pragma unroll
  for (int i = 0; i < 4; ++i) {
    const int m = m0 + ty * 4 + i;
    if (m >= M) continue;
#pragma unroll
    for (int j = 0; j < 4; ++j) {
      const int nn = n0 + tx * 4 + j;
      if (nn < N) C[cbase + (size_t)m * ldc + nn] = acc[i][j];
    }
  }
}

// ---------------------------------------------------------------------------
// 32x64-tile f32 GEMM: doubles grid size for M=1000 GEMMs -> fills 256 CUs.
// micro-tile 2x4. Optional residual-add (ADDD) and exp(alpha) scale.
// ---------------------------------------------------------------------------
template <int TRANSB, int ADDD, int EXPALPHA>
__global__ __launch_bounds__(256) void gemm32_k(
    const float* __restrict__ A, int lda, long long bsA,
    const float* __restrict__ B, int ldb, long long bsB,
    float* __restrict__ C, int ldc, long long bsC,
    const float* __restrict__ D, long long ldd,
    const float* __restrict__ alpha_ptr,
    int M, int N, int K)
{
  A += (size_t)blockIdx.z * bsA;
  B += (size_t)blockIdx.z * bsB;
  const int m0 = blockIdx.y * 32, n0 = blockIdx.x * 64;
  const int tid = threadIdx.x;
  __shared__ __attribute__((aligned(16))) float As[16][36];
  __shared__ __attribute__((aligned(16))) float Bs[16][68];
  float acc[2][4] = {};
  const int ty = tid >> 4, tx = tid & 15;
  const int am = tid >> 3, ak = (tid & 7) * 2;   // A: 32r x 16k, float2
  const int bk = tid >> 4, bn = (tid & 15) * 4;  // B normal: 16k x 64n
  const int bm = tid >> 2, bt = (tid & 3) * 4;   // B transb: 64n x 16k

  for (int k0 = 0; k0 < K; k0 += 16) {
    float2 av = make_float2(0.f, 0.f);
    float4 bv = make_float4(0.f, 0.f, 0.f, 0.f);
    if (m0 + am < M)
      av = *(const float2*)(A + (size_t)(m0 + am) * lda + (k0 + ak));
    if (TRANSB) {
      if (n0 + bm < N)
        bv = *(const float4*)(B + (size_t)(n0 + bm) * ldb + (k0 + bt));
    } else {
      if (n0 + bn < N)
        bv = *(const float4*)(B + (size_t)(k0 + bk) * ldb + (n0 + bn));
    }
    __syncthreads();
    As[ak][am] = av.x; As[ak + 1][am] = av.y;
    if (TRANSB) {
      Bs[bt + 0][bm] = bv.x; Bs[bt + 1][bm] = bv.y;
      Bs[bt + 2][bm] = bv.z; Bs[bt + 3][bm] = bv.w;
    } else {
      *(float4*)&Bs[bk][bn] = bv;
    }
    __syncthreads();
#pragma unroll
    for (int kk = 0; kk < 16; ++kk) {
      const float2 a  = *(const float2*)&As[kk][ty * 2];
      const float4 bq = *(const float4*)&Bs[kk][tx * 4];
      acc[0][0] += a.x * bq.x; acc[0][1] += a.x * bq.y; acc[0][2] += a.x * bq.z; acc[0][3] += a.x * bq.w;
      acc[1][0] += a.y * bq.x; acc[1][1] += a.y * bq.y; acc[1][2] += a.y * bq.z; acc[1][3] += a.y * bq.w;
    }
  }

  float alpha = 1.f;
  if (EXPALPHA) alpha = __expf(alpha_ptr[0]);
  const size_t cbase = (size_t)blockIdx.z * (size_t)bsC;
#pragma unroll
  for (int i = 0; i < 2; ++i) {
    const int m = m0 + ty * 2 + i;
    if (m >= M) continue;
#pragma unroll
    for (int j = 0; j < 4; ++j) {
      const int nn = n0 + tx * 4 + j;
      if (nn >= N) continue;
      float v = acc[i][j] * alpha;
      if (ADDD) v += D[(size_t)m * ldd + nn];
      C[cbase + (size_t)m * ldc + nn] = v;
    }
  }
}

// L2-normalize rows of x[rows][512] in place.
__global__ __launch_bounds__(256) void rownorm_kernel(float* __restrict__ x)
{
  const int r = blockIdx.x, tid = threadIdx.x;
  float* row = x + (size_t)r * 512;
  float2 v = *(float2*)(row + tid * 2);
  float ss = v.x * v.x + v.y * v.y;
  ss = wsum(ss);
  __shared__ float s4[4];
  const int w = tid >> 6, lane = tid & 63;
  if (lane == 0) s4[w] = ss;
  __syncthreads();
  const float sc = rsqrtf(s4[0] + s4[1] + s4[2] + s4[3]);
  v.x *= sc; v.y *= sc;
  *(float2*)(row + tid * 2) = v;
}

// hl[n] = LayerNorm(cls_tok[n][71]).
__global__ __launch_bounds__(64) void lnlast_kernel(
    const float* __restrict__ cls, const float* __restrict__ g,
    const float* __restrict__ b, float* __restrict__ hl)
{
  const int n = blockIdx.x, lane = threadIdx.x;
  const float* src = cls + ((size_t)n * 72 + 71) * 512;
  float x[8];
#pragma unroll
  for (int i = 0; i < 8; ++i) x[i] = src[lane + 64 * i];
  float s = 0.f, ss = 0.f;
#pragma unroll
  for (int i = 0; i < 8; ++i) { s += x[i]; ss += x[i] * x[i]; }
  s = wsum(s); ss = wsum(ss);
  const float mean = s * (1.f / 512.f);
  const float rstd = rsqrtf(ss * (1.f / 512.f) - mean * mean + 1e-5f);
  float* dst = hl + (size_t)n * 512;
#pragma unroll
  for (int i = 0; i < 8; ++i) {
    const int j = lane + 64 * i;
    dst[j] = (x[i] - mean) * rstd * g[j] + b[j];
  }
}

// ---------------------------------------------------------------------------
// FUSED pass1+pass2. Key identity: cls rows (keys 5..76) are IDENTICAL in
// both transformer passes (only ctx rows get scaled by attr). So one sweep
// over the 72 cls rows accumulates BOTH the pass-1 scores AND the pass-2
// per-head online-softmax state (m, l, V = sum e^s * h). Pass 2 then only
// needs the 5 ctx rows (kept in LDS) rescaled + an analytic combine.
// Reads wt[n] fully into LDS before writing u_out[n] (may alias).
// Lane owns elements j = lane*2 + 128*i + t (float2 pairs, conflict-free).
// ---------------------------------------------------------------------------
__global__ __launch_bounds__(256) void fused_sweep_kernel(
    const float* __restrict__ ctx, const float* __restrict__ cls,
    const float* __restrict__ g, const float* __restrict__ b,
    const float* __restrict__ wt, float* __restrict__ u_out)
{
  const int n = blockIdx.x, tid = threadIdx.x;
  const int w = tid >> 6, lane = tid & 63;
  __shared__ __attribute__((aligned(16))) float wt_s[8][512];
  __shared__ __attribute__((aligned(16))) float g_s[512], b_s[512];
  __shared__ __attribute__((aligned(16))) float hctx[5][512];  // ctx -> h2
  __shared__ __attribute__((aligned(16))) float V_s[8][512];
  __shared__ float sc_s[8][80];
  __shared__ float sc2_s[8][5];
  __shared__ float A_s[8][5];
  __shared__ float wstat[4][8][2];
  __shared__ float attr_s[5];
  __shared__ float M72[8], L72[8];
  __shared__ float cfV[8], cf_s[8][5];

  {
    const float4* wsrc = (const float4*)(wt + (size_t)n * 4096);
    float4* wdst = (float4*)&wt_s[0][0];
    for (int i = tid; i < 1024; i += 256) wdst[i] = wsrc[i];
    const float4* csrc = (const float4*)(ctx + (size_t)n * 2560);
    float4* cdst = (float4*)&hctx[0][0];
    for (int i = tid; i < 640; i += 256) cdst[i] = csrc[i];
    float4* vdst = (float4*)&V_s[0][0];
    for (int i = tid; i < 1024; i += 256) vdst[i] = make_float4(0.f, 0.f, 0.f, 0.f);
    if (tid < 128) ((float4*)g_s)[tid] = ((const float4*)g)[tid];
    else if (tid < 256) ((float4*)b_s)[tid - 128] = ((const float4*)b)[tid - 128];
  }
  __syncthreads();

  // ---- stage A: 5 unscaled ctx rows -> pass-1 scores sc_s[.][0..4]
  for (int k = w; k < 5; k += 4) {
    float2 x2[4];
#pragma unroll
    for (int i = 0; i < 4; ++i)
      x2[i] = *(const float2*)&hctx[k][lane * 2 + 128 * i];
    float s = 0.f, ss = 0.f;
#pragma unroll
    for (int i = 0; i < 4; ++i) {
      s += x2[i].x + x2[i].y; ss += x2[i].x * x2[i].x + x2[i].y * x2[i].y;
    }
    s = wsum(s); ss = wsum(ss);
    const float mean = s * (1.f / 512.f);
    const float rstd = rsqrtf(ss * (1.f / 512.f) - mean * mean + 1e-5f);
    float h[8];
#pragma unroll
    for (int i = 0; i < 4; ++i) {
      const float2 gg = *(const float2*)&g_s[lane * 2 + 128 * i];
      const float2 bb = *(const float2*)&b_s[lane * 2 + 128 * i];
      h[2 * i]     = (x2[i].x - mean) * rstd * gg.x + bb.x;
      h[2 * i + 1] = (x2[i].y - mean) * rstd * gg.y + bb.y;
    }
    float sc[8] = {};
#pragma unroll
    for (int hh = 0; hh < 8; ++hh)
#pragma unroll
      for (int i = 0; i < 4; ++i) {
        const float2 ww = *(const float2*)&wt_s[hh][lane * 2 + 128 * i];
        sc[hh] += h[2 * i] * ww.x + h[2 * i + 1] * ww.y;
      }
#pragma unroll
    for (int hh = 0; hh < 8; ++hh) sc[hh] = wsum(sc[hh]);
    if (lane == 0)
#pragma unroll
      for (int hh = 0; hh < 8; ++hh) sc_s[hh][k] = sc[hh] * 0.125f;
  }

  // ---- stage B: 72 cls rows, scores + per-head online softmax accumulate
  float V[8][8];
#pragma unroll
  for (int hh = 0; hh < 8; ++hh)
#pragma unroll
    for (int i = 0; i < 8; ++i) V[hh][i] = 0.f;
  float mrun[8], lrun[8];
#pragma unroll
  for (int hh = 0; hh < 8; ++hh) { mrun[hh] = -1e30f; lrun[hh] = 0.f; }

  const float* base = cls + (size_t)n * 72 * 512;
  float2 xc[4];
  {
    const float* src = base + (size_t)w * 512;
#pragma unroll
    for (int i = 0; i < 4; ++i)
      xc[i] = *(const float2*)(src + lane * 2 + 128 * i);
  }
  for (int k = 5 + w; k < 77; k += 4) {
    float2 xn[4];
    const bool more = (k + 4 < 77);
    if (more) {
      const float* srcn = base + (size_t)(k - 1) * 512;  // row (k+4)-5
#pragma unroll
      for (int i = 0; i < 4; ++i)
        xn[i] = *(const float2*)(srcn + lane * 2 + 128 * i);
    }
    float s = 0.f, ss = 0.f;
#pragma unroll
    for (int i = 0; i < 4; ++i) {
      s += xc[i].x + xc[i].y; ss += xc[i].x * xc[i].x + xc[i].y * xc[i].y;
    }
    s = wsum(s); ss = wsum(ss);
    const float mean = s * (1.f / 512.f);
    const float rstd = rsqrtf(ss * (1.f / 512.f) - mean * mean + 1e-5f);
    float h[8];
#pragma unroll
    for (int i = 0; i < 4; ++i) {
      const float2 gg = *(const float2*)&g_s[lane * 2 + 128 * i];
      const float2 bb = *(const float2*)&b_s[lane * 2 + 128 * i];
      h[2 * i]     = (xc[i].x - mean) * rstd * gg.x + bb.x;
      h[2 * i + 1] = (xc[i].y - mean) * rstd * gg.y + bb.y;
    }
    float sc[8] = {};
#pragma unroll
    for (int hh = 0; hh < 8; ++hh)
#pragma unroll
      for (int i = 0; i < 4; ++i) {
        const float2 ww = *(const float2*)&wt_s[hh][lane * 2 + 128 * i];
        sc[hh] += h[2 * i] * ww.x + h[2 * i + 1] * ww.y;
      }
#pragma unroll
    for (int hh = 0; hh < 8; ++hh) sc[hh] = wsum(sc[hh]);
    if (lane == 0)
#pragma unroll
      for (int hh = 0; hh < 8; ++hh) sc_s[hh][k] = sc[hh] * 0.125f;
#pragma unroll
    for (int hh = 0; hh < 8; ++hh) {
      const float sv = sc[hh] * 0.125f;
      const float nm = fmaxf(mrun[hh], sv);
      const float fac = __expf(mrun[hh] - nm);
      const float es = __expf(sv - nm);
      lrun[hh] = lrun[hh] * fac + es;
      mrun[hh] = nm;
#pragma unroll
      for (int i = 0; i < 8; ++i) V[hh][i] = V[hh][i] * fac + es * h[i];
    }
    if (more)
#pragma unroll
      for (int i = 0; i < 4; ++i) xc[i] = xn[i];
  }

  if (lane == 0)
#pragma unroll
    for (int hh = 0; hh < 8; ++hh) {
      wstat[w][hh][0] = mrun[hh]; wstat[w][hh][1] = lrun[hh];
    }
  __syncthreads();
  if (tid < 8) {
    const float M = fmaxf(fmaxf(wstat[0][tid][0], wstat[1][tid][0]),
                          fmaxf(wstat[2][tid][0], wstat[3][tid][0]));
    float L = 0.f;
    for (int wv = 0; wv < 4; ++wv)
      L += wstat[wv][tid][1] * __expf(wstat[wv][tid][0] - M);
    M72[tid] = M; L72[tid] = L;
  }
  __syncthreads();
  for (int wv = 0; wv < 4; ++wv) {
    if (w == wv) {
#pragma unroll
      for (int hh = 0; hh < 8; ++hh) {
        const float f = __expf(mrun[hh] - M72[hh]);
#pragma unroll
        for (int i = 0; i < 4; ++i) {
          float2* p = (float2*)&V_s[hh][lane * 2 + 128 * i];
          float2 v = *p;
          v.x += V[hh][2 * i] * f; v.y += V[hh][2 * i + 1] * f;
          *p = v;
        }
      }
    }
    __syncthreads();
  }

  // ---- pass-1 softmax over 77 keys -> head-mean of first 5 -> attr
  for (int hh = w; hh < 8; hh += 4) {
    const float v0 = sc_s[hh][lane];
    const float v1 = (lane + 64 < 77) ? sc_s[hh][lane + 64] : -1e30f;
    const float mx = wmaxr(fmaxf(v0, v1));
    const float e0 = __expf(v0 - mx);
    const float e1 = (lane + 64 < 77) ? __expf(v1 - mx) : 0.f;
    const float S = wsum(e0 + e1);
    if (lane < 5) A_s[hh][lane] = e0 / S;
  }
  __syncthreads();
  if (tid == 0) {
    float m[5], mx = -1e30f;
#pragma unroll
    for (int p = 0; p < 5; ++p) {
      float acc = 0.f;
      for (int hh = 0; hh < 8; ++hh) acc += A_s[hh][p];
      m[p] = acc * 0.125f;
      mx = fmaxf(mx, m[p]);
    }
    float e[5], S = 0.f;
#pragma unroll
    for (int p = 0; p < 5; ++p) { e[p] = __expf(m[p] - mx); S += e[p]; }
#pragma unroll
    for (int p = 0; p < 5; ++p) attr_s[p] = e[p] / S;
  }
  __syncthreads();

  // ---- stage C: scaled ctx rows -> h2 (in place in hctx) + scores sc2
  for (int k = w; k < 5; k += 4) {
    const float c = attr_s[k];
    float2 x2[4];
#pragma unroll
    for (int i = 0; i < 4; ++i) {
      x2[i] = *(const float2*)&hctx[k][lane * 2 + 128 * i];
      x2[i].x *= c; x2[i].y *= c;
    }
    float s = 0.f, ss = 0.f;
#pragma unroll
    for (int i = 0; i < 4; ++i) {
      s += x2[i].x + x2[i].y; ss += x2[i].x * x2[i].x + x2[i].y * x2[i].y;
    }
    s = wsum(s); ss = wsum(ss);
    const float mean = s * (1.f / 512.f);
    const float rstd = rsqrtf(ss * (1.f / 512.f) - mean * mean + 1e-5f);
    float h[8];
#pragma unroll
    for (int i = 0; i < 4; ++i) {
      const float2 gg = *(const float2*)&g_s[lane * 2 + 128 * i];
      const float2 bb = *(const float2*)&b_s[lane * 2 + 128 * i];
      h[2 * i]     = (x2[i].x - mean) * rstd * gg.x + bb.x;
      h[2 * i + 1] = (x2[i].y - mean) * rstd * gg.y + bb.y;
      float2 hv = make_float2(h[2 * i], h[2 * i + 1]);
      *(float2*)&hctx[k][lane * 2 + 128 * i] = hv;
    }
    float sc[8] = {};
#pragma unroll
    for (int hh = 0; hh < 8; ++hh)
#pragma unroll
      for (int i = 0; i < 4; ++i) {
        const float2 ww = *(const float2*)&wt_s[hh][lane * 2 + 128 * i];
        sc[hh] += h[2 * i] * ww.x + h[2 * i + 1] * ww.y;
      }
#pragma unroll
    for (int hh = 0; hh < 8; ++hh) sc[hh] = wsum(sc[hh]);
    if (lane == 0)
#pragma unroll
      for (int hh = 0; hh < 8; ++hh) sc2_s[hh][k] = sc[hh] * 0.125f;
  }
  __syncthreads();

  // ---- final combine coefficients per head
  if (tid < 8) {
    float Mf = M72[tid];
#pragma unroll
    for (int k = 0; k < 5; ++k) Mf = fmaxf(Mf, sc2_s[tid][k]);
    float e[5], den = L72[tid] * __expf(M72[tid] - Mf);
#pragma unroll
    for (int k = 0; k < 5; ++k) { e[k] = __expf(sc2_s[tid][k] - Mf); den += e[k]; }
    const float r = 1.f / den;
    cfV[tid] = __expf(M72[tid] - Mf) * r;
#pragma unroll
    for (int k = 0; k < 5; ++k) cf_s[tid][k] = e[k] * r;
  }
  __syncthreads();

  // ---- u[n][h][j] = cfV*V + sum_k cf*h2  -> global (coalesced)
  float* dst = u_out + (size_t)n * 4096;
  for (int idx = tid; idx < 4096; idx += 256) {
    const int hh = idx >> 9, j = idx & 511;
    float v = cfV[hh] * V_s[hh][j];
#pragma unroll
    for (int k = 0; k < 5; ++k) v += cf_s[hh][k] * hctx[k][j];
    dst[idx] = v;
  }
}

// ---------------------------------------------------------------------------
extern "C" void kernel_launch(void* const* d_in, const int* in_sizes, int n_in,
                              void* d_out, int out_size, void* d_ws, size_t ws_size,
                              hipStream_t stream)
{
  const float* images = (const float*)d_in[0];
  const float* W_img  = (const float*)d_in[1];
  const float* ctx    = (const float*)d_in[2];
  const float* cls    = (const float*)d_in[3];
  const float* ln_g   = (const float*)d_in[4];
  const float* ln_b   = (const float*)d_in[5];
  const float* Wq     = (const float*)d_in[6];
  const float* Wk     = (const float*)d_in[7];
  const float* Wv     = (const float*)d_in[8];
  const float* Wo     = (const float*)d_in[9];
  const float* tproj  = (const float*)d_in[10];
  const float* lscale = (const float*)d_in[11];

  float* ws   = (float*)d_ws;
  float* wtu  = ws;                 // wt -> u (in place) -> txt overlay
  float* img  = wtu + 4096000;
  float* hlO  = img + 131072;       // hl -> O
  float* qo2  = hlO + 512000;       // q  -> out2
  float* txt  = wtu;
  (void)in_sizes; (void)n_in; (void)out_size; (void)ws_size;

  // 1) image embedding + L2 norm
  gemm32_k<0,0,0><<<dim3(8,8,1),256,0,stream>>>(images,768,0, W_img,512,0,
      img,512,0, nullptr,0, nullptr, 256,512,768);
  rownorm_kernel<<<256,256,0,stream>>>(img);

  // 2) q = LN(last row) @ Wq
  lnlast_kernel<<<1000,64,0,stream>>>(cls, ln_g, ln_b, hlO);
  gemm32_k<0,0,0><<<dim3(8,32,1),256,0,stream>>>(hlO,512,0, Wq,512,0,
      qo2,512,0, nullptr,0, nullptr, 1000,512,512);

  // 3) wt[n][h][j] = sum_d Wk[j][h*64+d] * q[n][h*64+d]
  gemm_k<1><<<dim3(8,16,8),256,0,stream>>>(qo2,512,64, Wk,512,64,
      wtu,4096,512, 1000,512,64);

  // 4+5) fused pass1+pass2 sweep -> u[n][8][512] (in place over wt)
  fused_sweep_kernel<<<1000,256,0,stream>>>(ctx, cls, ln_g, ln_b, wtu, wtu);

  // 6) O[n][h*64+c] = u[n][h] @ Wv[:,h*64+c]
  gemm32_k<0,0,0><<<dim3(1,32,8),256,0,stream>>>(wtu,4096,512, Wv,512,64,
      hlO,512,64, nullptr,0, nullptr, 1000,64,512);

  // 7) out2 = cls_last + O @ Wo ; txt = out2 @ text_proj ; L2 norm
  gemm32_k<0,1,0><<<dim3(8,32,1),256,0,stream>>>(hlO,512,0, Wo,512,0,
      qo2,512,0, cls + 71*512, 72*512, nullptr, 1000,512,512);
  gemm32_k<0,0,0><<<dim3(8,32,1),256,0,stream>>>(qo2,512,0, tproj,512,0,
      txt,512,0, nullptr,0, nullptr, 1000,512,512);
  rownorm_kernel<<<1000,256,0,stream>>>(txt);

  // 8) logits = exp(ls) * img @ txt^T   (f32 out)
  gemm32_k<1,0,1><<<dim3(16,8,1),256,0,stream>>>(img,512,0, txt,512,0,
      (float*)d_out,1000,0, nullptr,0, lscale, 256,1000,512);
}

// Round 5
// 287.828 us; speedup vs baseline: 1.3521x; 1.0414x over previous
//
#include <hip/hip_runtime.h>
#include <hip/hip_bf16.h>

#define DEV static __device__ __forceinline__

DEV float wsum(float v) {
  v += __shfl_xor(v, 1);  v += __shfl_xor(v, 2);  v += __shfl_xor(v, 4);
  v += __shfl_xor(v, 8);  v += __shfl_xor(v, 16); v += __shfl_xor(v, 32);
  return v;
}
DEV float wmaxr(float v) {
  v = fmaxf(v, __shfl_xor(v, 1));  v = fmaxf(v, __shfl_xor(v, 2));
  v = fmaxf(v, __shfl_xor(v, 4));  v = fmaxf(v, __shfl_xor(v, 8));
  v = fmaxf(v, __shfl_xor(v, 16)); v = fmaxf(v, __shfl_xor(v, 32));
  return v;
}

// ---------------------------------------------------------------------------
// 64x64-tile f32 GEMM, double-buffered LDS + register prefetch.
// K must be a multiple of 16 (true for all call sites).
// ---------------------------------------------------------------------------
template <int TRANSB>
__global__ __launch_bounds__(256) void gemm_k(
    const float* __restrict__ A, int lda, long long bsA,
    const float* __restrict__ B, int ldb, long long bsB,
    float* __restrict__ C, int ldc, long long bsC,
    int M, int N, int K)
{
  A += (size_t)blockIdx.z * bsA;
  B += (size_t)blockIdx.z * bsB;
  const int m0 = blockIdx.y * 64, n0 = blockIdx.x * 64;
  const int tid = threadIdx.x;
  __shared__ __attribute__((aligned(16))) float As[2][16][68];
  __shared__ __attribute__((aligned(16))) float Bs[2][16][68];
  float acc[4][4] = {};
  const int ty = tid >> 4, tx = tid & 15;
  const int am = tid >> 2, ak = (tid & 3) * 4;
  const int bk = tid >> 4, bn = (tid & 15) * 4;
  const bool aval = (m0 + am < M);
  const bool bval = TRANSB ? (n0 + am < N) : (n0 + bn < N);

  float4 av, bv;
  auto gload = [&](int k0) {
    av = make_float4(0.f, 0.f, 0.f, 0.f);
    bv = make_float4(0.f, 0.f, 0.f, 0.f);
    if (aval) av = *(const float4*)(A + (size_t)(m0 + am) * lda + (k0 + ak));
    if (TRANSB) {
      if (bval) bv = *(const float4*)(B + (size_t)(n0 + am) * ldb + (k0 + ak));
    } else {
      if (bval) bv = *(const float4*)(B + (size_t)(k0 + bk) * ldb + (n0 + bn));
    }
  };
  auto sstore = [&](int buf) {
    As[buf][ak + 0][am] = av.x; As[buf][ak + 1][am] = av.y;
    As[buf][ak + 2][am] = av.z; As[buf][ak + 3][am] = av.w;
    if (TRANSB) {
      Bs[buf][ak + 0][am] = bv.x; Bs[buf][ak + 1][am] = bv.y;
      Bs[buf][ak + 2][am] = bv.z; Bs[buf][ak + 3][am] = bv.w;
    } else {
      *(float4*)&Bs[buf][bk][bn] = bv;
    }
  };

  const int nIt = K >> 4;
  gload(0); sstore(0);
  for (int it = 0; it < nIt; ++it) {
    __syncthreads();
    if (it + 1 < nIt) gload((it + 1) << 4);
    const int buf = it & 1;
#pragma unroll
    for (int kk = 0; kk < 16; ++kk) {
      const float4 a  = *(const float4*)&As[buf][kk][ty * 4];
      const float4 bq = *(const float4*)&Bs[buf][kk][tx * 4];
      acc[0][0] += a.x * bq.x; acc[0][1] += a.x * bq.y; acc[0][2] += a.x * bq.z; acc[0][3] += a.x * bq.w;
      acc[1][0] += a.y * bq.x; acc[1][1] += a.y * bq.y; acc[1][2] += a.y * bq.z; acc[1][3] += a.y * bq.w;
      acc[2][0] += a.z * bq.x; acc[2][1] += a.z * bq.y; acc[2][2] += a.z * bq.z; acc[2][3] += a.z * bq.w;
      acc[3][0] += a.w * bq.x; acc[3][1] += a.w * bq.y; acc[3][2] += a.w * bq.z; acc[3][3] += a.w * bq.w;
    }
    if (it + 1 < nIt) sstore((it + 1) & 1);
  }
  const size_t cbase = (size_t)blockIdx.z * (size_t)bsC;
#pragma unroll
  for (int i = 0; i < 4; ++i) {
    const int m = m0 + ty * 4 + i;
    if (m >= M) continue;
#pragma unroll
    for (int j = 0; j < 4; ++j) {
      const int nn = n0 + tx * 4 + j;
      if (nn < N) C[cbase + (size_t)m * ldc + nn] = acc[i][j];
    }
  }
}

// ---------------------------------------------------------------------------
// 32x64-tile f32 GEMM, double-buffered, grid 256 for M=1000 (fills 256 CUs).
// ---------------------------------------------------------------------------
template <int TRANSB, int ADDD, int EXPALPHA>
__global__ __launch_bounds__(256) void gemm32_k(
    const float* __restrict__ A, int lda, long long bsA,
    const float* __restrict__ B, int ldb, long long bsB,
    float* __restrict__ C, int ldc, long long bsC,
    const float* __restrict__ D, long long ldd,
    const float* __restrict__ alpha_ptr,
    int M, int N, int K)
{
  A += (size_t)blockIdx.z * bsA;
  B += (size_t)blockIdx.z * bsB;
  const int m0 = blockIdx.y * 32, n0 = blockIdx.x * 64;
  const int tid = threadIdx.x;
  __shared__ __attribute__((aligned(16))) float As[2][16][36];
  __shared__ __attribute__((aligned(16))) float Bs[2][16][68];
  float acc[2][4] = {};
  const int ty = tid >> 4, tx = tid & 15;
  const int am = tid >> 3, ak = (tid & 7) * 2;   // A: 32r x 16k, float2
  const int bk = tid >> 4, bn = (tid & 15) * 4;  // B normal: 16k x 64n
  const int bm = tid >> 2, bt = (tid & 3) * 4;   // B transb: 64n x 16k
  const bool aval = (m0 + am < M);
  const bool bval = TRANSB ? (n0 + bm < N) : (n0 + bn < N);

  float2 av; float4 bv;
  auto gload = [&](int k0) {
    av = make_float2(0.f, 0.f);
    bv = make_float4(0.f, 0.f, 0.f, 0.f);
    if (aval) av = *(const float2*)(A + (size_t)(m0 + am) * lda + (k0 + ak));
    if (TRANSB) {
      if (bval) bv = *(const float4*)(B + (size_t)(n0 + bm) * ldb + (k0 + bt));
    } else {
      if (bval) bv = *(const float4*)(B + (size_t)(k0 + bk) * ldb + (n0 + bn));
    }
  };
  auto sstore = [&](int buf) {
    As[buf][ak][am] = av.x; As[buf][ak + 1][am] = av.y;
    if (TRANSB) {
      Bs[buf][bt + 0][bm] = bv.x; Bs[buf][bt + 1][bm] = bv.y;
      Bs[buf][bt + 2][bm] = bv.z; Bs[buf][bt + 3][bm] = bv.w;
    } else {
      *(float4*)&Bs[buf][bk][bn] = bv;
    }
  };

  const int nIt = K >> 4;
  gload(0); sstore(0);
  for (int it = 0; it < nIt; ++it) {
    __syncthreads();
    if (it + 1 < nIt) gload((it + 1) << 4);
    const int buf = it & 1;
#pragma unroll
    for (int kk = 0; kk < 16; ++kk) {
      const float2 a  = *(const float2*)&As[buf][kk][ty * 2];
      const float4 bq = *(const float4*)&Bs[buf][kk][tx * 4];
      acc[0][0] += a.x * bq.x; acc[0][1] += a.x * bq.y; acc[0][2] += a.x * bq.z; acc[0][3] += a.x * bq.w;
      acc[1][0] += a.y * bq.x; acc[1][1] += a.y * bq.y; acc[1][2] += a.y * bq.z; acc[1][3] += a.y * bq.w;
    }
    if (it + 1 < nIt) sstore((it + 1) & 1);
  }

  float alpha = 1.f;
  if (EXPALPHA) alpha = __expf(alpha_ptr[0]);
  const size_t cbase = (size_t)blockIdx.z * (size_t)bsC;
#pragma unroll
  for (int i = 0; i < 2; ++i) {
    const int m = m0 + ty * 2 + i;
    if (m >= M) continue;
#pragma unroll
    for (int j = 0; j < 4; ++j) {
      const int nn = n0 + tx * 4 + j;
      if (nn >= N) continue;
      float v = acc[i][j] * alpha;
      if (ADDD) v += D[(size_t)m * ldd + nn];
      C[cbase + (size_t)m * ldc + nn] = v;
    }
  }
}

// L2-normalize rows of x[rows][512] in place.
__global__ __launch_bounds__(256) void rownorm_kernel(float* __restrict__ x)
{
  const int r = blockIdx.x, tid = threadIdx.x;
  float* row = x + (size_t)r * 512;
  float2 v = *(float2*)(row + tid * 2);
  float ss = v.x * v.x + v.y * v.y;
  ss = wsum(ss);
  __shared__ float s4[4];
  const int w = tid >> 6, lane = tid & 63;
  if (lane == 0) s4[w] = ss;
  __syncthreads();
  const float sc = rsqrtf(s4[0] + s4[1] + s4[2] + s4[3]);
  v.x *= sc; v.y *= sc;
  *(float2*)(row + tid * 2) = v;
}

// hl[n] = LayerNorm(cls_tok[n][71]).
__global__ __launch_bounds__(64) void lnlast_kernel(
    const float* __restrict__ cls, const float* __restrict__ g,
    const float* __restrict__ b, float* __restrict__ hl)
{
  const int n = blockIdx.x, lane = threadIdx.x;
  const float* src = cls + ((size_t)n * 72 + 71) * 512;
  float x[8];
#pragma unroll
  for (int i = 0; i < 8; ++i) x[i] = src[lane + 64 * i];
  float s = 0.f, ss = 0.f;
#pragma unroll
  for (int i = 0; i < 8; ++i) { s += x[i]; ss += x[i] * x[i]; }
  s = wsum(s); ss = wsum(ss);
  const float mean = s * (1.f / 512.f);
  const float rstd = rsqrtf(ss * (1.f / 512.f) - mean * mean + 1e-5f);
  float* dst = hl + (size_t)n * 512;
#pragma unroll
  for (int i = 0; i < 8; ++i) {
    const int j = lane + 64 * i;
    dst[j] = (x[i] - mean) * rstd * g[j] + b[j];
  }
}

// ---------------------------------------------------------------------------
// FUSED pass1+pass2 sweep — 512 threads / 8 waves (each wave: 9 cls rows).
// cls rows (keys 5..76) are identical in both transformer passes, so one
// sweep accumulates pass-1 scores AND the pass-2 online-softmax state
// (m, l, V = sum e^s * h). Pass 2 finishes with the 5 ctx rows from LDS.
// Reads wt[n] fully into LDS before writing u_out[n] (may alias).
// ---------------------------------------------------------------------------
__global__ __launch_bounds__(512) void fused_sweep_kernel(
    const float* __restrict__ ctx, const float* __restrict__ cls,
    const float* __restrict__ g, const float* __restrict__ b,
    const float* __restrict__ wt, float* __restrict__ u_out)
{
  const int n = blockIdx.x, tid = threadIdx.x;
  const int w = tid >> 6, lane = tid & 63;
  __shared__ __attribute__((aligned(16))) float wt_s[8][512];
  __shared__ __attribute__((aligned(16))) float g_s[512], b_s[512];
  __shared__ __attribute__((aligned(16))) float hctx[5][512];
  __shared__ __attribute__((aligned(16))) float V_s[8][512];
  __shared__ float sc_s[8][80];
  __shared__ float sc2_s[8][5];
  __shared__ float A_s[8][5];
  __shared__ float wstat[8][8][2];
  __shared__ float attr_s[5];
  __shared__ float M72[8], L72[8];
  __shared__ float cfV[8], cf_s[8][5];

  {
    const float4* wsrc = (const float4*)(wt + (size_t)n * 4096);
    float4* wdst = (float4*)&wt_s[0][0];
    for (int i = tid; i < 1024; i += 512) wdst[i] = wsrc[i];
    const float4* csrc = (const float4*)(ctx + (size_t)n * 2560);
    float4* cdst = (float4*)&hctx[0][0];
    for (int i = tid; i < 640; i += 512) cdst[i] = csrc[i];
    float4* vdst = (float4*)&V_s[0][0];
    for (int i = tid; i < 1024; i += 512) vdst[i] = make_float4(0.f, 0.f, 0.f, 0.f);
    if (tid < 128) ((float4*)g_s)[tid] = ((const float4*)g)[tid];
    else if (tid < 256) ((float4*)b_s)[tid - 128] = ((const float4*)b)[tid - 128];
  }
  __syncthreads();

  // ---- stage A: 5 unscaled ctx rows -> pass-1 scores sc_s[.][0..4]
  if (w < 5) {
    const int k = w;
    float2 x2[4];
#pragma unroll
    for (int i = 0; i < 4; ++i)
      x2[i] = *(const float2*)&hctx[k][lane * 2 + 128 * i];
    float s = 0.f, ss = 0.f;
#pragma unroll
    for (int i = 0; i < 4; ++i) {
      s += x2[i].x + x2[i].y; ss += x2[i].x * x2[i].x + x2[i].y * x2[i].y;
    }
    s = wsum(s); ss = wsum(ss);
    const float mean = s * (1.f / 512.f);
    const float rstd = rsqrtf(ss * (1.f / 512.f) - mean * mean + 1e-5f);
    float h[8];
#pragma unroll
    for (int i = 0; i < 4; ++i) {
      const float2 gg = *(const float2*)&g_s[lane * 2 + 128 * i];
      const float2 bb = *(const float2*)&b_s[lane * 2 + 128 * i];
      h[2 * i]     = (x2[i].x - mean) * rstd * gg.x + bb.x;
      h[2 * i + 1] = (x2[i].y - mean) * rstd * gg.y + bb.y;
    }
    float sc[8] = {};
#pragma unroll
    for (int hh = 0; hh < 8; ++hh)
#pragma unroll
      for (int i = 0; i < 4; ++i) {
        const float2 ww = *(const float2*)&wt_s[hh][lane * 2 + 128 * i];
        sc[hh] += h[2 * i] * ww.x + h[2 * i + 1] * ww.y;
      }
#pragma unroll
    for (int hh = 0; hh < 8; ++hh) sc[hh] = wsum(sc[hh]);
    if (lane == 0)
#pragma unroll
      for (int hh = 0; hh < 8; ++hh) sc_s[hh][k] = sc[hh] * 0.125f;
  }

  // ---- stage B: 72 cls rows (9 per wave), scores + online softmax state
  float V[8][8];
#pragma unroll
  for (int hh = 0; hh < 8; ++hh)
#pragma unroll
    for (int i = 0; i < 8; ++i) V[hh][i] = 0.f;
  float mrun[8], lrun[8];
#pragma unroll
  for (int hh = 0; hh < 8; ++hh) { mrun[hh] = -1e30f; lrun[hh] = 0.f; }

  const float* base = cls + (size_t)n * 72 * 512;
  float2 xc[4];
  {
    const float* src = base + (size_t)w * 512;   // row (5+w)-5 = w
#pragma unroll
    for (int i = 0; i < 4; ++i)
      xc[i] = *(const float2*)(src + lane * 2 + 128 * i);
  }
  for (int k = 5 + w; k < 77; k += 8) {
    float2 xn[4];
    const bool more = (k + 8 < 77);
    if (more) {
      const float* srcn = base + (size_t)(k + 3) * 512;  // row (k+8)-5
#pragma unroll
      for (int i = 0; i < 4; ++i)
        xn[i] = *(const float2*)(srcn + lane * 2 + 128 * i);
    }
    float s = 0.f, ss = 0.f;
#pragma unroll
    for (int i = 0; i < 4; ++i) {
      s += xc[i].x + xc[i].y; ss += xc[i].x * xc[i].x + xc[i].y * xc[i].y;
    }
    s = wsum(s); ss = wsum(ss);
    const float mean = s * (1.f / 512.f);
    const float rstd = rsqrtf(ss * (1.f / 512.f) - mean * mean + 1e-5f);
    float h[8];
#pragma unroll
    for (int i = 0; i < 4; ++i) {
      const float2 gg = *(const float2*)&g_s[lane * 2 + 128 * i];
      const float2 bb = *(const float2*)&b_s[lane * 2 + 128 * i];
      h[2 * i]     = (xc[i].x - mean) * rstd * gg.x + bb.x;
      h[2 * i + 1] = (xc[i].y - mean) * rstd * gg.y + bb.y;
    }
    float sc[8] = {};
#pragma unroll
    for (int hh = 0; hh < 8; ++hh)
#pragma unroll
      for (int i = 0; i < 4; ++i) {
        const float2 ww = *(const float2*)&wt_s[hh][lane * 2 + 128 * i];
        sc[hh] += h[2 * i] * ww.x + h[2 * i + 1] * ww.y;
      }
#pragma unroll
    for (int hh = 0; hh < 8; ++hh) sc[hh] = wsum(sc[hh]);
    if (lane == 0)
#pragma unroll
      for (int hh = 0; hh < 8; ++hh) sc_s[hh][k] = sc[hh] * 0.125f;
#pragma unroll
    for (int hh = 0; hh < 8; ++hh) {
      const float sv = sc[hh] * 0.125f;
      const float nm = fmaxf(mrun[hh], sv);
      const float fac = __expf(mrun[hh] - nm);
      const float es = __expf(sv - nm);
      lrun[hh] = lrun[hh] * fac + es;
      mrun[hh] = nm;
#pragma unroll
      for (int i = 0; i < 8; ++i) V[hh][i] = V[hh][i] * fac + es * h[i];
    }
    if (more)
#pragma unroll
      for (int i = 0; i < 4; ++i) xc[i] = xn[i];
  }

  if (lane == 0)
#pragma unroll
    for (int hh = 0; hh < 8; ++hh) {
      wstat[w][hh][0] = mrun[hh]; wstat[w][hh][1] = lrun[hh];
    }
  __syncthreads();
  if (tid < 8) {
    float M = -1e30f;
    for (int wv = 0; wv < 8; ++wv) M = fmaxf(M, wstat[wv][tid][0]);
    float L = 0.f;
    for (int wv = 0; wv < 8; ++wv)
      L += wstat[wv][tid][1] * __expf(wstat[wv][tid][0] - M);
    M72[tid] = M; L72[tid] = L;
  }
  __syncthreads();
  for (int wv = 0; wv < 8; ++wv) {
    if (w == wv) {
#pragma unroll
      for (int hh = 0; hh < 8; ++hh) {
        const float f = __expf(mrun[hh] - M72[hh]);
#pragma unroll
        for (int i = 0; i < 4; ++i) {
          float2* p = (float2*)&V_s[hh][lane * 2 + 128 * i];
          float2 v = *p;
          v.x += V[hh][2 * i] * f; v.y += V[hh][2 * i + 1] * f;
          *p = v;
        }
      }
    }
    __syncthreads();
  }

  // ---- pass-1 softmax over 77 keys -> head-mean of first 5 -> attr
  if (w < 8) {
    const int hh = w;
    const float v0 = sc_s[hh][lane];
    const float v1 = (lane + 64 < 77) ? sc_s[hh][lane + 64] : -1e30f;
    const float mx = wmaxr(fmaxf(v0, v1));
    const float e0 = __expf(v0 - mx);
    const float e1 = (lane + 64 < 77) ? __expf(v1 - mx) : 0.f;
    const float S = wsum(e0 + e1);
    if (lane < 5) A_s[hh][lane] = e0 / S;
  }
  __syncthreads();
  if (tid == 0) {
    float m[5], mx = -1e30f;
#pragma unroll
    for (int p = 0; p < 5; ++p) {
      float acc = 0.f;
      for (int hh = 0; hh < 8; ++hh) acc += A_s[hh][p];
      m[p] = acc * 0.125f;
      mx = fmaxf(mx, m[p]);
    }
    float e[5], S = 0.f;
#pragma unroll
    for (int p = 0; p < 5; ++p) { e[p] = __expf(m[p] - mx); S += e[p]; }
#pragma unroll
    for (int p = 0; p < 5; ++p) attr_s[p] = e[p] / S;
  }
  __syncthreads();

  // ---- stage C: scaled ctx rows -> h2 (in place in hctx) + scores sc2
  if (w < 5) {
    const int k = w;
    const float c = attr_s[k];
    float2 x2[4];
#pragma unroll
    for (int i = 0; i < 4; ++i) {
      x2[i] = *(const float2*)&hctx[k][lane * 2 + 128 * i];
      x2[i].x *= c; x2[i].y *= c;
    }
    float s = 0.f, ss = 0.f;
#pragma unroll
    for (int i = 0; i < 4; ++i) {
      s += x2[i].x + x2[i].y; ss += x2[i].x * x2[i].x + x2[i].y * x2[i].y;
    }
    s = wsum(s); ss = wsum(ss);
    const float mean = s * (1.f / 512.f);
    const float rstd = rsqrtf(ss * (1.f / 512.f) - mean * mean + 1e-5f);
    float h[8];
#pragma unroll
    for (int i = 0; i < 4; ++i) {
      const float2 gg = *(const float2*)&g_s[lane * 2 + 128 * i];
      const float2 bb = *(const float2*)&b_s[lane * 2 + 128 * i];
      h[2 * i]     = (x2[i].x - mean) * rstd * gg.x + bb.x;
      h[2 * i + 1] = (x2[i].y - mean) * rstd * gg.y + bb.y;
      *(float2*)&hctx[k][lane * 2 + 128 * i] = make_float2(h[2 * i], h[2 * i + 1]);
    }
    float sc[8] = {};
#pragma unroll
    for (int hh = 0; hh < 8; ++hh)
#pragma unroll
      for (int i = 0; i < 4; ++i) {
        const float2 ww = *(const float2*)&wt_s[hh][lane * 2 + 128 * i];
        sc[hh] += h[2 * i] * ww.x + h[2 * i + 1] * ww.y;
      }
#pragma unroll
    for (int hh = 0; hh < 8; ++hh) sc[hh] = wsum(sc[hh]);
    if (lane == 0)
#pragma unroll
      for (int hh = 0; hh < 8; ++hh) sc2_s[hh][k] = sc[hh] * 0.125f;
  }
  __syncthreads();

  // ---- final combine coefficients per head
  if (tid < 8) {
    float Mf = M72[tid];
#pragma unroll
    for (int k = 0; k < 5; ++k) Mf = fmaxf(Mf, sc2_s[tid][k]);
    float e[5], den = L72[tid] * __expf(M72[tid] - Mf);
#pragma unroll
    for (int k = 0; k < 5; ++k) { e[k] = __expf(sc2_s[tid][k] - Mf); den += e[k]; }
    const float r = 1.f / den;
    cfV[tid] = __expf(M72[tid] - Mf) * r;
#pragma unroll
    for (int k = 0; k < 5; ++k) cf_s[tid][k] = e[k] * r;
  }
  __syncthreads();

  // ---- u[n][h][j] = cfV*V + sum_k cf*h2  -> global (coalesced)
  float* dst = u_out + (size_t)n * 4096;
  for (int idx = tid; idx < 4096; idx += 512) {
    const int hh = idx >> 9, j = idx & 511;
    float v = cfV[hh] * V_s[hh][j];
#pragma unroll
    for (int k = 0; k < 5; ++k) v += cf_s[hh][k] * hctx[k][j];
    dst[idx] = v;
  }
}

// ---------------------------------------------------------------------------
extern "C" void kernel_launch(void* const* d_in, const int* in_sizes, int n_in,
                              void* d_out, int out_size, void* d_ws, size_t ws_size,
                              hipStream_t stream)
{
  const float* images = (const float*)d_in[0];
  const float* W_img  = (const float*)d_in[1];
  const float* ctx    = (const float*)d_in[2];
  const float* cls    = (const float*)d_in[3];
  const float* ln_g   = (const float*)d_in[4];
  const float* ln_b   = (const float*)d_in[5];
  const float* Wq     = (const float*)d_in[6];
  const float* Wk     = (const float*)d_in[7];
  const float* Wv     = (const float*)d_in[8];
  const float* Wo     = (const float*)d_in[9];
  const float* tproj  = (const float*)d_in[10];
  const float* lscale = (const float*)d_in[11];

  float* ws   = (float*)d_ws;
  float* wtu  = ws;                 // wt -> u (in place) -> txt overlay
  float* img  = wtu + 4096000;
  float* hlO  = img + 131072;       // hl -> O
  float* qo2  = hlO + 512000;       // q  -> out2
  float* txt  = wtu;
  (void)in_sizes; (void)n_in; (void)out_size; (void)ws_size;

  // 1) image embedding + L2 norm
  gemm32_k<0,0,0><<<dim3(8,8,1),256,0,stream>>>(images,768,0, W_img,512,0,
      img,512,0, nullptr,0, nullptr, 256,512,768);
  rownorm_kernel<<<256,256,0,stream>>>(img);

  // 2) q = LN(last row) @ Wq
  lnlast_kernel<<<1000,64,0,stream>>>(cls, ln_g, ln_b, hlO);
  gemm32_k<0,0,0><<<dim3(8,32,1),256,0,stream>>>(hlO,512,0, Wq,512,0,
      qo2,512,0, nullptr,0, nullptr, 1000,512,512);

  // 3) wt[n][h][j] = sum_d Wk[j][h*64+d] * q[n][h*64+d]
  gemm_k<1><<<dim3(8,16,8),256,0,stream>>>(qo2,512,64, Wk,512,64,
      wtu,4096,512, 1000,512,64);

  // 4+5) fused pass1+pass2 sweep -> u[n][8][512] (in place over wt)
  fused_sweep_kernel<<<1000,512,0,stream>>>(ctx, cls, ln_g, ln_b, wtu, wtu);

  // 6) O[n][h*64+c] = u[n][h] @ Wv[:,h*64+c]
  gemm32_k<0,0,0><<<dim3(1,32,8),256,0,stream>>>(wtu,4096,512, Wv,512,64,
      hlO,512,64, nullptr,0, nullptr, 1000,64,512);

  // 7) out2 = cls_last + O @ Wo ; txt = out2 @ text_proj ; L2 norm
  gemm32_k<0,1,0><<<dim3(8,32,1),256,0,stream>>>(hlO,512,0, Wo,512,0,
      qo2,512,0, cls + 71*512, 72*512, nullptr, 1000,512,512);
  gemm32_k<0,0,0><<<dim3(8,32,1),256,0,stream>>>(qo2,512,0, tproj,512,0,
      txt,512,0, nullptr,0, nullptr, 1000,512,512);
  rownorm_kernel<<<1000,256,0,stream>>>(txt);

  // 8) logits = exp(ls) * img @ txt^T   (f32 out)
  gemm32_k<1,0,1><<<dim3(16,8,1),256,0,stream>>>(img,512,0, txt,512,0,
      (float*)d_out,1000,0, nullptr,0, lscale, 256,1000,512);
}

// Round 6
// 232.116 us; speedup vs baseline: 1.6766x; 1.2400x over previous
//
#include <hip/hip_runtime.h>
#include <hip/hip_bf16.h>

#define DEV static __device__ __forceinline__

DEV float wsum(float v) {
  v += __shfl_xor(v, 1);  v += __shfl_xor(v, 2);  v += __shfl_xor(v, 4);
  v += __shfl_xor(v, 8);  v += __shfl_xor(v, 16); v += __shfl_xor(v, 32);
  return v;
}
DEV float wmaxr(float v) {
  v = fmaxf(v, __shfl_xor(v, 1));  v = fmaxf(v, __shfl_xor(v, 2));
  v = fmaxf(v, __shfl_xor(v, 4));  v = fmaxf(v, __shfl_xor(v, 8));
  v = fmaxf(v, __shfl_xor(v, 16)); v = fmaxf(v, __shfl_xor(v, 32));
  return v;
}

// Fold-reduce 8 per-lane values across 64 lanes: returns the full 64-lane sum
// of head (lane & 7), replicated in every 8-lane group. ~27 instrs vs 96.
DEV float fold8(const float v[8], int lane) {
  float w4[4];
#pragma unroll
  for (int j = 0; j < 4; ++j) {
    const float mine  = (lane & 1) ? v[2 * j + 1] : v[2 * j];
    const float other = (lane & 1) ? v[2 * j]     : v[2 * j + 1];
    w4[j] = mine + __shfl_xor(other, 1);
  }
  float u2[2];
#pragma unroll
  for (int j = 0; j < 2; ++j) {
    const float mine  = (lane & 2) ? w4[2 * j + 1] : w4[2 * j];
    const float other = (lane & 2) ? w4[2 * j]     : w4[2 * j + 1];
    u2[j] = mine + __shfl_xor(other, 2);
  }
  const float mine  = (lane & 4) ? u2[1] : u2[0];
  const float other = (lane & 4) ? u2[0] : u2[1];
  float z = mine + __shfl_xor(other, 4);
  z += __shfl_xor(z, 8); z += __shfl_xor(z, 16); z += __shfl_xor(z, 32);
  return z;   // sum of head (lane&7)
}

// All-gather: input = value of head (lane&7); output out[j] = head j, all lanes.
DEV void gather8(float e, int lane, float out[8]) {
  const float t  = __shfl_xor(e, 1);
  const float lo1 = (lane & 1) ? t : e;     // head (b2 b1 0)
  const float hi1 = (lane & 1) ? e : t;     // head (b2 b1 1)
  const float t0 = __shfl_xor(lo1, 2), t1 = __shfl_xor(hi1, 2);
  const float a00 = (lane & 2) ? t0 : lo1;  // (b2 0 0)
  const float a01 = (lane & 2) ? t1 : hi1;  // (b2 0 1)
  const float a10 = (lane & 2) ? lo1 : t0;  // (b2 1 0)
  const float a11 = (lane & 2) ? hi1 : t1;  // (b2 1 1)
  const float s00 = __shfl_xor(a00, 4), s01 = __shfl_xor(a01, 4);
  const float s10 = __shfl_xor(a10, 4), s11 = __shfl_xor(a11, 4);
  out[0] = (lane & 4) ? s00 : a00;  out[1] = (lane & 4) ? s01 : a01;
  out[2] = (lane & 4) ? s10 : a10;  out[3] = (lane & 4) ? s11 : a11;
  out[4] = (lane & 4) ? a00 : s00;  out[5] = (lane & 4) ? a01 : s01;
  out[6] = (lane & 4) ? a10 : s10;  out[7] = (lane & 4) ? a11 : s11;
}

// ---------------------------------------------------------------------------
// 64x64-tile f32 GEMM, double-buffered LDS + register prefetch.
// ---------------------------------------------------------------------------
template <int TRANSB>
__global__ __launch_bounds__(256) void gemm_k(
    const float* __restrict__ A, int lda, long long bsA,
    const float* __restrict__ B, int ldb, long long bsB,
    float* __restrict__ C, int ldc, long long bsC,
    int M, int N, int K)
{
  A += (size_t)blockIdx.z * bsA;
  B += (size_t)blockIdx.z * bsB;
  const int m0 = blockIdx.y * 64, n0 = blockIdx.x * 64;
  const int tid = threadIdx.x;
  __shared__ __attribute__((aligned(16))) float As[2][16][68];
  __shared__ __attribute__((aligned(16))) float Bs[2][16][68];
  float acc[4][4] = {};
  const int ty = tid >> 4, tx = tid & 15;
  const int am = tid >> 2, ak = (tid & 3) * 4;
  const int bk = tid >> 4, bn = (tid & 15) * 4;
  const bool aval = (m0 + am < M);
  const bool bval = TRANSB ? (n0 + am < N) : (n0 + bn < N);

  float4 av, bv;
  auto gload = [&](int k0) {
    av = make_float4(0.f, 0.f, 0.f, 0.f);
    bv = make_float4(0.f, 0.f, 0.f, 0.f);
    if (aval) av = *(const float4*)(A + (size_t)(m0 + am) * lda + (k0 + ak));
    if (TRANSB) {
      if (bval) bv = *(const float4*)(B + (size_t)(n0 + am) * ldb + (k0 + ak));
    } else {
      if (bval) bv = *(const float4*)(B + (size_t)(k0 + bk) * ldb + (n0 + bn));
    }
  };
  auto sstore = [&](int buf) {
    As[buf][ak + 0][am] = av.x; As[buf][ak + 1][am] = av.y;
    As[buf][ak + 2][am] = av.z; As[buf][ak + 3][am] = av.w;
    if (TRANSB) {
      Bs[buf][ak + 0][am] = bv.x; Bs[buf][ak + 1][am] = bv.y;
      Bs[buf][ak + 2][am] = bv.z; Bs[buf][ak + 3][am] = bv.w;
    } else {
      *(float4*)&Bs[buf][bk][bn] = bv;
    }
  };

  const int nIt = K >> 4;
  gload(0); sstore(0);
  for (int it = 0; it < nIt; ++it) {
    __syncthreads();
    if (it + 1 < nIt) gload((it + 1) << 4);
    const int buf = it & 1;
#pragma unroll
    for (int kk = 0; kk < 16; ++kk) {
      const float4 a  = *(const float4*)&As[buf][kk][ty * 4];
      const float4 bq = *(const float4*)&Bs[buf][kk][tx * 4];
      acc[0][0] += a.x * bq.x; acc[0][1] += a.x * bq.y; acc[0][2] += a.x * bq.z; acc[0][3] += a.x * bq.w;
      acc[1][0] += a.y * bq.x; acc[1][1] += a.y * bq.y; acc[1][2] += a.y * bq.z; acc[1][3] += a.y * bq.w;
      acc[2][0] += a.z * bq.x; acc[2][1] += a.z * bq.y; acc[2][2] += a.z * bq.z; acc[2][3] += a.z * bq.w;
      acc[3][0] += a.w * bq.x; acc[3][1] += a.w * bq.y; acc[3][2] += a.w * bq.z; acc[3][3] += a.w * bq.w;
    }
    if (it + 1 < nIt) sstore((it + 1) & 1);
  }
  const size_t cbase = (size_t)blockIdx.z * (size_t)bsC;
#pragma unroll
  for (int i = 0; i < 4; ++i) {
    const int m = m0 + ty * 4 + i;
    if (m >= M) continue;
#pragma unroll
    for (int j = 0; j < 4; ++j) {
      const int nn = n0 + tx * 4 + j;
      if (nn < N) C[cbase + (size_t)m * ldc + nn] = acc[i][j];
    }
  }
}

// ---------------------------------------------------------------------------
// 32x64-tile f32 GEMM, double-buffered, grid ~256 for M=1000.
// ---------------------------------------------------------------------------
template <int TRANSB, int ADDD, int EXPALPHA>
__global__ __launch_bounds__(256) void gemm32_k(
    const float* __restrict__ A, int lda, long long bsA,
    const float* __restrict__ B, int ldb, long long bsB,
    float* __restrict__ C, int ldc, long long bsC,
    const float* __restrict__ D, long long ldd,
    const float* __restrict__ alpha_ptr,
    int M, int N, int K)
{
  A += (size_t)blockIdx.z * bsA;
  B += (size_t)blockIdx.z * bsB;
  const int m0 = blockIdx.y * 32, n0 = blockIdx.x * 64;
  const int tid = threadIdx.x;
  __shared__ __attribute__((aligned(16))) float As[2][16][36];
  __shared__ __attribute__((aligned(16))) float Bs[2][16][68];
  float acc[2][4] = {};
  const int ty = tid >> 4, tx = tid & 15;
  const int am = tid >> 3, ak = (tid & 7) * 2;
  const int bk = tid >> 4, bn = (tid & 15) * 4;
  const int bm = tid >> 2, bt = (tid & 3) * 4;
  const bool aval = (m0 + am < M);
  const bool bval = TRANSB ? (n0 + bm < N) : (n0 + bn < N);

  float2 av; float4 bv;
  auto gload = [&](int k0) {
    av = make_float2(0.f, 0.f);
    bv = make_float4(0.f, 0.f, 0.f, 0.f);
    if (aval) av = *(const float2*)(A + (size_t)(m0 + am) * lda + (k0 + ak));
    if (TRANSB) {
      if (bval) bv = *(const float4*)(B + (size_t)(n0 + bm) * ldb + (k0 + bt));
    } else {
      if (bval) bv = *(const float4*)(B + (size_t)(k0 + bk) * ldb + (n0 + bn));
    }
  };
  auto sstore = [&](int buf) {
    As[buf][ak][am] = av.x; As[buf][ak + 1][am] = av.y;
    if (TRANSB) {
      Bs[buf][bt + 0][bm] = bv.x; Bs[buf][bt + 1][bm] = bv.y;
      Bs[buf][bt + 2][bm] = bv.z; Bs[buf][bt + 3][bm] = bv.w;
    } else {
      *(float4*)&Bs[buf][bk][bn] = bv;
    }
  };

  const int nIt = K >> 4;
  gload(0); sstore(0);
  for (int it = 0; it < nIt; ++it) {
    __syncthreads();
    if (it + 1 < nIt) gload((it + 1) << 4);
    const int buf = it & 1;
#pragma unroll
    for (int kk = 0; kk < 16; ++kk) {
      const float2 a  = *(const float2*)&As[buf][kk][ty * 2];
      const float4 bq = *(const float4*)&Bs[buf][kk][tx * 4];
      acc[0][0] += a.x * bq.x; acc[0][1] += a.x * bq.y; acc[0][2] += a.x * bq.z; acc[0][3] += a.x * bq.w;
      acc[1][0] += a.y * bq.x; acc[1][1] += a.y * bq.y; acc[1][2] += a.y * bq.z; acc[1][3] += a.y * bq.w;
    }
    if (it + 1 < nIt) sstore((it + 1) & 1);
  }

  float alpha = 1.f;
  if (EXPALPHA) alpha = __expf(alpha_ptr[0]);
  const size_t cbase = (size_t)blockIdx.z * (size_t)bsC;
#pragma unroll
  for (int i = 0; i < 2; ++i) {
    const int m = m0 + ty * 2 + i;
    if (m >= M) continue;
#pragma unroll
    for (int j = 0; j < 4; ++j) {
      const int nn = n0 + tx * 4 + j;
      if (nn >= N) continue;
      float v = acc[i][j] * alpha;
      if (ADDD) v += D[(size_t)m * ldd + nn];
      C[cbase + (size_t)m * ldc + nn] = v;
    }
  }
}

__global__ __launch_bounds__(256) void rownorm_kernel(float* __restrict__ x)
{
  const int r = blockIdx.x, tid = threadIdx.x;
  float* row = x + (size_t)r * 512;
  float2 v = *(float2*)(row + tid * 2);
  float ss = v.x * v.x + v.y * v.y;
  ss = wsum(ss);
  __shared__ float s4[4];
  const int w = tid >> 6, lane = tid & 63;
  if (lane == 0) s4[w] = ss;
  __syncthreads();
  const float sc = rsqrtf(s4[0] + s4[1] + s4[2] + s4[3]);
  v.x *= sc; v.y *= sc;
  *(float2*)(row + tid * 2) = v;
}

__global__ __launch_bounds__(64) void lnlast_kernel(
    const float* __restrict__ cls, const float* __restrict__ g,
    const float* __restrict__ b, float* __restrict__ hl)
{
  const int n = blockIdx.x, lane = threadIdx.x;
  const float* src = cls + ((size_t)n * 72 + 71) * 512;
  float x[8];
#pragma unroll
  for (int i = 0; i < 8; ++i) x[i] = src[lane + 64 * i];
  float s = 0.f, ss = 0.f;
#pragma unroll
  for (int i = 0; i < 8; ++i) { s += x[i]; ss += x[i] * x[i]; }
  s = wsum(s); ss = wsum(ss);
  const float mean = s * (1.f / 512.f);
  const float rstd = rsqrtf(ss * (1.f / 512.f) - mean * mean + 1e-5f);
  float* dst = hl + (size_t)n * 512;
#pragma unroll
  for (int i = 0; i < 8; ++i) {
    const int j = lane + 64 * i;
    dst[j] = (x[i] - mean) * rstd * g[j] + b[j];
  }
}

// ---------------------------------------------------------------------------
// FUSED sweep, v3. 256 thr / 4 waves. Per-row cost cut via:
//  - scores on RAW x: s = 0.125*(rstd*(x.gw - mean*Sgw) + bw), gw = g*wt
//  - fold8 reduce (27 instr) + gather8 instead of 8 wsums (96)
//  - raw-exp accumulation (scores O(1), no overflow): A += e*rstd*x,
//    B += e*rstd*mean, L += e;  Sum e*h = g*(A-B) + b*L  (exact algebra)
//  - 1 exp per row per lane (exp before gather)
// LDS ~34 KB -> 4 blocks/CU. Reads wt[n] fully to LDS before writing u_out[n].
// ---------------------------------------------------------------------------
__global__ __launch_bounds__(256) void fused_sweep_kernel(
    const float* __restrict__ ctx, const float* __restrict__ cls,
    const float* __restrict__ g, const float* __restrict__ b,
    const float* __restrict__ wt, float* __restrict__ u_out)
{
  const int n = blockIdx.x, tid = threadIdx.x;
  const int w = tid >> 6, lane = tid & 63;
  __shared__ __attribute__((aligned(16))) float gw_s[8][512];  // wt->g*wt->A
  __shared__ __attribute__((aligned(16))) float g_s[512], b_s[512];
  __shared__ __attribute__((aligned(16))) float hctx[5][512];  // ctx -> h2
  __shared__ float sc_s[8][80];
  __shared__ float sc2_s[8][5];
  __shared__ float ah_s[8][5];
  __shared__ float wstatB[4][8], wstatL[4][8];
  __shared__ float attr_s[5];
  __shared__ float Sgw_l[8], bw_l[8];
  __shared__ float Bt_s[8], Lt_s[8], inv_s[8];
  __shared__ float e2_s[8][5];

  {
    const float4* wsrc = (const float4*)(wt + (size_t)n * 4096);
    float4* wdst = (float4*)&gw_s[0][0];
    for (int i = tid; i < 1024; i += 256) wdst[i] = wsrc[i];
    const float4* csrc = (const float4*)(ctx + (size_t)n * 2560);
    float4* cdst = (float4*)&hctx[0][0];
    for (int i = tid; i < 640; i += 256) cdst[i] = csrc[i];
    if (tid < 128) ((float4*)g_s)[tid] = ((const float4*)g)[tid];
    else ((float4*)b_s)[tid - 128] = ((const float4*)b)[tid - 128];
  }
  __syncthreads();

  // precompute gw = g*wt (in place), Sgw = sum gw, bw = sum b*wt
  for (int hh = w; hh < 8; hh += 4) {
    float s1 = 0.f, s2 = 0.f;
#pragma unroll
    for (int i = 0; i < 8; ++i) {
      const int j = lane + 64 * i;
      const float wv = gw_s[hh][j];
      const float gv = wv * g_s[j];
      s1 += gv; s2 += wv * b_s[j];
      gw_s[hh][j] = gv;
    }
    s1 = wsum(s1); s2 = wsum(s2);
    if (lane == 0) { Sgw_l[hh] = s1; bw_l[hh] = s2; }
  }
  __syncthreads();
  const float sg_r  = Sgw_l[lane & 7];
  const float bw8_r = bw_l[lane & 7] * 0.125f;

  // ---- stage A: 5 unscaled ctx rows -> pass-1 scores
  for (int k = w; k < 5; k += 4) {
    float2 x2[4];
#pragma unroll
    for (int i = 0; i < 4; ++i)
      x2[i] = *(const float2*)&hctx[k][lane * 2 + 128 * i];
    float s = 0.f, ss = 0.f;
#pragma unroll
    for (int i = 0; i < 4; ++i) {
      s += x2[i].x + x2[i].y; ss += x2[i].x * x2[i].x + x2[i].y * x2[i].y;
    }
    float v8[8] = {};
#pragma unroll
    for (int hh = 0; hh < 8; ++hh)
#pragma unroll
      for (int i = 0; i < 4; ++i) {
        const float2 ww = *(const float2*)&gw_s[hh][lane * 2 + 128 * i];
        v8[hh] += x2[i].x * ww.x + x2[i].y * ww.y;
      }
    s = wsum(s); ss = wsum(ss);
    const float mean = s * (1.f / 512.f);
    const float rstd = rsqrtf(ss * (1.f / 512.f) - mean * mean + 1e-5f);
    const float z = fold8(v8, lane);
    const float zf = rstd * 0.125f * (z - mean * sg_r) + bw8_r;
    if (lane < 8) sc_s[lane][k] = zf;
  }

  // ---- stage B: 72 cls rows (18/wave): scores + raw-exp accumulation
  float A[8][8];
#pragma unroll
  for (int hh = 0; hh < 8; ++hh)
#pragma unroll
    for (int i = 0; i < 8; ++i) A[hh][i] = 0.f;
  float B8[8] = {}, L8[8] = {};

  const float* base = cls + (size_t)n * 72 * 512;
  float2 xc[4];
  {
    const float* src = base + (size_t)w * 512;
#pragma unroll
    for (int i = 0; i < 4; ++i)
      xc[i] = *(const float2*)(src + lane * 2 + 128 * i);
  }
  for (int k = 5 + w; k < 77; k += 4) {
    float2 xn[4];
    const bool more = (k + 4 < 77);
    if (more) {
      const float* srcn = base + (size_t)(k - 1) * 512;  // row (k+4)-5
#pragma unroll
      for (int i = 0; i < 4; ++i)
        xn[i] = *(const float2*)(srcn + lane * 2 + 128 * i);
    }
    float s = 0.f, ss = 0.f;
#pragma unroll
    for (int i = 0; i < 4; ++i) {
      s += xc[i].x + xc[i].y; ss += xc[i].x * xc[i].x + xc[i].y * xc[i].y;
    }
    float v8[8] = {};
#pragma unroll
    for (int hh = 0; hh < 8; ++hh)
#pragma unroll
      for (int i = 0; i < 4; ++i) {
        const float2 ww = *(const float2*)&gw_s[hh][lane * 2 + 128 * i];
        v8[hh] += xc[i].x * ww.x + xc[i].y * ww.y;
      }
    s = wsum(s); ss = wsum(ss);
    const float mean = s * (1.f / 512.f);
    const float rstd = rsqrtf(ss * (1.f / 512.f) - mean * mean + 1e-5f);
    const float z = fold8(v8, lane);
    const float zf = rstd * 0.125f * (z - mean * sg_r) + bw8_r;
    if (lane < 8) sc_s[lane][k] = zf;
    const float ez = __expf(zf);          // head (lane&7); scores O(1): safe
    float es[8];
    gather8(ez, lane, es);                // es[j] = head j, all lanes
#pragma unroll
    for (int hh = 0; hh < 8; ++hh) {
      const float er = es[hh] * rstd;
#pragma unroll
      for (int i = 0; i < 4; ++i) {
        A[hh][2 * i]     += er * xc[i].x;
        A[hh][2 * i + 1] += er * xc[i].y;
      }
      B8[hh] += er * mean;
      L8[hh] += es[hh];
    }
    if (more)
#pragma unroll
      for (int i = 0; i < 4; ++i) xc[i] = xn[i];
  }
  if (lane == 0)
#pragma unroll
    for (int hh = 0; hh < 8; ++hh) {
      wstatB[w][hh] = B8[hh]; wstatL[w][hh] = L8[hh];
    }
  __syncthreads();

  // ---- pass-1 softmax over 77 -> head-mean of first 5 -> attr
  for (int hh = w; hh < 8; hh += 4) {
    const float v0 = sc_s[hh][lane];
    const float v1 = (lane + 64 < 77) ? sc_s[hh][lane + 64] : -1e30f;
    const float mx = wmaxr(fmaxf(v0, v1));
    const float e0 = __expf(v0 - mx);
    const float e1 = (lane + 64 < 77) ? __expf(v1 - mx) : 0.f;
    const float S = wsum(e0 + e1);
    if (lane < 5) ah_s[hh][lane] = e0 / S;
  }
  __syncthreads();
  if (tid == 0) {
    float m[5], mx = -1e30f;
#pragma unroll
    for (int p = 0; p < 5; ++p) {
      float acc = 0.f;
      for (int hh = 0; hh < 8; ++hh) acc += ah_s[hh][p];
      m[p] = acc * 0.125f;
      mx = fmaxf(mx, m[p]);
    }
    float e[5], S = 0.f;
#pragma unroll
    for (int p = 0; p < 5; ++p) { e[p] = __expf(m[p] - mx); S += e[p]; }
#pragma unroll
    for (int p = 0; p < 5; ++p) attr_s[p] = e[p] / S;
  }
  __syncthreads();

  // ---- stage C: scaled ctx rows -> h2 (into hctx) + scores sc2
  for (int k = w; k < 5; k += 4) {
    const float c = attr_s[k];
    float2 x2[4];
#pragma unroll
    for (int i = 0; i < 4; ++i) {
      x2[i] = *(const float2*)&hctx[k][lane * 2 + 128 * i];
      x2[i].x *= c; x2[i].y *= c;
    }
    float s = 0.f, ss = 0.f;
#pragma unroll
    for (int i = 0; i < 4; ++i) {
      s += x2[i].x + x2[i].y; ss += x2[i].x * x2[i].x + x2[i].y * x2[i].y;
    }
    float v8[8] = {};
#pragma unroll
    for (int hh = 0; hh < 8; ++hh)
#pragma unroll
      for (int i = 0; i < 4; ++i) {
        const float2 ww = *(const float2*)&gw_s[hh][lane * 2 + 128 * i];
        v8[hh] += x2[i].x * ww.x + x2[i].y * ww.y;
      }
    s = wsum(s); ss = wsum(ss);
    const float mean = s * (1.f / 512.f);
    const float rstd = rsqrtf(ss * (1.f / 512.f) - mean * mean + 1e-5f);
#pragma unroll
    for (int i = 0; i < 4; ++i) {
      const int j0 = lane * 2 + 128 * i;
      const float2 gg = *(const float2*)&g_s[j0];
      const float2 bb = *(const float2*)&b_s[j0];
      *(float2*)&hctx[k][j0] = make_float2(
          (x2[i].x - mean) * rstd * gg.x + bb.x,
          (x2[i].y - mean) * rstd * gg.y + bb.y);
    }
    const float z = fold8(v8, lane);
    const float zf = rstd * 0.125f * (z - mean * sg_r) + bw8_r;
    if (lane < 8) sc2_s[lane][k] = zf;
  }
  __syncthreads();   // gw_s dead as weights; hctx now h2

  // ---- cross-wave A combine into gw_s region (wave 0 writes, rest add)
  for (int wv = 0; wv < 4; ++wv) {
    if (w == wv) {
#pragma unroll
      for (int hh = 0; hh < 8; ++hh)
#pragma unroll
        for (int i = 0; i < 4; ++i) {
          float2* p = (float2*)&gw_s[hh][lane * 2 + 128 * i];
          const float2 a = make_float2(A[hh][2 * i], A[hh][2 * i + 1]);
          if (wv == 0) *p = a;
          else { float2 v = *p; v.x += a.x; v.y += a.y; *p = v; }
        }
    }
    __syncthreads();
  }

  if (tid < 8) {
    float Bt = 0.f, Lt = 0.f;
    for (int wv = 0; wv < 4; ++wv) { Bt += wstatB[wv][tid]; Lt += wstatL[wv][tid]; }
    float den = Lt;
#pragma unroll
    for (int k = 0; k < 5; ++k) {
      const float e = __expf(sc2_s[tid][k]);
      e2_s[tid][k] = e; den += e;
    }
    Bt_s[tid] = Bt; Lt_s[tid] = Lt; inv_s[tid] = 1.f / den;
  }
  __syncthreads();

  // ---- u[hh][j] = (g*(A-B) + b*L + sum_k e2*h2) / den
  float* dst = u_out + (size_t)n * 4096;
  for (int idx = tid; idx < 4096; idx += 256) {
    const int hh = idx >> 9, j = idx & 511;
    float v = (gw_s[hh][j] - Bt_s[hh]) * g_s[j] + Lt_s[hh] * b_s[j];
#pragma unroll
    for (int k = 0; k < 5; ++k) v += e2_s[hh][k] * hctx[k][j];
    dst[idx] = v * inv_s[hh];
  }
}

// ---------------------------------------------------------------------------
extern "C" void kernel_launch(void* const* d_in, const int* in_sizes, int n_in,
                              void* d_out, int out_size, void* d_ws, size_t ws_size,
                              hipStream_t stream)
{
  const float* images = (const float*)d_in[0];
  const float* W_img  = (const float*)d_in[1];
  const float* ctx    = (const float*)d_in[2];
  const float* cls    = (const float*)d_in[3];
  const float* ln_g   = (const float*)d_in[4];
  const float* ln_b   = (const float*)d_in[5];
  const float* Wq     = (const float*)d_in[6];
  const float* Wk     = (const float*)d_in[7];
  const float* Wv     = (const float*)d_in[8];
  const float* Wo     = (const float*)d_in[9];
  const float* tproj  = (const float*)d_in[10];
  const float* lscale = (const float*)d_in[11];

  float* ws   = (float*)d_ws;
  float* wtu  = ws;                 // wt -> u (in place) -> txt overlay
  float* img  = wtu + 4096000;
  float* hlO  = img + 131072;       // hl -> O
  float* qo2  = hlO + 512000;       // q  -> out2
  float* txt  = wtu;
  (void)in_sizes; (void)n_in; (void)out_size; (void)ws_size;

  gemm32_k<0,0,0><<<dim3(8,8,1),256,0,stream>>>(images,768,0, W_img,512,0,
      img,512,0, nullptr,0, nullptr, 256,512,768);
  rownorm_kernel<<<256,256,0,stream>>>(img);

  lnlast_kernel<<<1000,64,0,stream>>>(cls, ln_g, ln_b, hlO);
  gemm32_k<0,0,0><<<dim3(8,32,1),256,0,stream>>>(hlO,512,0, Wq,512,0,
      qo2,512,0, nullptr,0, nullptr, 1000,512,512);

  gemm_k<1><<<dim3(8,16,8),256,0,stream>>>(qo2,512,64, Wk,512,64,
      wtu,4096,512, 1000,512,64);

  fused_sweep_kernel<<<1000,256,0,stream>>>(ctx, cls, ln_g, ln_b, wtu, wtu);

  gemm32_k<0,0,0><<<dim3(1,32,8),256,0,stream>>>(wtu,4096,512, Wv,512,64,
      hlO,512,64, nullptr,0, nullptr, 1000,64,512);

  gemm32_k<0,1,0><<<dim3(8,32,1),256,0,stream>>>(hlO,512,0, Wo,512,0,
      qo2,512,0, cls + 71*512, 72*512, nullptr, 1000,512,512);
  gemm32_k<0,0,0><<<dim3(8,32,1),256,0,stream>>>(qo2,512,0, tproj,512,0,
      txt,512,0, nullptr,0, nullptr, 1000,512,512);
  rownorm_kernel<<<1000,256,0,stream>>>(txt);

  gemm32_k<1,0,1><<<dim3(16,8,1),256,0,stream>>>(img,512,0, txt,512,0,
      (float*)d_out,1000,0, nullptr,0, lscale, 256,1000,512);
}

// Round 7
// 223.632 us; speedup vs baseline: 1.7402x; 1.0379x over previous
//
#include <hip/hip_runtime.h>
#include <hip/hip_bf16.h>

#define DEV static __device__ __forceinline__

typedef __attribute__((ext_vector_type(8))) short bf16x8;
typedef __attribute__((ext_vector_type(4))) float f32x4;

DEV float wsum(float v) {
  v += __shfl_xor(v, 1);  v += __shfl_xor(v, 2);  v += __shfl_xor(v, 4);
  v += __shfl_xor(v, 8);  v += __shfl_xor(v, 16); v += __shfl_xor(v, 32);
  return v;
}
DEV float wmaxr(float v) {
  v = fmaxf(v, __shfl_xor(v, 1));  v = fmaxf(v, __shfl_xor(v, 2));
  v = fmaxf(v, __shfl_xor(v, 4));  v = fmaxf(v, __shfl_xor(v, 8));
  v = fmaxf(v, __shfl_xor(v, 16)); v = fmaxf(v, __shfl_xor(v, 32));
  return v;
}
DEV short f2bf(float x) {
  __hip_bfloat16 h = __float2bfloat16(x);
  return *reinterpret_cast<short*>(&h);
}

// Fold-reduce 8 per-lane values across 64 lanes -> full sum of head (lane&7).
DEV float fold8(const float v[8], int lane) {
  float w4[4];
#pragma unroll
  for (int j = 0; j < 4; ++j) {
    const float mine  = (lane & 1) ? v[2 * j + 1] : v[2 * j];
    const float other = (lane & 1) ? v[2 * j]     : v[2 * j + 1];
    w4[j] = mine + __shfl_xor(other, 1);
  }
  float u2[2];
#pragma unroll
  for (int j = 0; j < 2; ++j) {
    const float mine  = (lane & 2) ? w4[2 * j + 1] : w4[2 * j];
    const float other = (lane & 2) ? w4[2 * j]     : w4[2 * j + 1];
    u2[j] = mine + __shfl_xor(other, 2);
  }
  const float mine  = (lane & 4) ? u2[1] : u2[0];
  const float other = (lane & 4) ? u2[0] : u2[1];
  float z = mine + __shfl_xor(other, 4);
  z += __shfl_xor(z, 8); z += __shfl_xor(z, 16); z += __shfl_xor(z, 32);
  return z;
}

// All-gather: input = value of head (lane&7); out[j] = head j, all lanes.
DEV void gather8(float e, int lane, float out[8]) {
  const float t  = __shfl_xor(e, 1);
  const float lo1 = (lane & 1) ? t : e;
  const float hi1 = (lane & 1) ? e : t;
  const float t0 = __shfl_xor(lo1, 2), t1 = __shfl_xor(hi1, 2);
  const float a00 = (lane & 2) ? t0 : lo1;
  const float a01 = (lane & 2) ? t1 : hi1;
  const float a10 = (lane & 2) ? lo1 : t0;
  const float a11 = (lane & 2) ? hi1 : t1;
  const float s00 = __shfl_xor(a00, 4), s01 = __shfl_xor(a01, 4);
  const float s10 = __shfl_xor(a10, 4), s11 = __shfl_xor(a11, 4);
  out[0] = (lane & 4) ? s00 : a00;  out[1] = (lane & 4) ? s01 : a01;
  out[2] = (lane & 4) ? s10 : a10;  out[3] = (lane & 4) ? s11 : a11;
  out[4] = (lane & 4) ? a00 : s00;  out[5] = (lane & 4) ? a01 : s01;
  out[6] = (lane & 4) ? a10 : s10;  out[7] = (lane & 4) ? a11 : s11;
}

// ---------------------------------------------------------------------------
// bf16 MFMA GEMM: C[M,N] = A[M,K]@B[K,N] (+D). 64x64 tile, 4 waves (2x2),
// BK=32, f32 inputs converted to bf16 in LDS, f32 accumulation via
// v_mfma_f32_16x16x32_bf16. Frag layout: A row=lane&15, k=(lane>>4)*8+j;
// C/D col=lane&15, row=(lane>>4)*4+reg (m89-verified).
// ---------------------------------------------------------------------------
template <int ADDD>
__global__ __launch_bounds__(256) void gemm_mfma_k(
    const float* __restrict__ A, int lda,
    const float* __restrict__ B, int ldb,
    float* __restrict__ C, int ldc,
    const float* __restrict__ D, long long ldd,
    int M, int N, int K)
{
  const int m0 = blockIdx.y * 64, n0 = blockIdx.x * 64;
  const int tid = threadIdx.x;
  const int w = tid >> 6, lane = tid & 63;
  const int wr = w >> 1, wc = w & 1;
  __shared__ __attribute__((aligned(16))) short As[64][40];
  __shared__ __attribute__((aligned(16))) short Bs[64][40];
  f32x4 acc[2][2] = {};

  const int ar = tid >> 2, akc = (tid & 3) * 8;   // A: 64 rows x 32 k
  const int br = tid >> 3, bnc = (tid & 7) * 8;   // B: 32 k-rows x 64 cols
  const bool arv = (m0 + ar < M);
  const int rbase = wr * 32 + (lane & 15);
  const int cbase = wc * 32 + (lane & 15);
  const int kb = (lane >> 4) * 8;

  for (int k0 = 0; k0 < K; k0 += 32) {
    float4 a0 = make_float4(0.f, 0.f, 0.f, 0.f), a1 = a0;
    if (arv) {
      a0 = *(const float4*)(A + (size_t)(m0 + ar) * lda + k0 + akc);
      a1 = *(const float4*)(A + (size_t)(m0 + ar) * lda + k0 + akc + 4);
    }
    const float4 b0 = *(const float4*)(B + (size_t)(k0 + br) * ldb + n0 + bnc);
    const float4 b1 = *(const float4*)(B + (size_t)(k0 + br) * ldb + n0 + bnc + 4);
    __syncthreads();   // prev-tile frag reads done
    {
      bf16x8 av;
      av[0] = f2bf(a0.x); av[1] = f2bf(a0.y); av[2] = f2bf(a0.z); av[3] = f2bf(a0.w);
      av[4] = f2bf(a1.x); av[5] = f2bf(a1.y); av[6] = f2bf(a1.z); av[7] = f2bf(a1.w);
      *(bf16x8*)&As[ar][akc] = av;
      Bs[bnc + 0][br] = f2bf(b0.x); Bs[bnc + 1][br] = f2bf(b0.y);
      Bs[bnc + 2][br] = f2bf(b0.z); Bs[bnc + 3][br] = f2bf(b0.w);
      Bs[bnc + 4][br] = f2bf(b1.x); Bs[bnc + 5][br] = f2bf(b1.y);
      Bs[bnc + 6][br] = f2bf(b1.z); Bs[bnc + 7][br] = f2bf(b1.w);
    }
    __syncthreads();   // stage ready
    bf16x8 af0 = *(const bf16x8*)&As[rbase][kb];
    bf16x8 af1 = *(const bf16x8*)&As[rbase + 16][kb];
    bf16x8 bf0 = *(const bf16x8*)&Bs[cbase][kb];
    bf16x8 bf1 = *(const bf16x8*)&Bs[cbase + 16][kb];
    acc[0][0] = __builtin_amdgcn_mfma_f32_16x16x32_bf16(af0, bf0, acc[0][0], 0, 0, 0);
    acc[0][1] = __builtin_amdgcn_mfma_f32_16x16x32_bf16(af0, bf1, acc[0][1], 0, 0, 0);
    acc[1][0] = __builtin_amdgcn_mfma_f32_16x16x32_bf16(af1, bf0, acc[1][0], 0, 0, 0);
    acc[1][1] = __builtin_amdgcn_mfma_f32_16x16x32_bf16(af1, bf1, acc[1][1], 0, 0, 0);
  }

#pragma unroll
  for (int mi = 0; mi < 2; ++mi)
#pragma unroll
    for (int ni = 0; ni < 2; ++ni)
#pragma unroll
      for (int r = 0; r < 4; ++r) {
        const int row = m0 + wr * 32 + mi * 16 + (lane >> 4) * 4 + r;
        const int col = n0 + wc * 32 + ni * 16 + (lane & 15);
        if (row < M) {
          float v = acc[mi][ni][r];
          if (ADDD) v += D[(size_t)row * ldd + col];
          C[(size_t)row * ldc + col] = v;
        }
      }
}

// ---------------------------------------------------------------------------
// 64x64-tile f32 GEMM, double-buffered (wt-GEMM, K=64, grid 1024).
// ---------------------------------------------------------------------------
template <int TRANSB>
__global__ __launch_bounds__(256) void gemm_k(
    const float* __restrict__ A, int lda, long long bsA,
    const float* __restrict__ B, int ldb, long long bsB,
    float* __restrict__ C, int ldc, long long bsC,
    int M, int N, int K)
{
  A += (size_t)blockIdx.z * bsA;
  B += (size_t)blockIdx.z * bsB;
  const int m0 = blockIdx.y * 64, n0 = blockIdx.x * 64;
  const int tid = threadIdx.x;
  __shared__ __attribute__((aligned(16))) float As[2][16][68];
  __shared__ __attribute__((aligned(16))) float Bs[2][16][68];
  float acc[4][4] = {};
  const int ty = tid >> 4, tx = tid & 15;
  const int am = tid >> 2, ak = (tid & 3) * 4;
  const int bk = tid >> 4, bn = (tid & 15) * 4;
  const bool aval = (m0 + am < M);
  const bool bval = TRANSB ? (n0 + am < N) : (n0 + bn < N);

  float4 av, bv;
  auto gload = [&](int k0) {
    av = make_float4(0.f, 0.f, 0.f, 0.f);
    bv = make_float4(0.f, 0.f, 0.f, 0.f);
    if (aval) av = *(const float4*)(A + (size_t)(m0 + am) * lda + (k0 + ak));
    if (TRANSB) {
      if (bval) bv = *(const float4*)(B + (size_t)(n0 + am) * ldb + (k0 + ak));
    } else {
      if (bval) bv = *(const float4*)(B + (size_t)(k0 + bk) * ldb + (n0 + bn));
    }
  };
  auto sstore = [&](int buf) {
    As[buf][ak + 0][am] = av.x; As[buf][ak + 1][am] = av.y;
    As[buf][ak + 2][am] = av.z; As[buf][ak + 3][am] = av.w;
    if (TRANSB) {
      Bs[buf][ak + 0][am] = bv.x; Bs[buf][ak + 1][am] = bv.y;
      Bs[buf][ak + 2][am] = bv.z; Bs[buf][ak + 3][am] = bv.w;
    } else {
      *(float4*)&Bs[buf][bk][bn] = bv;
    }
  };

  const int nIt = K >> 4;
  gload(0); sstore(0);
  for (int it = 0; it < nIt; ++it) {
    __syncthreads();
    if (it + 1 < nIt) gload((it + 1) << 4);
    const int buf = it & 1;
#pragma unroll
    for (int kk = 0; kk < 16; ++kk) {
      const float4 a  = *(const float4*)&As[buf][kk][ty * 4];
      const float4 bq = *(const float4*)&Bs[buf][kk][tx * 4];
      acc[0][0] += a.x * bq.x; acc[0][1] += a.x * bq.y; acc[0][2] += a.x * bq.z; acc[0][3] += a.x * bq.w;
      acc[1][0] += a.y * bq.x; acc[1][1] += a.y * bq.y; acc[1][2] += a.y * bq.z; acc[1][3] += a.y * bq.w;
      acc[2][0] += a.z * bq.x; acc[2][1] += a.z * bq.y; acc[2][2] += a.z * bq.z; acc[2][3] += a.z * bq.w;
      acc[3][0] += a.w * bq.x; acc[3][1] += a.w * bq.y; acc[3][2] += a.w * bq.z; acc[3][3] += a.w * bq.w;
    }
    if (it + 1 < nIt) sstore((it + 1) & 1);
  }
  const size_t cbase = (size_t)blockIdx.z * (size_t)bsC;
#pragma unroll
  for (int i = 0; i < 4; ++i) {
    const int m = m0 + ty * 4 + i;
    if (m >= M) continue;
#pragma unroll
    for (int j = 0; j < 4; ++j) {
      const int nn = n0 + tx * 4 + j;
      if (nn < N) C[cbase + (size_t)m * ldc + nn] = acc[i][j];
    }
  }
}

// ---------------------------------------------------------------------------
// 32x64-tile f32 GEMM, double-buffered (img, q, O, logits GEMMs).
// ---------------------------------------------------------------------------
template <int TRANSB, int ADDD, int EXPALPHA>
__global__ __launch_bounds__(256) void gemm32_k(
    const float* __restrict__ A, int lda, long long bsA,
    const float* __restrict__ B, int ldb, long long bsB,
    float* __restrict__ C, int ldc, long long bsC,
    const float* __restrict__ D, long long ldd,
    const float* __restrict__ alpha_ptr,
    int M, int N, int K)
{
  A += (size_t)blockIdx.z * bsA;
  B += (size_t)blockIdx.z * bsB;
  const int m0 = blockIdx.y * 32, n0 = blockIdx.x * 64;
  const int tid = threadIdx.x;
  __shared__ __attribute__((aligned(16))) float As[2][16][36];
  __shared__ __attribute__((aligned(16))) float Bs[2][16][68];
  float acc[2][4] = {};
  const int ty = tid >> 4, tx = tid & 15;
  const int am = tid >> 3, ak = (tid & 7) * 2;
  const int bk = tid >> 4, bn = (tid & 15) * 4;
  const int bm = tid >> 2, bt = (tid & 3) * 4;
  const bool aval = (m0 + am < M);
  const bool bval = TRANSB ? (n0 + bm < N) : (n0 + bn < N);

  float2 av; float4 bv;
  auto gload = [&](int k0) {
    av = make_float2(0.f, 0.f);
    bv = make_float4(0.f, 0.f, 0.f, 0.f);
    if (aval) av = *(const float2*)(A + (size_t)(m0 + am) * lda + (k0 + ak));
    if (TRANSB) {
      if (bval) bv = *(const float4*)(B + (size_t)(n0 + bm) * ldb + (k0 + bt));
    } else {
      if (bval) bv = *(const float4*)(B + (size_t)(k0 + bk) * ldb + (n0 + bn));
    }
  };
  auto sstore = [&](int buf) {
    As[buf][ak][am] = av.x; As[buf][ak + 1][am] = av.y;
    if (TRANSB) {
      Bs[buf][bt + 0][bm] = bv.x; Bs[buf][bt + 1][bm] = bv.y;
      Bs[buf][bt + 2][bm] = bv.z; Bs[buf][bt + 3][bm] = bv.w;
    } else {
      *(float4*)&Bs[buf][bk][bn] = bv;
    }
  };

  const int nIt = K >> 4;
  gload(0); sstore(0);
  for (int it = 0; it < nIt; ++it) {
    __syncthreads();
    if (it + 1 < nIt) gload((it + 1) << 4);
    const int buf = it & 1;
#pragma unroll
    for (int kk = 0; kk < 16; ++kk) {
      const float2 a  = *(const float2*)&As[buf][kk][ty * 2];
      const float4 bq = *(const float4*)&Bs[buf][kk][tx * 4];
      acc[0][0] += a.x * bq.x; acc[0][1] += a.x * bq.y; acc[0][2] += a.x * bq.z; acc[0][3] += a.x * bq.w;
      acc[1][0] += a.y * bq.x; acc[1][1] += a.y * bq.y; acc[1][2] += a.y * bq.z; acc[1][3] += a.y * bq.w;
    }
    if (it + 1 < nIt) sstore((it + 1) & 1);
  }

  float alpha = 1.f;
  if (EXPALPHA) alpha = __expf(alpha_ptr[0]);
  const size_t cbase = (size_t)blockIdx.z * (size_t)bsC;
#pragma unroll
  for (int i = 0; i < 2; ++i) {
    const int m = m0 + ty * 2 + i;
    if (m >= M) continue;
#pragma unroll
    for (int j = 0; j < 4; ++j) {
      const int nn = n0 + tx * 4 + j;
      if (nn >= N) continue;
      float v = acc[i][j] * alpha;
      if (ADDD) v += D[(size_t)m * ldd + nn];
      C[cbase + (size_t)m * ldc + nn] = v;
    }
  }
}

__global__ __launch_bounds__(256) void rownorm_kernel(float* __restrict__ x)
{
  const int r = blockIdx.x, tid = threadIdx.x;
  float* row = x + (size_t)r * 512;
  float2 v = *(float2*)(row + tid * 2);
  float ss = v.x * v.x + v.y * v.y;
  ss = wsum(ss);
  __shared__ float s4[4];
  const int w = tid >> 6, lane = tid & 63;
  if (lane == 0) s4[w] = ss;
  __syncthreads();
  const float sc = rsqrtf(s4[0] + s4[1] + s4[2] + s4[3]);
  v.x *= sc; v.y *= sc;
  *(float2*)(row + tid * 2) = v;
}

__global__ __launch_bounds__(64) void lnlast_kernel(
    const float* __restrict__ cls, const float* __restrict__ g,
    const float* __restrict__ b, float* __restrict__ hl)
{
  const int n = blockIdx.x, lane = threadIdx.x;
  const float* src = cls + ((size_t)n * 72 + 71) * 512;
  float x[8];
#pragma unroll
  for (int i = 0; i < 8; ++i) x[i] = src[lane + 64 * i];
  float s = 0.f, ss = 0.f;
#pragma unroll
  for (int i = 0; i < 8; ++i) { s += x[i]; ss += x[i] * x[i]; }
  s = wsum(s); ss = wsum(ss);
  const float mean = s * (1.f / 512.f);
  const float rstd = rsqrtf(ss * (1.f / 512.f) - mean * mean + 1e-5f);
  float* dst = hl + (size_t)n * 512;
#pragma unroll
  for (int i = 0; i < 8; ++i) {
    const int j = lane + 64 * i;
    dst[j] = (x[i] - mean) * rstd * g[j] + b[j];
  }
}

// ---------------------------------------------------------------------------
// FUSED sweep v4: pair-row processing. Each wave handles 9 pairs (k, k+4) —
// identical row order/FP math as v3, but gw LDS reads shared across the pair
// (halved LDS traffic), two independent dependency chains (2x ILP), and
// pair-ahead global prefetch. 256 thr / 4 waves.
// ---------------------------------------------------------------------------
__global__ __launch_bounds__(256) void fused_sweep_kernel(
    const float* __restrict__ ctx, const float* __restrict__ cls,
    const float* __restrict__ g, const float* __restrict__ b,
    const float* __restrict__ wt, float* __restrict__ u_out)
{
  const int n = blockIdx.x, tid = threadIdx.x;
  const int w = tid >> 6, lane = tid & 63;
  __shared__ __attribute__((aligned(16))) float gw_s[8][512];  // wt->g*wt->A
  __shared__ __attribute__((aligned(16))) float g_s[512], b_s[512];
  __shared__ __attribute__((aligned(16))) float hctx[5][512];  // ctx -> h2
  __shared__ float sc_s[8][80];
  __shared__ float sc2_s[8][5];
  __shared__ float ah_s[8][5];
  __shared__ float wstatB[4][8], wstatL[4][8];
  __shared__ float attr_s[5];
  __shared__ float Sgw_l[8], bw_l[8];
  __shared__ float Bt_s[8], Lt_s[8], inv_s[8];
  __shared__ float e2_s[8][5];

  {
    const float4* wsrc = (const float4*)(wt + (size_t)n * 4096);
    float4* wdst = (float4*)&gw_s[0][0];
    for (int i = tid; i < 1024; i += 256) wdst[i] = wsrc[i];
    const float4* csrc = (const float4*)(ctx + (size_t)n * 2560);
    float4* cdst = (float4*)&hctx[0][0];
    for (int i = tid; i < 640; i += 256) cdst[i] = csrc[i];
    if (tid < 128) ((float4*)g_s)[tid] = ((const float4*)g)[tid];
    else ((float4*)b_s)[tid - 128] = ((const float4*)b)[tid - 128];
  }
  __syncthreads();

  // gw = g*wt (in place), Sgw = sum gw, bw = sum b*wt
  for (int hh = w; hh < 8; hh += 4) {
    float s1 = 0.f, s2 = 0.f;
#pragma unroll
    for (int i = 0; i < 8; ++i) {
      const int j = lane + 64 * i;
      const float wv = gw_s[hh][j];
      const float gv = wv * g_s[j];
      s1 += gv; s2 += wv * b_s[j];
      gw_s[hh][j] = gv;
    }
    s1 = wsum(s1); s2 = wsum(s2);
    if (lane == 0) { Sgw_l[hh] = s1; bw_l[hh] = s2; }
  }
  __syncthreads();
  const float sg_r  = Sgw_l[lane & 7];
  const float bw8_r = bw_l[lane & 7] * 0.125f;

  // ---- stage A: 5 unscaled ctx rows -> pass-1 scores
  for (int k = w; k < 5; k += 4) {
    float2 x2[4];
#pragma unroll
    for (int i = 0; i < 4; ++i)
      x2[i] = *(const float2*)&hctx[k][lane * 2 + 128 * i];
    float s = 0.f, ss = 0.f;
#pragma unroll
    for (int i = 0; i < 4; ++i) {
      s += x2[i].x + x2[i].y; ss += x2[i].x * x2[i].x + x2[i].y * x2[i].y;
    }
    float v8[8] = {};
#pragma unroll
    for (int hh = 0; hh < 8; ++hh)
#pragma unroll
      for (int i = 0; i < 4; ++i) {
        const float2 ww = *(const float2*)&gw_s[hh][lane * 2 + 128 * i];
        v8[hh] += x2[i].x * ww.x + x2[i].y * ww.y;
      }
    s = wsum(s); ss = wsum(ss);
    const float mean = s * (1.f / 512.f);
    const float rstd = rsqrtf(ss * (1.f / 512.f) - mean * mean + 1e-5f);
    const float z = fold8(v8, lane);
    const float zf = rstd * 0.125f * (z - mean * sg_r) + bw8_r;
    if (lane < 8) sc_s[lane][k] = zf;
  }

  // ---- stage B: 72 cls rows as 9 pairs/wave (rows w+8p, w+4+8p)
  float A[8][8];
#pragma unroll
  for (int hh = 0; hh < 8; ++hh)
#pragma unroll
    for (int i = 0; i < 8; ++i) A[hh][i] = 0.f;
  float B8[8] = {}, L8[8] = {};

  const float* base = cls + (size_t)n * 72 * 512;
  float2 xa[4], xb[4];
  {
    const float* sA = base + (size_t)w * 512;
    const float* sB = base + (size_t)(w + 4) * 512;
#pragma unroll
    for (int i = 0; i < 4; ++i) {
      xa[i] = *(const float2*)(sA + lane * 2 + 128 * i);
      xb[i] = *(const float2*)(sB + lane * 2 + 128 * i);
    }
  }
  for (int p = 0; p < 9; ++p) {
    float2 na[4], nb[4];
    const bool more = (p < 8);
    if (more) {
      const float* sA = base + (size_t)(w + 8 * (p + 1)) * 512;
      const float* sB = base + (size_t)(w + 4 + 8 * (p + 1)) * 512;
#pragma unroll
      for (int i = 0; i < 4; ++i) {
        na[i] = *(const float2*)(sA + lane * 2 + 128 * i);
        nb[i] = *(const float2*)(sB + lane * 2 + 128 * i);
      }
    }
    float sa = 0.f, ssa = 0.f, sb = 0.f, ssb = 0.f;
#pragma unroll
    for (int i = 0; i < 4; ++i) {
      sa += xa[i].x + xa[i].y; ssa += xa[i].x * xa[i].x + xa[i].y * xa[i].y;
      sb += xb[i].x + xb[i].y; ssb += xb[i].x * xb[i].x + xb[i].y * xb[i].y;
    }
    float v8a[8] = {}, v8b[8] = {};
#pragma unroll
    for (int hh = 0; hh < 8; ++hh)
#pragma unroll
      for (int i = 0; i < 4; ++i) {
        const float2 ww = *(const float2*)&gw_s[hh][lane * 2 + 128 * i];
        v8a[hh] += xa[i].x * ww.x + xa[i].y * ww.y;
        v8b[hh] += xb[i].x * ww.x + xb[i].y * ww.y;
      }
    sa = wsum(sa); ssa = wsum(ssa); sb = wsum(sb); ssb = wsum(ssb);
    const float meanA = sa * (1.f / 512.f);
    const float rstdA = rsqrtf(ssa * (1.f / 512.f) - meanA * meanA + 1e-5f);
    const float meanB = sb * (1.f / 512.f);
    const float rstdB = rsqrtf(ssb * (1.f / 512.f) - meanB * meanB + 1e-5f);
    const float za = fold8(v8a, lane);
    const float zb = fold8(v8b, lane);
    const float zfa = rstdA * 0.125f * (za - meanA * sg_r) + bw8_r;
    const float zfb = rstdB * 0.125f * (zb - meanB * sg_r) + bw8_r;
    const int kA = 5 + w + 8 * p;
    if (lane < 8) { sc_s[lane][kA] = zfa; sc_s[lane][kA + 4] = zfb; }
    const float eza = __expf(zfa);
    const float ezb = __expf(zfb);
    float esa[8], esb[8];
    gather8(eza, lane, esa);
    gather8(ezb, lane, esb);
#pragma unroll
    for (int hh = 0; hh < 8; ++hh) {
      const float erA = esa[hh] * rstdA;
      const float erB = esb[hh] * rstdB;
#pragma unroll
      for (int i = 0; i < 4; ++i) {
        A[hh][2 * i]     += erA * xa[i].x;
        A[hh][2 * i + 1] += erA * xa[i].y;
      }
      B8[hh] += erA * meanA;
      L8[hh] += esa[hh];
#pragma unroll
      for (int i = 0; i < 4; ++i) {
        A[hh][2 * i]     += erB * xb[i].x;
        A[hh][2 * i + 1] += erB * xb[i].y;
      }
      B8[hh] += erB * meanB;
      L8[hh] += esb[hh];
    }
    if (more)
#pragma unroll
      for (int i = 0; i < 4; ++i) { xa[i] = na[i]; xb[i] = nb[i]; }
  }
  if (lane == 0)
#pragma unroll
    for (int hh = 0; hh < 8; ++hh) {
      wstatB[w][hh] = B8[hh]; wstatL[w][hh] = L8[hh];
    }
  __syncthreads();

  // ---- pass-1 softmax over 77 -> head-mean of first 5 -> attr
  for (int hh = w; hh < 8; hh += 4) {
    const float v0 = sc_s[hh][lane];
    const float v1 = (lane + 64 < 77) ? sc_s[hh][lane + 64] : -1e30f;
    const float mx = wmaxr(fmaxf(v0, v1));
    const float e0 = __expf(v0 - mx);
    const float e1 = (lane + 64 < 77) ? __expf(v1 - mx) : 0.f;
    const float S = wsum(e0 + e1);
    if (lane < 5) ah_s[hh][lane] = e0 / S;
  }
  __syncthreads();
  if (tid == 0) {
    float m[5], mx = -1e30f;
#pragma unroll
    for (int p = 0; p < 5; ++p) {
      float acc = 0.f;
      for (int hh = 0; hh < 8; ++hh) acc += ah_s[hh][p];
      m[p] = acc * 0.125f;
      mx = fmaxf(mx, m[p]);
    }
    float e[5], S = 0.f;
#pragma unroll
    for (int p = 0; p < 5; ++p) { e[p] = __expf(m[p] - mx); S += e[p]; }
#pragma unroll
    for (int p = 0; p < 5; ++p) attr_s[p] = e[p] / S;
  }
  __syncthreads();

  // ---- stage C: scaled ctx rows -> h2 (into hctx) + scores sc2
  for (int k = w; k < 5; k += 4) {
    const float c = attr_s[k];
    float2 x2[4];
#pragma unroll
    for (int i = 0; i < 4; ++i) {
      x2[i] = *(const float2*)&hctx[k][lane * 2 + 128 * i];
      x2[i].x *= c; x2[i].y *= c;
    }
    float s = 0.f, ss = 0.f;
#pragma unroll
    for (int i = 0; i < 4; ++i) {
      s += x2[i].x + x2[i].y; ss += x2[i].x * x2[i].x + x2[i].y * x2[i].y;
    }
    float v8[8] = {};
#pragma unroll
    for (int hh = 0; hh < 8; ++hh)
#pragma unroll
      for (int i = 0; i < 4; ++i) {
        const float2 ww = *(const float2*)&gw_s[hh][lane * 2 + 128 * i];
        v8[hh] += x2[i].x * ww.x + x2[i].y * ww.y;
      }
    s = wsum(s); ss = wsum(ss);
    const float mean = s * (1.f / 512.f);
    const float rstd = rsqrtf(ss * (1.f / 512.f) - mean * mean + 1e-5f);
#pragma unroll
    for (int i = 0; i < 4; ++i) {
      const int j0 = lane * 2 + 128 * i;
      const float2 gg = *(const float2*)&g_s[j0];
      const float2 bb = *(const float2*)&b_s[j0];
      *(float2*)&hctx[k][j0] = make_float2(
          (x2[i].x - mean) * rstd * gg.x + bb.x,
          (x2[i].y - mean) * rstd * gg.y + bb.y);
    }
    const float z = fold8(v8, lane);
    const float zf = rstd * 0.125f * (z - mean * sg_r) + bw8_r;
    if (lane < 8) sc2_s[lane][k] = zf;
  }
  __syncthreads();   // gw_s dead as weights

  // ---- cross-wave A combine into gw_s region
  for (int wv = 0; wv < 4; ++wv) {
    if (w == wv) {
#pragma unroll
      for (int hh = 0; hh < 8; ++hh)
#pragma unroll
        for (int i = 0; i < 4; ++i) {
          float2* p = (float2*)&gw_s[hh][lane * 2 + 128 * i];
          const float2 a = make_float2(A[hh][2 * i], A[hh][2 * i + 1]);
          if (wv == 0) *p = a;
          else { float2 v = *p; v.x += a.x; v.y += a.y; *p = v; }
        }
    }
    __syncthreads();
  }

  if (tid < 8) {
    float Bt = 0.f, Lt = 0.f;
    for (int wv = 0; wv < 4; ++wv) { Bt += wstatB[wv][tid]; Lt += wstatL[wv][tid]; }
    float den = Lt;
#pragma unroll
    for (int k = 0; k < 5; ++k) {
      const float e = __expf(sc2_s[tid][k]);
      e2_s[tid][k] = e; den += e;
    }
    Bt_s[tid] = Bt; Lt_s[tid] = Lt; inv_s[tid] = 1.f / den;
  }
  __syncthreads();

  // ---- u[hh][j] = (g*(A-B) + b*L + sum_k e2*h2) / den
  float* dst = u_out + (size_t)n * 4096;
  for (int idx = tid; idx < 4096; idx += 256) {
    const int hh = idx >> 9, j = idx & 511;
    float v = (gw_s[hh][j] - Bt_s[hh]) * g_s[j] + Lt_s[hh] * b_s[j];
#pragma unroll
    for (int k = 0; k < 5; ++k) v += e2_s[hh][k] * hctx[k][j];
    dst[idx] = v * inv_s[hh];
  }
}

// ---------------------------------------------------------------------------
extern "C" void kernel_launch(void* const* d_in, const int* in_sizes, int n_in,
                              void* d_out, int out_size, void* d_ws, size_t ws_size,
                              hipStream_t stream)
{
  const float* images = (const float*)d_in[0];
  const float* W_img  = (const float*)d_in[1];
  const float* ctx    = (const float*)d_in[2];
  const float* cls    = (const float*)d_in[3];
  const float* ln_g   = (const float*)d_in[4];
  const float* ln_b   = (const float*)d_in[5];
  const float* Wq     = (const float*)d_in[6];
  const float* Wk     = (const float*)d_in[7];
  const float* Wv     = (const float*)d_in[8];
  const float* Wo     = (const float*)d_in[9];
  const float* tproj  = (const float*)d_in[10];
  const float* lscale = (const float*)d_in[11];

  float* ws   = (float*)d_ws;
  float* wtu  = ws;                 // wt -> u (in place) -> txt overlay
  float* img  = wtu + 4096000;
  float* hlO  = img + 131072;       // hl -> O
  float* qo2  = hlO + 512000;       // q  -> out2
  float* txt  = wtu;
  (void)in_sizes; (void)n_in; (void)out_size; (void)ws_size;

  gemm32_k<0,0,0><<<dim3(8,8,1),256,0,stream>>>(images,768,0, W_img,512,0,
      img,512,0, nullptr,0, nullptr, 256,512,768);
  rownorm_kernel<<<256,256,0,stream>>>(img);

  lnlast_kernel<<<1000,64,0,stream>>>(cls, ln_g, ln_b, hlO);
  gemm32_k<0,0,0><<<dim3(8,32,1),256,0,stream>>>(hlO,512,0, Wq,512,0,
      qo2,512,0, nullptr,0, nullptr, 1000,512,512);

  gemm_k<1><<<dim3(8,16,8),256,0,stream>>>(qo2,512,64, Wk,512,64,
      wtu,4096,512, 1000,512,64);

  fused_sweep_kernel<<<1000,256,0,stream>>>(ctx, cls, ln_g, ln_b, wtu, wtu);

  gemm32_k<0,0,0><<<dim3(1,32,8),256,0,stream>>>(wtu,4096,512, Wv,512,64,
      hlO,512,64, nullptr,0, nullptr, 1000,64,512);

  // out2 = cls_last + O @ Wo   (bf16 MFMA)
  gemm_mfma_k<1><<<dim3(8,16),256,0,stream>>>(hlO,512, Wo,512,
      qo2,512, cls + 71*512, 72*512, 1000,512,512);
  // txt = out2 @ text_proj     (bf16 MFMA)
  gemm_mfma_k<0><<<dim3(8,16),256,0,stream>>>(qo2,512, tproj,512,
      txt,512, nullptr,0, 1000,512,512);
  rownorm_kernel<<<1000,256,0,stream>>>(txt);

  gemm32_k<1,0,1><<<dim3(16,8,1),256,0,stream>>>(img,512,0, txt,512,0,
      (float*)d_out,1000,0, nullptr,0, lscale, 256,1000,512);
}

// Round 8
// 204.560 us; speedup vs baseline: 1.9025x; 1.0932x over previous
//
#include <hip/hip_runtime.h>
#include <hip/hip_bf16.h>

#define DEV static __device__ __forceinline__

typedef __attribute__((ext_vector_type(8))) short bf16x8;
typedef __attribute__((ext_vector_type(4))) float f32x4;

DEV float wsum(float v) {
  v += __shfl_xor(v, 1);  v += __shfl_xor(v, 2);  v += __shfl_xor(v, 4);
  v += __shfl_xor(v, 8);  v += __shfl_xor(v, 16); v += __shfl_xor(v, 32);
  return v;
}
DEV float wmaxr(float v) {
  v = fmaxf(v, __shfl_xor(v, 1));  v = fmaxf(v, __shfl_xor(v, 2));
  v = fmaxf(v, __shfl_xor(v, 4));  v = fmaxf(v, __shfl_xor(v, 8));
  v = fmaxf(v, __shfl_xor(v, 16)); v = fmaxf(v, __shfl_xor(v, 32));
  return v;
}
DEV short f2bf(float x) {
  __hip_bfloat16 h = __float2bfloat16(x);
  return *reinterpret_cast<short*>(&h);
}

// Fold-reduce 8 per-lane values across 64 lanes -> full sum of head (lane&7).
DEV float fold8(const float v[8], int lane) {
  float w4[4];
#pragma unroll
  for (int j = 0; j < 4; ++j) {
    const float mine  = (lane & 1) ? v[2 * j + 1] : v[2 * j];
    const float other = (lane & 1) ? v[2 * j]     : v[2 * j + 1];
    w4[j] = mine + __shfl_xor(other, 1);
  }
  float u2[2];
#pragma unroll
  for (int j = 0; j < 2; ++j) {
    const float mine  = (lane & 2) ? w4[2 * j + 1] : w4[2 * j];
    const float other = (lane & 2) ? w4[2 * j]     : w4[2 * j + 1];
    u2[j] = mine + __shfl_xor(other, 2);
  }
  const float mine  = (lane & 4) ? u2[1] : u2[0];
  const float other = (lane & 4) ? u2[0] : u2[1];
  float z = mine + __shfl_xor(other, 4);
  z += __shfl_xor(z, 8); z += __shfl_xor(z, 16); z += __shfl_xor(z, 32);
  return z;
}

// All-gather: input = value of head (lane&7); out[j] = head j, all lanes.
DEV void gather8(float e, int lane, float out[8]) {
  const float t  = __shfl_xor(e, 1);
  const float lo1 = (lane & 1) ? t : e;
  const float hi1 = (lane & 1) ? e : t;
  const float t0 = __shfl_xor(lo1, 2), t1 = __shfl_xor(hi1, 2);
  const float a00 = (lane & 2) ? t0 : lo1;
  const float a01 = (lane & 2) ? t1 : hi1;
  const float a10 = (lane & 2) ? lo1 : t0;
  const float a11 = (lane & 2) ? hi1 : t1;
  const float s00 = __shfl_xor(a00, 4), s01 = __shfl_xor(a01, 4);
  const float s10 = __shfl_xor(a10, 4), s11 = __shfl_xor(a11, 4);
  out[0] = (lane & 4) ? s00 : a00;  out[1] = (lane & 4) ? s01 : a01;
  out[2] = (lane & 4) ? s10 : a10;  out[3] = (lane & 4) ? s11 : a11;
  out[4] = (lane & 4) ? a00 : s00;  out[5] = (lane & 4) ? a01 : s01;
  out[6] = (lane & 4) ? a10 : s10;  out[7] = (lane & 4) ? a11 : s11;
}

// ---------------------------------------------------------------------------
// Unified bf16 MFMA GEMM. C[M,N] = A[M,K]@B (+D). 64x64 tile, 4 waves (2x2),
// BK=32, f32->bf16 staged in LDS, f32 accum (v_mfma_f32_16x16x32_bf16).
// TRANSB: B is [N,K] row-major (use B[n][k]). blockIdx.z batches via
// bsA/bsB/bsC element strides. Layout HW-validated in round 7 (passed).
// Requires: N multiple of 64 (grid-covered), K multiple of 32.
// ---------------------------------------------------------------------------
template <int TRANSB, int ADDD>
__global__ __launch_bounds__(256) void gemm_mfma_k(
    const float* __restrict__ A, int lda, long long bsA,
    const float* __restrict__ B, int ldb, long long bsB,
    float* __restrict__ C, int ldc, long long bsC,
    const float* __restrict__ D, long long ldd,
    int M, int N, int K)
{
  A += (size_t)blockIdx.z * bsA;
  B += (size_t)blockIdx.z * bsB;
  const int m0 = blockIdx.y * 64, n0 = blockIdx.x * 64;
  const int tid = threadIdx.x;
  const int w = tid >> 6, lane = tid & 63;
  const int wr = w >> 1, wc = w & 1;
  __shared__ __attribute__((aligned(16))) short As[64][40];
  __shared__ __attribute__((aligned(16))) short Bs[64][40];
  f32x4 acc[2][2] = {};

  const int ar = tid >> 2, akc = (tid & 3) * 8;   // 64 rows x 32 k (A, B^T)
  const int br = tid >> 3, bnc = (tid & 7) * 8;   // 32 k-rows x 64 cols (B)
  const bool arv = (m0 + ar < M);
  const int rbase = wr * 32 + (lane & 15);
  const int cbase = wc * 32 + (lane & 15);
  const int kb = (lane >> 4) * 8;

  for (int k0 = 0; k0 < K; k0 += 32) {
    float4 a0 = make_float4(0.f, 0.f, 0.f, 0.f), a1 = a0;
    if (arv) {
      a0 = *(const float4*)(A + (size_t)(m0 + ar) * lda + k0 + akc);
      a1 = *(const float4*)(A + (size_t)(m0 + ar) * lda + k0 + akc + 4);
    }
    float4 b0, b1;
    if (TRANSB) {
      b0 = *(const float4*)(B + (size_t)(n0 + ar) * ldb + k0 + akc);
      b1 = *(const float4*)(B + (size_t)(n0 + ar) * ldb + k0 + akc + 4);
    } else {
      b0 = *(const float4*)(B + (size_t)(k0 + br) * ldb + n0 + bnc);
      b1 = *(const float4*)(B + (size_t)(k0 + br) * ldb + n0 + bnc + 4);
    }
    __syncthreads();   // prev-tile frag reads done
    {
      bf16x8 av;
      av[0] = f2bf(a0.x); av[1] = f2bf(a0.y); av[2] = f2bf(a0.z); av[3] = f2bf(a0.w);
      av[4] = f2bf(a1.x); av[5] = f2bf(a1.y); av[6] = f2bf(a1.z); av[7] = f2bf(a1.w);
      *(bf16x8*)&As[ar][akc] = av;
      if (TRANSB) {
        bf16x8 bv;
        bv[0] = f2bf(b0.x); bv[1] = f2bf(b0.y); bv[2] = f2bf(b0.z); bv[3] = f2bf(b0.w);
        bv[4] = f2bf(b1.x); bv[5] = f2bf(b1.y); bv[6] = f2bf(b1.z); bv[7] = f2bf(b1.w);
        *(bf16x8*)&Bs[ar][akc] = bv;
      } else {
        Bs[bnc + 0][br] = f2bf(b0.x); Bs[bnc + 1][br] = f2bf(b0.y);
        Bs[bnc + 2][br] = f2bf(b0.z); Bs[bnc + 3][br] = f2bf(b0.w);
        Bs[bnc + 4][br] = f2bf(b1.x); Bs[bnc + 5][br] = f2bf(b1.y);
        Bs[bnc + 6][br] = f2bf(b1.z); Bs[bnc + 7][br] = f2bf(b1.w);
      }
    }
    __syncthreads();   // stage ready
    bf16x8 af0 = *(const bf16x8*)&As[rbase][kb];
    bf16x8 af1 = *(const bf16x8*)&As[rbase + 16][kb];
    bf16x8 bf0 = *(const bf16x8*)&Bs[cbase][kb];
    bf16x8 bf1 = *(const bf16x8*)&Bs[cbase + 16][kb];
    acc[0][0] = __builtin_amdgcn_mfma_f32_16x16x32_bf16(af0, bf0, acc[0][0], 0, 0, 0);
    acc[0][1] = __builtin_amdgcn_mfma_f32_16x16x32_bf16(af0, bf1, acc[0][1], 0, 0, 0);
    acc[1][0] = __builtin_amdgcn_mfma_f32_16x16x32_bf16(af1, bf0, acc[1][0], 0, 0, 0);
    acc[1][1] = __builtin_amdgcn_mfma_f32_16x16x32_bf16(af1, bf1, acc[1][1], 0, 0, 0);
  }

  const size_t cbase2 = (size_t)blockIdx.z * (size_t)bsC;
#pragma unroll
  for (int mi = 0; mi < 2; ++mi)
#pragma unroll
    for (int ni = 0; ni < 2; ++ni)
#pragma unroll
      for (int r = 0; r < 4; ++r) {
        const int row = m0 + wr * 32 + mi * 16 + (lane >> 4) * 4 + r;
        const int col = n0 + wc * 32 + ni * 16 + (lane & 15);
        if (row < M) {
          float v = acc[mi][ni][r];
          if (ADDD) v += D[(size_t)row * ldd + col];
          C[cbase2 + (size_t)row * ldc + col] = v;
        }
      }
}

// ---------------------------------------------------------------------------
// 32x64-tile f32 GEMM, double-buffered (logits GEMM only — kept f32 since it
// writes d_out directly with no downstream renormalization).
// ---------------------------------------------------------------------------
template <int TRANSB, int ADDD, int EXPALPHA>
__global__ __launch_bounds__(256) void gemm32_k(
    const float* __restrict__ A, int lda, long long bsA,
    const float* __restrict__ B, int ldb, long long bsB,
    float* __restrict__ C, int ldc, long long bsC,
    const float* __restrict__ D, long long ldd,
    const float* __restrict__ alpha_ptr,
    int M, int N, int K)
{
  A += (size_t)blockIdx.z * bsA;
  B += (size_t)blockIdx.z * bsB;
  const int m0 = blockIdx.y * 32, n0 = blockIdx.x * 64;
  const int tid = threadIdx.x;
  __shared__ __attribute__((aligned(16))) float As[2][16][36];
  __shared__ __attribute__((aligned(16))) float Bs[2][16][68];
  float acc[2][4] = {};
  const int ty = tid >> 4, tx = tid & 15;
  const int am = tid >> 3, ak = (tid & 7) * 2;
  const int bk = tid >> 4, bn = (tid & 15) * 4;
  const int bm = tid >> 2, bt = (tid & 3) * 4;
  const bool aval = (m0 + am < M);
  const bool bval = TRANSB ? (n0 + bm < N) : (n0 + bn < N);

  float2 av; float4 bv;
  auto gload = [&](int k0) {
    av = make_float2(0.f, 0.f);
    bv = make_float4(0.f, 0.f, 0.f, 0.f);
    if (aval) av = *(const float2*)(A + (size_t)(m0 + am) * lda + (k0 + ak));
    if (TRANSB) {
      if (bval) bv = *(const float4*)(B + (size_t)(n0 + bm) * ldb + (k0 + bt));
    } else {
      if (bval) bv = *(const float4*)(B + (size_t)(k0 + bk) * ldb + (n0 + bn));
    }
  };
  auto sstore = [&](int buf) {
    As[buf][ak][am] = av.x; As[buf][ak + 1][am] = av.y;
    if (TRANSB) {
      Bs[buf][bt + 0][bm] = bv.x; Bs[buf][bt + 1][bm] = bv.y;
      Bs[buf][bt + 2][bm] = bv.z; Bs[buf][bt + 3][bm] = bv.w;
    } else {
      *(float4*)&Bs[buf][bk][bn] = bv;
    }
  };

  const int nIt = K >> 4;
  gload(0); sstore(0);
  for (int it = 0; it < nIt; ++it) {
    __syncthreads();
    if (it + 1 < nIt) gload((it + 1) << 4);
    const int buf = it & 1;
#pragma unroll
    for (int kk = 0; kk < 16; ++kk) {
      const float2 a  = *(const float2*)&As[buf][kk][ty * 2];
      const float4 bq = *(const float4*)&Bs[buf][kk][tx * 4];
      acc[0][0] += a.x * bq.x; acc[0][1] += a.x * bq.y; acc[0][2] += a.x * bq.z; acc[0][3] += a.x * bq.w;
      acc[1][0] += a.y * bq.x; acc[1][1] += a.y * bq.y; acc[1][2] += a.y * bq.z; acc[1][3] += a.y * bq.w;
    }
    if (it + 1 < nIt) sstore((it + 1) & 1);
  }

  float alpha = 1.f;
  if (EXPALPHA) alpha = __expf(alpha_ptr[0]);
  const size_t cbase = (size_t)blockIdx.z * (size_t)bsC;
#pragma unroll
  for (int i = 0; i < 2; ++i) {
    const int m = m0 + ty * 2 + i;
    if (m >= M) continue;
#pragma unroll
    for (int j = 0; j < 4; ++j) {
      const int nn = n0 + tx * 4 + j;
      if (nn >= N) continue;
      float v = acc[i][j] * alpha;
      if (ADDD) v += D[(size_t)m * ldd + nn];
      C[cbase + (size_t)m * ldc + nn] = v;
    }
  }
}

__global__ __launch_bounds__(256) void rownorm_kernel(float* __restrict__ x)
{
  const int r = blockIdx.x, tid = threadIdx.x;
  float* row = x + (size_t)r * 512;
  float2 v = *(float2*)(row + tid * 2);
  float ss = v.x * v.x + v.y * v.y;
  ss = wsum(ss);
  __shared__ float s4[4];
  const int w = tid >> 6, lane = tid & 63;
  if (lane == 0) s4[w] = ss;
  __syncthreads();
  const float sc = rsqrtf(s4[0] + s4[1] + s4[2] + s4[3]);
  v.x *= sc; v.y *= sc;
  *(float2*)(row + tid * 2) = v;
}

__global__ __launch_bounds__(64) void lnlast_kernel(
    const float* __restrict__ cls, const float* __restrict__ g,
    const float* __restrict__ b, float* __restrict__ hl)
{
  const int n = blockIdx.x, lane = threadIdx.x;
  const float* src = cls + ((size_t)n * 72 + 71) * 512;
  float x[8];
#pragma unroll
  for (int i = 0; i < 8; ++i) x[i] = src[lane + 64 * i];
  float s = 0.f, ss = 0.f;
#pragma unroll
  for (int i = 0; i < 8; ++i) { s += x[i]; ss += x[i] * x[i]; }
  s = wsum(s); ss = wsum(ss);
  const float mean = s * (1.f / 512.f);
  const float rstd = rsqrtf(ss * (1.f / 512.f) - mean * mean + 1e-5f);
  float* dst = hl + (size_t)n * 512;
#pragma unroll
  for (int i = 0; i < 8; ++i) {
    const int j = lane + 64 * i;
    dst[j] = (x[i] - mean) * rstd * g[j] + b[j];
  }
}

// ---------------------------------------------------------------------------
// FUSED sweep v4 (unchanged from round 7; 90 us, known-good).
// ---------------------------------------------------------------------------
__global__ __launch_bounds__(256) void fused_sweep_kernel(
    const float* __restrict__ ctx, const float* __restrict__ cls,
    const float* __restrict__ g, const float* __restrict__ b,
    const float* __restrict__ wt, float* __restrict__ u_out)
{
  const int n = blockIdx.x, tid = threadIdx.x;
  const int w = tid >> 6, lane = tid & 63;
  __shared__ __attribute__((aligned(16))) float gw_s[8][512];
  __shared__ __attribute__((aligned(16))) float g_s[512], b_s[512];
  __shared__ __attribute__((aligned(16))) float hctx[5][512];
  __shared__ float sc_s[8][80];
  __shared__ float sc2_s[8][5];
  __shared__ float ah_s[8][5];
  __shared__ float wstatB[4][8], wstatL[4][8];
  __shared__ float attr_s[5];
  __shared__ float Sgw_l[8], bw_l[8];
  __shared__ float Bt_s[8], Lt_s[8], inv_s[8];
  __shared__ float e2_s[8][5];

  {
    const float4* wsrc = (const float4*)(wt + (size_t)n * 4096);
    float4* wdst = (float4*)&gw_s[0][0];
    for (int i = tid; i < 1024; i += 256) wdst[i] = wsrc[i];
    const float4* csrc = (const float4*)(ctx + (size_t)n * 2560);
    float4* cdst = (float4*)&hctx[0][0];
    for (int i = tid; i < 640; i += 256) cdst[i] = csrc[i];
    if (tid < 128) ((float4*)g_s)[tid] = ((const float4*)g)[tid];
    else ((float4*)b_s)[tid - 128] = ((const float4*)b)[tid - 128];
  }
  __syncthreads();

  for (int hh = w; hh < 8; hh += 4) {
    float s1 = 0.f, s2 = 0.f;
#pragma unroll
    for (int i = 0; i < 8; ++i) {
      const int j = lane + 64 * i;
      const float wv = gw_s[hh][j];
      const float gv = wv * g_s[j];
      s1 += gv; s2 += wv * b_s[j];
      gw_s[hh][j] = gv;
    }
    s1 = wsum(s1); s2 = wsum(s2);
    if (lane == 0) { Sgw_l[hh] = s1; bw_l[hh] = s2; }
  }
  __syncthreads();
  const float sg_r  = Sgw_l[lane & 7];
  const float bw8_r = bw_l[lane & 7] * 0.125f;

  for (int k = w; k < 5; k += 4) {
    float2 x2[4];
#pragma unroll
    for (int i = 0; i < 4; ++i)
      x2[i] = *(const float2*)&hctx[k][lane * 2 + 128 * i];
    float s = 0.f, ss = 0.f;
#pragma unroll
    for (int i = 0; i < 4; ++i) {
      s += x2[i].x + x2[i].y; ss += x2[i].x * x2[i].x + x2[i].y * x2[i].y;
    }
    float v8[8] = {};
#pragma unroll
    for (int hh = 0; hh < 8; ++hh)
#pragma unroll
      for (int i = 0; i < 4; ++i) {
        const float2 ww = *(const float2*)&gw_s[hh][lane * 2 + 128 * i];
        v8[hh] += x2[i].x * ww.x + x2[i].y * ww.y;
      }
    s = wsum(s); ss = wsum(ss);
    const float mean = s * (1.f / 512.f);
    const float rstd = rsqrtf(ss * (1.f / 512.f) - mean * mean + 1e-5f);
    const float z = fold8(v8, lane);
    const float zf = rstd * 0.125f * (z - mean * sg_r) + bw8_r;
    if (lane < 8) sc_s[lane][k] = zf;
  }

  float A[8][8];
#pragma unroll
  for (int hh = 0; hh < 8; ++hh)
#pragma unroll
    for (int i = 0; i < 8; ++i) A[hh][i] = 0.f;
  float B8[8] = {}, L8[8] = {};

  const float* base = cls + (size_t)n * 72 * 512;
  float2 xa[4], xb[4];
  {
    const float* sA = base + (size_t)w * 512;
    const float* sB = base + (size_t)(w + 4) * 512;
#pragma unroll
    for (int i = 0; i < 4; ++i) {
      xa[i] = *(const float2*)(sA + lane * 2 + 128 * i);
      xb[i] = *(const float2*)(sB + lane * 2 + 128 * i);
    }
  }
  for (int p = 0; p < 9; ++p) {
    float2 na[4], nb[4];
    const bool more = (p < 8);
    if (more) {
      const float* sA = base + (size_t)(w + 8 * (p + 1)) * 512;
      const float* sB = base + (size_t)(w + 4 + 8 * (p + 1)) * 512;
#pragma unroll
      for (int i = 0; i < 4; ++i) {
        na[i] = *(const float2*)(sA + lane * 2 + 128 * i);
        nb[i] = *(const float2*)(sB + lane * 2 + 128 * i);
      }
    }
    float sa = 0.f, ssa = 0.f, sb = 0.f, ssb = 0.f;
#pragma unroll
    for (int i = 0; i < 4; ++i) {
      sa += xa[i].x + xa[i].y; ssa += xa[i].x * xa[i].x + xa[i].y * xa[i].y;
      sb += xb[i].x + xb[i].y; ssb += xb[i].x * xb[i].x + xb[i].y * xb[i].y;
    }
    float v8a[8] = {}, v8b[8] = {};
#pragma unroll
    for (int hh = 0; hh < 8; ++hh)
#pragma unroll
      for (int i = 0; i < 4; ++i) {
        const float2 ww = *(const float2*)&gw_s[hh][lane * 2 + 128 * i];
        v8a[hh] += xa[i].x * ww.x + xa[i].y * ww.y;
        v8b[hh] += xb[i].x * ww.x + xb[i].y * ww.y;
      }
    sa = wsum(sa); ssa = wsum(ssa); sb = wsum(sb); ssb = wsum(ssb);
    const float meanA = sa * (1.f / 512.f);
    const float rstdA = rsqrtf(ssa * (1.f / 512.f) - meanA * meanA + 1e-5f);
    const float meanB = sb * (1.f / 512.f);
    const float rstdB = rsqrtf(ssb * (1.f / 512.f) - meanB * meanB + 1e-5f);
    const float za = fold8(v8a, lane);
    const float zb = fold8(v8b, lane);
    const float zfa = rstdA * 0.125f * (za - meanA * sg_r) + bw8_r;
    const float zfb = rstdB * 0.125f * (zb - meanB * sg_r) + bw8_r;
    const int kA = 5 + w + 8 * p;
    if (lane < 8) { sc_s[lane][kA] = zfa; sc_s[lane][kA + 4] = zfb; }
    const float eza = __expf(zfa);
    const float ezb = __expf(zfb);
    float esa[8], esb[8];
    gather8(eza, lane, esa);
    gather8(ezb, lane, esb);
#pragma unroll
    for (int hh = 0; hh < 8; ++hh) {
      const float erA = esa[hh] * rstdA;
      const float erB = esb[hh] * rstdB;
#pragma unroll
      for (int i = 0; i < 4; ++i) {
        A[hh][2 * i]     += erA * xa[i].x;
        A[hh][2 * i + 1] += erA * xa[i].y;
      }
      B8[hh] += erA * meanA;
      L8[hh] += esa[hh];
#pragma unroll
      for (int i = 0; i < 4; ++i) {
        A[hh][2 * i]     += erB * xb[i].x;
        A[hh][2 * i + 1] += erB * xb[i].y;
      }
      B8[hh] += erB * meanB;
      L8[hh] += esb[hh];
    }
    if (more)
#pragma unroll
      for (int i = 0; i < 4; ++i) { xa[i] = na[i]; xb[i] = nb[i]; }
  }
  if (lane == 0)
#pragma unroll
    for (int hh = 0; hh < 8; ++hh) {
      wstatB[w][hh] = B8[hh]; wstatL[w][hh] = L8[hh];
    }
  __syncthreads();

  for (int hh = w; hh < 8; hh += 4) {
    const float v0 = sc_s[hh][lane];
    const float v1 = (lane + 64 < 77) ? sc_s[hh][lane + 64] : -1e30f;
    const float mx = wmaxr(fmaxf(v0, v1));
    const float e0 = __expf(v0 - mx);
    const float e1 = (lane + 64 < 77) ? __expf(v1 - mx) : 0.f;
    const float S = wsum(e0 + e1);
    if (lane < 5) ah_s[hh][lane] = e0 / S;
  }
  __syncthreads();
  if (tid == 0) {
    float m[5], mx = -1e30f;
#pragma unroll
    for (int p = 0; p < 5; ++p) {
      float acc = 0.f;
      for (int hh = 0; hh < 8; ++hh) acc += ah_s[hh][p];
      m[p] = acc * 0.125f;
      mx = fmaxf(mx, m[p]);
    }
    float e[5], S = 0.f;
#pragma unroll
    for (int p = 0; p < 5; ++p) { e[p] = __expf(m[p] - mx); S += e[p]; }
#pragma unroll
    for (int p = 0; p < 5; ++p) attr_s[p] = e[p] / S;
  }
  __syncthreads();

  for (int k = w; k < 5; k += 4) {
    const float c = attr_s[k];
    float2 x2[4];
#pragma unroll
    for (int i = 0; i < 4; ++i) {
      x2[i] = *(const float2*)&hctx[k][lane * 2 + 128 * i];
      x2[i].x *= c; x2[i].y *= c;
    }
    float s = 0.f, ss = 0.f;
#pragma unroll
    for (int i = 0; i < 4; ++i) {
      s += x2[i].x + x2[i].y; ss += x2[i].x * x2[i].x + x2[i].y * x2[i].y;
    }
    float v8[8] = {};
#pragma unroll
    for (int hh = 0; hh < 8; ++hh)
#pragma unroll
      for (int i = 0; i < 4; ++i) {
        const float2 ww = *(const float2*)&gw_s[hh][lane * 2 + 128 * i];
        v8[hh] += x2[i].x * ww.x + x2[i].y * ww.y;
      }
    s = wsum(s); ss = wsum(ss);
    const float mean = s * (1.f / 512.f);
    const float rstd = rsqrtf(ss * (1.f / 512.f) - mean * mean + 1e-5f);
#pragma unroll
    for (int i = 0; i < 4; ++i) {
      const int j0 = lane * 2 + 128 * i;
      const float2 gg = *(const float2*)&g_s[j0];
      const float2 bb = *(const float2*)&b_s[j0];
      *(float2*)&hctx[k][j0] = make_float2(
          (x2[i].x - mean) * rstd * gg.x + bb.x,
          (x2[i].y - mean) * rstd * gg.y + bb.y);
    }
    const float z = fold8(v8, lane);
    const float zf = rstd * 0.125f * (z - mean * sg_r) + bw8_r;
    if (lane < 8) sc2_s[lane][k] = zf;
  }
  __syncthreads();

  for (int wv = 0; wv < 4; ++wv) {
    if (w == wv) {
#pragma unroll
      for (int hh = 0; hh < 8; ++hh)
#pragma unroll
        for (int i = 0; i < 4; ++i) {
          float2* p = (float2*)&gw_s[hh][lane * 2 + 128 * i];
          const float2 a = make_float2(A[hh][2 * i], A[hh][2 * i + 1]);
          if (wv == 0) *p = a;
          else { float2 v = *p; v.x += a.x; v.y += a.y; *p = v; }
        }
    }
    __syncthreads();
  }

  if (tid < 8) {
    float Bt = 0.f, Lt = 0.f;
    for (int wv = 0; wv < 4; ++wv) { Bt += wstatB[wv][tid]; Lt += wstatL[wv][tid]; }
    float den = Lt;
#pragma unroll
    for (int k = 0; k < 5; ++k) {
      const float e = __expf(sc2_s[tid][k]);
      e2_s[tid][k] = e; den += e;
    }
    Bt_s[tid] = Bt; Lt_s[tid] = Lt; inv_s[tid] = 1.f / den;
  }
  __syncthreads();

  float* dst = u_out + (size_t)n * 4096;
  for (int idx = tid; idx < 4096; idx += 256) {
    const int hh = idx >> 9, j = idx & 511;
    float v = (gw_s[hh][j] - Bt_s[hh]) * g_s[j] + Lt_s[hh] * b_s[j];
#pragma unroll
    for (int k = 0; k < 5; ++k) v += e2_s[hh][k] * hctx[k][j];
    dst[idx] = v * inv_s[hh];
  }
}

// ---------------------------------------------------------------------------
extern "C" void kernel_launch(void* const* d_in, const int* in_sizes, int n_in,
                              void* d_out, int out_size, void* d_ws, size_t ws_size,
                              hipStream_t stream)
{
  const float* images = (const float*)d_in[0];
  const float* W_img  = (const float*)d_in[1];
  const float* ctx    = (const float*)d_in[2];
  const float* cls    = (const float*)d_in[3];
  const float* ln_g   = (const float*)d_in[4];
  const float* ln_b   = (const float*)d_in[5];
  const float* Wq     = (const float*)d_in[6];
  const float* Wk     = (const float*)d_in[7];
  const float* Wv     = (const float*)d_in[8];
  const float* Wo     = (const float*)d_in[9];
  const float* tproj  = (const float*)d_in[10];
  const float* lscale = (const float*)d_in[11];

  float* ws   = (float*)d_ws;
  float* wtu  = ws;                 // wt -> u (in place) -> txt overlay
  float* img  = wtu + 4096000;
  float* hlO  = img + 131072;       // hl -> O
  float* qo2  = hlO + 512000;       // q  -> out2
  float* txt  = wtu;
  (void)in_sizes; (void)n_in; (void)out_size; (void)ws_size;

  // 1) image embedding (bf16 MFMA) + L2 norm
  gemm_mfma_k<0,0><<<dim3(8,4,1),256,0,stream>>>(images,768,0, W_img,512,0,
      img,512,0, nullptr,0, 256,512,768);
  rownorm_kernel<<<256,256,0,stream>>>(img);

  // 2) q = LN(last row) @ Wq  (bf16 MFMA)
  lnlast_kernel<<<1000,64,0,stream>>>(cls, ln_g, ln_b, hlO);
  gemm_mfma_k<0,0><<<dim3(8,16,1),256,0,stream>>>(hlO,512,0, Wq,512,0,
      qo2,512,0, nullptr,0, 1000,512,512);

  // 3) wt[n][h][j] = q[n][h.] @ Wk[j][h.]^T  (bf16 MFMA, TRANSB, batched)
  gemm_mfma_k<1,0><<<dim3(8,16,8),256,0,stream>>>(qo2,512,64, Wk,512,64,
      wtu,4096,512, nullptr,0, 1000,512,64);

  // 4+5) fused pass1+pass2 sweep -> u[n][8][512] (in place over wt)
  fused_sweep_kernel<<<1000,256,0,stream>>>(ctx, cls, ln_g, ln_b, wtu, wtu);

  // 6) O[n][h*64+c] = u[n][h] @ Wv[:,h*64+c]  (bf16 MFMA, batched)
  gemm_mfma_k<0,0><<<dim3(1,16,8),256,0,stream>>>(wtu,4096,512, Wv,512,64,
      hlO,512,64, nullptr,0, 1000,64,512);

  // 7) out2 = cls_last + O @ Wo ; txt = out2 @ text_proj  (bf16 MFMA)
  gemm_mfma_k<0,1><<<dim3(8,16,1),256,0,stream>>>(hlO,512,0, Wo,512,0,
      qo2,512,0, cls + 71*512, 72*512, 1000,512,512);
  gemm_mfma_k<0,0><<<dim3(8,16,1),256,0,stream>>>(qo2,512,0, tproj,512,0,
      txt,512,0, nullptr,0, 1000,512,512);
  rownorm_kernel<<<1000,256,0,stream>>>(txt);

  // 8) logits = exp(ls) * img @ txt^T  (f32 — direct output, keep precision)
  gemm32_k<1,0,1><<<dim3(16,8,1),256,0,stream>>>(img,512,0, txt,512,0,
      (float*)d_out,1000,0, nullptr,0, lscale, 256,1000,512);
}

// Round 9
// 204.119 us; speedup vs baseline: 1.9066x; 1.0022x over previous
//
#include <hip/hip_runtime.h>
#include <hip/hip_bf16.h>

#define DEV static __device__ __forceinline__

typedef __attribute__((ext_vector_type(8))) short bf16x8;
typedef __attribute__((ext_vector_type(4))) float f32x4;

DEV float wsum(float v) {
  v += __shfl_xor(v, 1);  v += __shfl_xor(v, 2);  v += __shfl_xor(v, 4);
  v += __shfl_xor(v, 8);  v += __shfl_xor(v, 16); v += __shfl_xor(v, 32);
  return v;
}
DEV float wmaxr(float v) {
  v = fmaxf(v, __shfl_xor(v, 1));  v = fmaxf(v, __shfl_xor(v, 2));
  v = fmaxf(v, __shfl_xor(v, 4));  v = fmaxf(v, __shfl_xor(v, 8));
  v = fmaxf(v, __shfl_xor(v, 16)); v = fmaxf(v, __shfl_xor(v, 32));
  return v;
}
DEV short f2bf(float x) {
  __hip_bfloat16 h = __float2bfloat16(x);
  return *reinterpret_cast<short*>(&h);
}

// Fold-reduce 8 per-lane values across 64 lanes -> full sum of head (lane&7).
DEV float fold8(const float v[8], int lane) {
  float w4[4];
#pragma unroll
  for (int j = 0; j < 4; ++j) {
    const float mine  = (lane & 1) ? v[2 * j + 1] : v[2 * j];
    const float other = (lane & 1) ? v[2 * j]     : v[2 * j + 1];
    w4[j] = mine + __shfl_xor(other, 1);
  }
  float u2[2];
#pragma unroll
  for (int j = 0; j < 2; ++j) {
    const float mine  = (lane & 2) ? w4[2 * j + 1] : w4[2 * j];
    const float other = (lane & 2) ? w4[2 * j]     : w4[2 * j + 1];
    u2[j] = mine + __shfl_xor(other, 2);
  }
  const float mine  = (lane & 4) ? u2[1] : u2[0];
  const float other = (lane & 4) ? u2[0] : u2[1];
  float z = mine + __shfl_xor(other, 4);
  z += __shfl_xor(z, 8); z += __shfl_xor(z, 16); z += __shfl_xor(z, 32);
  return z;
}

// ---------------------------------------------------------------------------
// Unified bf16 MFMA GEMM (HW-validated rounds 7/8). C = A@B (+D).
// 64x64 tile, 4 waves, BK=32, f32->bf16 LDS staging, f32 accum.
// ---------------------------------------------------------------------------
template <int TRANSB, int ADDD>
__global__ __launch_bounds__(256) void gemm_mfma_k(
    const float* __restrict__ A, int lda, long long bsA,
    const float* __restrict__ B, int ldb, long long bsB,
    float* __restrict__ C, int ldc, long long bsC,
    const float* __restrict__ D, long long ldd,
    int M, int N, int K)
{
  A += (size_t)blockIdx.z * bsA;
  B += (size_t)blockIdx.z * bsB;
  const int m0 = blockIdx.y * 64, n0 = blockIdx.x * 64;
  const int tid = threadIdx.x;
  const int w = tid >> 6, lane = tid & 63;
  const int wr = w >> 1, wc = w & 1;
  __shared__ __attribute__((aligned(16))) short As[64][40];
  __shared__ __attribute__((aligned(16))) short Bs[64][40];
  f32x4 acc[2][2] = {};

  const int ar = tid >> 2, akc = (tid & 3) * 8;
  const int br = tid >> 3, bnc = (tid & 7) * 8;
  const bool arv = (m0 + ar < M);
  const int rbase = wr * 32 + (lane & 15);
  const int cbase = wc * 32 + (lane & 15);
  const int kb = (lane >> 4) * 8;

  for (int k0 = 0; k0 < K; k0 += 32) {
    float4 a0 = make_float4(0.f, 0.f, 0.f, 0.f), a1 = a0;
    if (arv) {
      a0 = *(const float4*)(A + (size_t)(m0 + ar) * lda + k0 + akc);
      a1 = *(const float4*)(A + (size_t)(m0 + ar) * lda + k0 + akc + 4);
    }
    float4 b0, b1;
    if (TRANSB) {
      b0 = *(const float4*)(B + (size_t)(n0 + ar) * ldb + k0 + akc);
      b1 = *(const float4*)(B + (size_t)(n0 + ar) * ldb + k0 + akc + 4);
    } else {
      b0 = *(const float4*)(B + (size_t)(k0 + br) * ldb + n0 + bnc);
      b1 = *(const float4*)(B + (size_t)(k0 + br) * ldb + n0 + bnc + 4);
    }
    __syncthreads();
    {
      bf16x8 av;
      av[0] = f2bf(a0.x); av[1] = f2bf(a0.y); av[2] = f2bf(a0.z); av[3] = f2bf(a0.w);
      av[4] = f2bf(a1.x); av[5] = f2bf(a1.y); av[6] = f2bf(a1.z); av[7] = f2bf(a1.w);
      *(bf16x8*)&As[ar][akc] = av;
      if (TRANSB) {
        bf16x8 bv;
        bv[0] = f2bf(b0.x); bv[1] = f2bf(b0.y); bv[2] = f2bf(b0.z); bv[3] = f2bf(b0.w);
        bv[4] = f2bf(b1.x); bv[5] = f2bf(b1.y); bv[6] = f2bf(b1.z); bv[7] = f2bf(b1.w);
        *(bf16x8*)&Bs[ar][akc] = bv;
      } else {
        Bs[bnc + 0][br] = f2bf(b0.x); Bs[bnc + 1][br] = f2bf(b0.y);
        Bs[bnc + 2][br] = f2bf(b0.z); Bs[bnc + 3][br] = f2bf(b0.w);
        Bs[bnc + 4][br] = f2bf(b1.x); Bs[bnc + 5][br] = f2bf(b1.y);
        Bs[bnc + 6][br] = f2bf(b1.z); Bs[bnc + 7][br] = f2bf(b1.w);
      }
    }
    __syncthreads();
    bf16x8 af0 = *(const bf16x8*)&As[rbase][kb];
    bf16x8 af1 = *(const bf16x8*)&As[rbase + 16][kb];
    bf16x8 bf0 = *(const bf16x8*)&Bs[cbase][kb];
    bf16x8 bf1 = *(const bf16x8*)&Bs[cbase + 16][kb];
    acc[0][0] = __builtin_amdgcn_mfma_f32_16x16x32_bf16(af0, bf0, acc[0][0], 0, 0, 0);
    acc[0][1] = __builtin_amdgcn_mfma_f32_16x16x32_bf16(af0, bf1, acc[0][1], 0, 0, 0);
    acc[1][0] = __builtin_amdgcn_mfma_f32_16x16x32_bf16(af1, bf0, acc[1][0], 0, 0, 0);
    acc[1][1] = __builtin_amdgcn_mfma_f32_16x16x32_bf16(af1, bf1, acc[1][1], 0, 0, 0);
  }

  const size_t cbase2 = (size_t)blockIdx.z * (size_t)bsC;
#pragma unroll
  for (int mi = 0; mi < 2; ++mi)
#pragma unroll
    for (int ni = 0; ni < 2; ++ni)
#pragma unroll
      for (int r = 0; r < 4; ++r) {
        const int row = m0 + wr * 32 + mi * 16 + (lane >> 4) * 4 + r;
        const int col = n0 + wc * 32 + ni * 16 + (lane & 15);
        if (row < M) {
          float v = acc[mi][ni][r];
          if (ADDD) v += D[(size_t)row * ldd + col];
          C[cbase2 + (size_t)row * ldc + col] = v;
        }
      }
}

// ---------------------------------------------------------------------------
// bf16 MFMA GEMM with LayerNorm fused on A: C = LN(A_rows; g,b) @ B.
// A rows at stride lda (classes). Per-block stats prologue (4 thr/row),
// LN applied during bf16 staging. Replaces lnlast + hl roundtrip.
// ---------------------------------------------------------------------------
__global__ __launch_bounds__(256) void gemm_mfma_lnA_k(
    const float* __restrict__ A, long long lda,
    const float* __restrict__ g, const float* __restrict__ b,
    const float* __restrict__ B, int ldb,
    float* __restrict__ C, int ldc,
    int M, int N, int K)
{
  const int m0 = blockIdx.y * 64, n0 = blockIdx.x * 64;
  const int tid = threadIdx.x;
  const int w = tid >> 6, lane = tid & 63;
  const int wr = w >> 1, wc = w & 1;
  __shared__ __attribute__((aligned(16))) short As[64][40];
  __shared__ __attribute__((aligned(16))) short Bs[64][40];
  __shared__ __attribute__((aligned(16))) float g_s[512], b_s[512];
  __shared__ float mean_s[64], rstd_s[64];
  f32x4 acc[2][2] = {};

  if (tid < 128) ((float4*)g_s)[tid] = ((const float4*)g)[tid];
  else ((float4*)b_s)[tid - 128] = ((const float4*)b)[tid - 128];

  // stats prologue: row r = tid>>2 (4 threads/row, 128 elems each)
  {
    const int r = tid >> 2, p = tid & 3;
    float s = 0.f, ss = 0.f;
    if (m0 + r < M) {
      const float4* src = (const float4*)(A + (size_t)(m0 + r) * lda + p * 128);
#pragma unroll 8
      for (int i = 0; i < 32; ++i) {
        const float4 v = src[i];
        s += v.x + v.y + v.z + v.w;
        ss += v.x * v.x + v.y * v.y + v.z * v.z + v.w * v.w;
      }
    }
    s += __shfl_xor(s, 1);  s += __shfl_xor(s, 2);
    ss += __shfl_xor(ss, 1); ss += __shfl_xor(ss, 2);
    if (p == 0) {
      const float mean = s * (1.f / 512.f);
      mean_s[r] = mean;
      rstd_s[r] = rsqrtf(ss * (1.f / 512.f) - mean * mean + 1e-5f);
    }
  }
  __syncthreads();

  const int ar = tid >> 2, akc = (tid & 3) * 8;
  const int br = tid >> 3, bnc = (tid & 7) * 8;
  const bool arv = (m0 + ar < M);
  const int rbase = wr * 32 + (lane & 15);
  const int cbase = wc * 32 + (lane & 15);
  const int kb = (lane >> 4) * 8;

  for (int k0 = 0; k0 < K; k0 += 32) {
    float4 a0 = make_float4(0.f, 0.f, 0.f, 0.f), a1 = a0;
    if (arv) {
      a0 = *(const float4*)(A + (size_t)(m0 + ar) * lda + k0 + akc);
      a1 = *(const float4*)(A + (size_t)(m0 + ar) * lda + k0 + akc + 4);
    }
    const float4 b0 = *(const float4*)(B + (size_t)(k0 + br) * ldb + n0 + bnc);
    const float4 b1 = *(const float4*)(B + (size_t)(k0 + br) * ldb + n0 + bnc + 4);
    __syncthreads();
    {
      const float mn = mean_s[ar], rs = rstd_s[ar];
      const int kc = k0 + akc;
      bf16x8 av;
      av[0] = f2bf((a0.x - mn) * rs * g_s[kc + 0] + b_s[kc + 0]);
      av[1] = f2bf((a0.y - mn) * rs * g_s[kc + 1] + b_s[kc + 1]);
      av[2] = f2bf((a0.z - mn) * rs * g_s[kc + 2] + b_s[kc + 2]);
      av[3] = f2bf((a0.w - mn) * rs * g_s[kc + 3] + b_s[kc + 3]);
      av[4] = f2bf((a1.x - mn) * rs * g_s[kc + 4] + b_s[kc + 4]);
      av[5] = f2bf((a1.y - mn) * rs * g_s[kc + 5] + b_s[kc + 5]);
      av[6] = f2bf((a1.z - mn) * rs * g_s[kc + 6] + b_s[kc + 6]);
      av[7] = f2bf((a1.w - mn) * rs * g_s[kc + 7] + b_s[kc + 7]);
      *(bf16x8*)&As[ar][akc] = av;
      Bs[bnc + 0][br] = f2bf(b0.x); Bs[bnc + 1][br] = f2bf(b0.y);
      Bs[bnc + 2][br] = f2bf(b0.z); Bs[bnc + 3][br] = f2bf(b0.w);
      Bs[bnc + 4][br] = f2bf(b1.x); Bs[bnc + 5][br] = f2bf(b1.y);
      Bs[bnc + 6][br] = f2bf(b1.z); Bs[bnc + 7][br] = f2bf(b1.w);
    }
    __syncthreads();
    bf16x8 af0 = *(const bf16x8*)&As[rbase][kb];
    bf16x8 af1 = *(const bf16x8*)&As[rbase + 16][kb];
    bf16x8 bf0 = *(const bf16x8*)&Bs[cbase][kb];
    bf16x8 bf1 = *(const bf16x8*)&Bs[cbase + 16][kb];
    acc[0][0] = __builtin_amdgcn_mfma_f32_16x16x32_bf16(af0, bf0, acc[0][0], 0, 0, 0);
    acc[0][1] = __builtin_amdgcn_mfma_f32_16x16x32_bf16(af0, bf1, acc[0][1], 0, 0, 0);
    acc[1][0] = __builtin_amdgcn_mfma_f32_16x16x32_bf16(af1, bf0, acc[1][0], 0, 0, 0);
    acc[1][1] = __builtin_amdgcn_mfma_f32_16x16x32_bf16(af1, bf1, acc[1][1], 0, 0, 0);
  }

#pragma unroll
  for (int mi = 0; mi < 2; ++mi)
#pragma unroll
    for (int ni = 0; ni < 2; ++ni)
#pragma unroll
      for (int r = 0; r < 4; ++r) {
        const int row = m0 + wr * 32 + mi * 16 + (lane >> 4) * 4 + r;
        const int col = n0 + wc * 32 + ni * 16 + (lane & 15);
        if (row < M) C[(size_t)row * ldc + col] = acc[mi][ni][r];
      }
}

// ---------------------------------------------------------------------------
// Logits GEMM with fused L2-normalization of A rows and B rows:
// C[m,n] = exp(alpha) * dot(A_m, B_n) / (|A_m| |B_n|).  32x64 tile, TRANSB,
// double-buffered f32. Each block covers full K, so row/col norms are
// accumulated from its own staged registers (replaces both rownorm kernels).
// ---------------------------------------------------------------------------
__global__ __launch_bounds__(256) void logits_k(
    const float* __restrict__ A, int lda,
    const float* __restrict__ B, int ldb,
    float* __restrict__ C, int ldc,
    const float* __restrict__ alpha_ptr,
    int M, int N, int K)
{
  const int m0 = blockIdx.y * 32, n0 = blockIdx.x * 64;
  const int tid = threadIdx.x;
  __shared__ __attribute__((aligned(16))) float As[2][16][36];
  __shared__ __attribute__((aligned(16))) float Bs[2][16][68];
  __shared__ float nA[32], nB[64];
  float acc[2][4] = {};
  float ssA = 0.f, ssB = 0.f;
  const int ty = tid >> 4, tx = tid & 15;
  const int am = tid >> 3, ak = (tid & 7) * 2;
  const int bm = tid >> 2, bt = (tid & 3) * 4;
  const bool aval = (m0 + am < M);
  const bool bval = (n0 + bm < N);

  float2 av; float4 bv;
  auto gload = [&](int k0) {
    av = make_float2(0.f, 0.f);
    bv = make_float4(0.f, 0.f, 0.f, 0.f);
    if (aval) av = *(const float2*)(A + (size_t)(m0 + am) * lda + (k0 + ak));
    if (bval) bv = *(const float4*)(B + (size_t)(n0 + bm) * ldb + (k0 + bt));
    ssA += av.x * av.x + av.y * av.y;
    ssB += bv.x * bv.x + bv.y * bv.y + bv.z * bv.z + bv.w * bv.w;
  };
  auto sstore = [&](int buf) {
    As[buf][ak][am] = av.x; As[buf][ak + 1][am] = av.y;
    Bs[buf][bt + 0][bm] = bv.x; Bs[buf][bt + 1][bm] = bv.y;
    Bs[buf][bt + 2][bm] = bv.z; Bs[buf][bt + 3][bm] = bv.w;
  };

  const int nIt = K >> 4;
  gload(0); sstore(0);
  for (int it = 0; it < nIt; ++it) {
    __syncthreads();
    if (it + 1 < nIt) gload((it + 1) << 4);
    const int buf = it & 1;
#pragma unroll
    for (int kk = 0; kk < 16; ++kk) {
      const float2 a  = *(const float2*)&As[buf][kk][ty * 2];
      const float4 bq = *(const float4*)&Bs[buf][kk][tx * 4];
      acc[0][0] += a.x * bq.x; acc[0][1] += a.x * bq.y; acc[0][2] += a.x * bq.z; acc[0][3] += a.x * bq.w;
      acc[1][0] += a.y * bq.x; acc[1][1] += a.y * bq.y; acc[1][2] += a.y * bq.z; acc[1][3] += a.y * bq.w;
    }
    if (it + 1 < nIt) sstore((it + 1) & 1);
  }

  // row norms: 8 threads share row am (tid = am*8+{0..7}); col: 4 per bm.
  ssA += __shfl_xor(ssA, 1); ssA += __shfl_xor(ssA, 2); ssA += __shfl_xor(ssA, 4);
  if ((tid & 7) == 0) nA[am] = rsqrtf(ssA);
  ssB += __shfl_xor(ssB, 1); ssB += __shfl_xor(ssB, 2);
  if ((tid & 3) == 0) nB[bm] = rsqrtf(ssB);
  __syncthreads();

  const float alpha = __expf(alpha_ptr[0]);
#pragma unroll
  for (int i = 0; i < 2; ++i) {
    const int m = m0 + ty * 2 + i;
    if (m >= M) continue;
    const float fa = alpha * nA[ty * 2 + i];
#pragma unroll
    for (int j = 0; j < 4; ++j) {
      const int nn = n0 + tx * 4 + j;
      if (nn < N) C[(size_t)m * ldc + nn] = acc[i][j] * fa * nB[tx * 4 + j];
    }
  }
}

// ---------------------------------------------------------------------------
// FUSED sweep v5: v4 + gather8 replaced by LDS wave-broadcast of exp(score)
// (lanes 0-7 write, all lanes read 2x float4; same-wave RAW, wave_barrier
// pins compiler ordering). exp now on 8 lanes instead of 64.
// ---------------------------------------------------------------------------
__global__ __launch_bounds__(256) void fused_sweep_kernel(
    const float* __restrict__ ctx, const float* __restrict__ cls,
    const float* __restrict__ g, const float* __restrict__ b,
    const float* __restrict__ wt, float* __restrict__ u_out)
{
  const int n = blockIdx.x, tid = threadIdx.x;
  const int w = tid >> 6, lane = tid & 63;
  __shared__ __attribute__((aligned(16))) float gw_s[8][512];
  __shared__ __attribute__((aligned(16))) float g_s[512], b_s[512];
  __shared__ __attribute__((aligned(16))) float hctx[5][512];
  __shared__ float sc_s[8][80];
  __shared__ float sc2_s[8][5];
  __shared__ float ah_s[8][5];
  __shared__ float wstatB[4][8], wstatL[4][8];
  __shared__ float attr_s[5];
  __shared__ float Sgw_l[8], bw_l[8];
  __shared__ float Bt_s[8], Lt_s[8], inv_s[8];
  __shared__ float e2_s[8][5];
  __shared__ __attribute__((aligned(16))) float es_s[4][2][8];

  {
    const float4* wsrc = (const float4*)(wt + (size_t)n * 4096);
    float4* wdst = (float4*)&gw_s[0][0];
    for (int i = tid; i < 1024; i += 256) wdst[i] = wsrc[i];
    const float4* csrc = (const float4*)(ctx + (size_t)n * 2560);
    float4* cdst = (float4*)&hctx[0][0];
    for (int i = tid; i < 640; i += 256) cdst[i] = csrc[i];
    if (tid < 128) ((float4*)g_s)[tid] = ((const float4*)g)[tid];
    else ((float4*)b_s)[tid - 128] = ((const float4*)b)[tid - 128];
  }
  __syncthreads();

  for (int hh = w; hh < 8; hh += 4) {
    float s1 = 0.f, s2 = 0.f;
#pragma unroll
    for (int i = 0; i < 8; ++i) {
      const int j = lane + 64 * i;
      const float wv = gw_s[hh][j];
      const float gv = wv * g_s[j];
      s1 += gv; s2 += wv * b_s[j];
      gw_s[hh][j] = gv;
    }
    s1 = wsum(s1); s2 = wsum(s2);
    if (lane == 0) { Sgw_l[hh] = s1; bw_l[hh] = s2; }
  }
  __syncthreads();
  const float sg_r  = Sgw_l[lane & 7];
  const float bw8_r = bw_l[lane & 7] * 0.125f;

  for (int k = w; k < 5; k += 4) {
    float2 x2[4];
#pragma unroll
    for (int i = 0; i < 4; ++i)
      x2[i] = *(const float2*)&hctx[k][lane * 2 + 128 * i];
    float s = 0.f, ss = 0.f;
#pragma unroll
    for (int i = 0; i < 4; ++i) {
      s += x2[i].x + x2[i].y; ss += x2[i].x * x2[i].x + x2[i].y * x2[i].y;
    }
    float v8[8] = {};
#pragma unroll
    for (int hh = 0; hh < 8; ++hh)
#pragma unroll
      for (int i = 0; i < 4; ++i) {
        const float2 ww = *(const float2*)&gw_s[hh][lane * 2 + 128 * i];
        v8[hh] += x2[i].x * ww.x + x2[i].y * ww.y;
      }
    s = wsum(s); ss = wsum(ss);
    const float mean = s * (1.f / 512.f);
    const float rstd = rsqrtf(ss * (1.f / 512.f) - mean * mean + 1e-5f);
    const float z = fold8(v8, lane);
    const float zf = rstd * 0.125f * (z - mean * sg_r) + bw8_r;
    if (lane < 8) sc_s[lane][k] = zf;
  }

  float A[8][8];
#pragma unroll
  for (int hh = 0; hh < 8; ++hh)
#pragma unroll
    for (int i = 0; i < 8; ++i) A[hh][i] = 0.f;
  float B8[8] = {}, L8[8] = {};

  const float* base = cls + (size_t)n * 72 * 512;
  float2 xa[4], xb[4];
  {
    const float* sA = base + (size_t)w * 512;
    const float* sB = base + (size_t)(w + 4) * 512;
#pragma unroll
    for (int i = 0; i < 4; ++i) {
      xa[i] = *(const float2*)(sA + lane * 2 + 128 * i);
      xb[i] = *(const float2*)(sB + lane * 2 + 128 * i);
    }
  }
  for (int p = 0; p < 9; ++p) {
    float2 na[4], nb[4];
    const bool more = (p < 8);
    if (more) {
      const float* sA = base + (size_t)(w + 8 * (p + 1)) * 512;
      const float* sB = base + (size_t)(w + 4 + 8 * (p + 1)) * 512;
#pragma unroll
      for (int i = 0; i < 4; ++i) {
        na[i] = *(const float2*)(sA + lane * 2 + 128 * i);
        nb[i] = *(const float2*)(sB + lane * 2 + 128 * i);
      }
    }
    float sa = 0.f, ssa = 0.f, sb = 0.f, ssb = 0.f;
#pragma unroll
    for (int i = 0; i < 4; ++i) {
      sa += xa[i].x + xa[i].y; ssa += xa[i].x * xa[i].x + xa[i].y * xa[i].y;
      sb += xb[i].x + xb[i].y; ssb += xb[i].x * xb[i].x + xb[i].y * xb[i].y;
    }
    float v8a[8] = {}, v8b[8] = {};
#pragma unroll
    for (int hh = 0; hh < 8; ++hh)
#pragma unroll
      for (int i = 0; i < 4; ++i) {
        const float2 ww = *(const float2*)&gw_s[hh][lane * 2 + 128 * i];
        v8a[hh] += xa[i].x * ww.x + xa[i].y * ww.y;
        v8b[hh] += xb[i].x * ww.x + xb[i].y * ww.y;
      }
    sa = wsum(sa); ssa = wsum(ssa); sb = wsum(sb); ssb = wsum(ssb);
    const float meanA = sa * (1.f / 512.f);
    const float rstdA = rsqrtf(ssa * (1.f / 512.f) - meanA * meanA + 1e-5f);
    const float meanB = sb * (1.f / 512.f);
    const float rstdB = rsqrtf(ssb * (1.f / 512.f) - meanB * meanB + 1e-5f);
    const float za = fold8(v8a, lane);
    const float zb = fold8(v8b, lane);
    const float zfa = rstdA * 0.125f * (za - meanA * sg_r) + bw8_r;
    const float zfb = rstdB * 0.125f * (zb - meanB * sg_r) + bw8_r;
    const int kA = 5 + w + 8 * p;
    if (lane < 8) {
      sc_s[lane][kA] = zfa; sc_s[lane][kA + 4] = zfb;
      es_s[w][0][lane] = __expf(zfa);
      es_s[w][1][lane] = __expf(zfb);
    }
    __builtin_amdgcn_wave_barrier();   // pin ds_write before ds_read (same wave)
    const float4 ea0 = *(const float4*)&es_s[w][0][0];
    const float4 ea1 = *(const float4*)&es_s[w][0][4];
    const float4 eb0 = *(const float4*)&es_s[w][1][0];
    const float4 eb1 = *(const float4*)&es_s[w][1][4];
    const float esa[8] = {ea0.x, ea0.y, ea0.z, ea0.w, ea1.x, ea1.y, ea1.z, ea1.w};
    const float esb[8] = {eb0.x, eb0.y, eb0.z, eb0.w, eb1.x, eb1.y, eb1.z, eb1.w};
#pragma unroll
    for (int hh = 0; hh < 8; ++hh) {
      const float erA = esa[hh] * rstdA;
      const float erB = esb[hh] * rstdB;
#pragma unroll
      for (int i = 0; i < 4; ++i) {
        A[hh][2 * i]     += erA * xa[i].x;
        A[hh][2 * i + 1] += erA * xa[i].y;
      }
      B8[hh] += erA * meanA;
      L8[hh] += esa[hh];
#pragma unroll
      for (int i = 0; i < 4; ++i) {
        A[hh][2 * i]     += erB * xb[i].x;
        A[hh][2 * i + 1] += erB * xb[i].y;
      }
      B8[hh] += erB * meanB;
      L8[hh] += esb[hh];
    }
    if (more)
#pragma unroll
      for (int i = 0; i < 4; ++i) { xa[i] = na[i]; xb[i] = nb[i]; }
  }
  if (lane == 0)
#pragma unroll
    for (int hh = 0; hh < 8; ++hh) {
      wstatB[w][hh] = B8[hh]; wstatL[w][hh] = L8[hh];
    }
  __syncthreads();

  for (int hh = w; hh < 8; hh += 4) {
    const float v0 = sc_s[hh][lane];
    const float v1 = (lane + 64 < 77) ? sc_s[hh][lane + 64] : -1e30f;
    const float mx = wmaxr(fmaxf(v0, v1));
    const float e0 = __expf(v0 - mx);
    const float e1 = (lane + 64 < 77) ? __expf(v1 - mx) : 0.f;
    const float S = wsum(e0 + e1);
    if (lane < 5) ah_s[hh][lane] = e0 / S;
  }
  __syncthreads();
  if (tid == 0) {
    float m[5], mx = -1e30f;
#pragma unroll
    for (int p = 0; p < 5; ++p) {
      float acc = 0.f;
      for (int hh = 0; hh < 8; ++hh) acc += ah_s[hh][p];
      m[p] = acc * 0.125f;
      mx = fmaxf(mx, m[p]);
    }
    float e[5], S = 0.f;
#pragma unroll
    for (int p = 0; p < 5; ++p) { e[p] = __expf(m[p] - mx); S += e[p]; }
#pragma unroll
    for (int p = 0; p < 5; ++p) attr_s[p] = e[p] / S;
  }
  __syncthreads();

  for (int k = w; k < 5; k += 4) {
    const float c = attr_s[k];
    float2 x2[4];
#pragma unroll
    for (int i = 0; i < 4; ++i) {
      x2[i] = *(const float2*)&hctx[k][lane * 2 + 128 * i];
      x2[i].x *= c; x2[i].y *= c;
    }
    float s = 0.f, ss = 0.f;
#pragma unroll
    for (int i = 0; i < 4; ++i) {
      s += x2[i].x + x2[i].y; ss += x2[i].x * x2[i].x + x2[i].y * x2[i].y;
    }
    float v8[8] = {};
#pragma unroll
    for (int hh = 0; hh < 8; ++hh)
#pragma unroll
      for (int i = 0; i < 4; ++i) {
        const float2 ww = *(const float2*)&gw_s[hh][lane * 2 + 128 * i];
        v8[hh] += x2[i].x * ww.x + x2[i].y * ww.y;
      }
    s = wsum(s); ss = wsum(ss);
    const float mean = s * (1.f / 512.f);
    const float rstd = rsqrtf(ss * (1.f / 512.f) - mean * mean + 1e-5f);
#pragma unroll
    for (int i = 0; i < 4; ++i) {
      const int j0 = lane * 2 + 128 * i;
      const float2 gg = *(const float2*)&g_s[j0];
      const float2 bb = *(const float2*)&b_s[j0];
      *(float2*)&hctx[k][j0] = make_float2(
          (x2[i].x - mean) * rstd * gg.x + bb.x,
          (x2[i].y - mean) * rstd * gg.y + bb.y);
    }
    const float z = fold8(v8, lane);
    const float zf = rstd * 0.125f * (z - mean * sg_r) + bw8_r;
    if (lane < 8) sc2_s[lane][k] = zf;
  }
  __syncthreads();

  for (int wv = 0; wv < 4; ++wv) {
    if (w == wv) {
#pragma unroll
      for (int hh = 0; hh < 8; ++hh)
#pragma unroll
        for (int i = 0; i < 4; ++i) {
          float2* p = (float2*)&gw_s[hh][lane * 2 + 128 * i];
          const float2 a = make_float2(A[hh][2 * i], A[hh][2 * i + 1]);
          if (wv == 0) *p = a;
          else { float2 v = *p; v.x += a.x; v.y += a.y; *p = v; }
        }
    }
    __syncthreads();
  }

  if (tid < 8) {
    float Bt = 0.f, Lt = 0.f;
    for (int wv = 0; wv < 4; ++wv) { Bt += wstatB[wv][tid]; Lt += wstatL[wv][tid]; }
    float den = Lt;
#pragma unroll
    for (int k = 0; k < 5; ++k) {
      const float e = __expf(sc2_s[tid][k]);
      e2_s[tid][k] = e; den += e;
    }
    Bt_s[tid] = Bt; Lt_s[tid] = Lt; inv_s[tid] = 1.f / den;
  }
  __syncthreads();

  float* dst = u_out + (size_t)n * 4096;
  for (int idx = tid; idx < 4096; idx += 256) {
    const int hh = idx >> 9, j = idx & 511;
    float v = (gw_s[hh][j] - Bt_s[hh]) * g_s[j] + Lt_s[hh] * b_s[j];
#pragma unroll
    for (int k = 0; k < 5; ++k) v += e2_s[hh][k] * hctx[k][j];
    dst[idx] = v * inv_s[hh];
  }
}

// ---------------------------------------------------------------------------
extern "C" void kernel_launch(void* const* d_in, const int* in_sizes, int n_in,
                              void* d_out, int out_size, void* d_ws, size_t ws_size,
                              hipStream_t stream)
{
  const float* images = (const float*)d_in[0];
  const float* W_img  = (const float*)d_in[1];
  const float* ctx    = (const float*)d_in[2];
  const float* cls    = (const float*)d_in[3];
  const float* ln_g   = (const float*)d_in[4];
  const float* ln_b   = (const float*)d_in[5];
  const float* Wq     = (const float*)d_in[6];
  const float* Wk     = (const float*)d_in[7];
  const float* Wv     = (const float*)d_in[8];
  const float* Wo     = (const float*)d_in[9];
  const float* tproj  = (const float*)d_in[10];
  const float* lscale = (const float*)d_in[11];

  float* ws   = (float*)d_ws;
  float* wtu  = ws;                 // wt -> u (in place) -> txt overlay
  float* img  = wtu + 4096000;      // unnormalized (logits_k normalizes)
  float* hlO  = img + 131072;       // O
  float* qo2  = hlO + 512000;       // q -> out2
  float* txt  = wtu;
  (void)in_sizes; (void)n_in; (void)out_size; (void)ws_size;

  // 1) image embedding (bf16 MFMA), unnormalized
  gemm_mfma_k<0,0><<<dim3(8,4,1),256,0,stream>>>(images,768,0, W_img,512,0,
      img,512,0, nullptr,0, 256,512,768);

  // 2) q = LN(cls_last) @ Wq  (LN fused into staging)
  gemm_mfma_lnA_k<<<dim3(8,16),256,0,stream>>>(cls + 71*512, 72*512,
      ln_g, ln_b, Wq,512, qo2,512, 1000,512,512);

  // 3) wt = per-head q @ Wk^T  (bf16 MFMA, TRANSB, batched)
  gemm_mfma_k<1,0><<<dim3(8,16,8),256,0,stream>>>(qo2,512,64, Wk,512,64,
      wtu,4096,512, nullptr,0, 1000,512,64);

  // 4+5) fused pass1+pass2 sweep -> u (in place over wt)
  fused_sweep_kernel<<<1000,256,0,stream>>>(ctx, cls, ln_g, ln_b, wtu, wtu);

  // 6) O = per-head u @ Wv  (bf16 MFMA, batched)
  gemm_mfma_k<0,0><<<dim3(1,16,8),256,0,stream>>>(wtu,4096,512, Wv,512,64,
      hlO,512,64, nullptr,0, 1000,64,512);

  // 7) out2 = cls_last + O @ Wo ; txt = out2 @ text_proj  (bf16 MFMA)
  gemm_mfma_k<0,1><<<dim3(8,16,1),256,0,stream>>>(hlO,512,0, Wo,512,0,
      qo2,512,0, cls + 71*512, 72*512, 1000,512,512);
  gemm_mfma_k<0,0><<<dim3(8,16,1),256,0,stream>>>(qo2,512,0, tproj,512,0,
      txt,512,0, nullptr,0, 1000,512,512);

  // 8) logits = exp(ls) * (img/|img|) @ (txt/|txt|)^T  (norms fused, f32)
  logits_k<<<dim3(16,8),256,0,stream>>>(img,512, txt,512,
      (float*)d_out,1000, lscale, 256,1000,512);
}

// Round 10
// 188.686 us; speedup vs baseline: 2.0625x; 1.0818x over previous
//
#include <hip/hip_runtime.h>
#include <hip/hip_bf16.h>

#define DEV static __device__ __forceinline__

typedef __attribute__((ext_vector_type(8))) short bf16x8;
typedef __attribute__((ext_vector_type(4))) short s16x4;
typedef __attribute__((ext_vector_type(4))) float f32x4;

DEV float wsum(float v) {
  v += __shfl_xor(v, 1);  v += __shfl_xor(v, 2);  v += __shfl_xor(v, 4);
  v += __shfl_xor(v, 8);  v += __shfl_xor(v, 16); v += __shfl_xor(v, 32);
  return v;
}
DEV float wmaxr(float v) {
  v = fmaxf(v, __shfl_xor(v, 1));  v = fmaxf(v, __shfl_xor(v, 2));
  v = fmaxf(v, __shfl_xor(v, 4));  v = fmaxf(v, __shfl_xor(v, 8));
  v = fmaxf(v, __shfl_xor(v, 16)); v = fmaxf(v, __shfl_xor(v, 32));
  return v;
}
DEV short f2bf(float x) {
  __hip_bfloat16 h = __float2bfloat16(x);
  return *reinterpret_cast<short*>(&h);
}
DEV float bf2f(unsigned int u) {
  const unsigned int x = u << 16;
  return __uint_as_float(x);
}

// Fold-reduce 8 per-lane values across 64 lanes -> full sum of head (lane&7).
DEV float fold8(const float v[8], int lane) {
  float w4[4];
#pragma unroll
  for (int j = 0; j < 4; ++j) {
    const float mine  = (lane & 1) ? v[2 * j + 1] : v[2 * j];
    const float other = (lane & 1) ? v[2 * j]     : v[2 * j + 1];
    w4[j] = mine + __shfl_xor(other, 1);
  }
  float u2[2];
#pragma unroll
  for (int j = 0; j < 2; ++j) {
    const float mine  = (lane & 2) ? w4[2 * j + 1] : w4[2 * j];
    const float other = (lane & 2) ? w4[2 * j]     : w4[2 * j + 1];
    u2[j] = mine + __shfl_xor(other, 2);
  }
  const float mine  = (lane & 4) ? u2[1] : u2[0];
  const float other = (lane & 4) ? u2[0] : u2[1];
  float z = mine + __shfl_xor(other, 4);
  z += __shfl_xor(z, 8); z += __shfl_xor(z, 16); z += __shfl_xor(z, 32);
  return z;
}

// ---------------------------------------------------------------------------
// Unified bf16 MFMA GEMM. C = A@B (+D). 64x64 tile, 4 waves, BK=32.
// ABF16: A is bf16 in memory (loaded straight to LDS, no cvt).
// OUTBF16: C stored as bf16. Layout HW-validated rounds 7/8.
// ---------------------------------------------------------------------------
template <int TRANSB, int ADDD, int ABF16, int OUTBF16>
__global__ __launch_bounds__(256) void gemm_mfma_k(
    const void* __restrict__ Av, int lda, long long bsA,
    const float* __restrict__ B, int ldb, long long bsB,
    void* __restrict__ Cv, int ldc, long long bsC,
    const float* __restrict__ D, long long ldd,
    int M, int N, int K)
{
  const float* Af = (const float*)Av + (ABF16 ? 0 : (size_t)blockIdx.z * bsA);
  const short* Ah = (const short*)Av + (ABF16 ? (size_t)blockIdx.z * bsA : 0);
  B += (size_t)blockIdx.z * bsB;
  const int m0 = blockIdx.y * 64, n0 = blockIdx.x * 64;
  const int tid = threadIdx.x;
  const int w = tid >> 6, lane = tid & 63;
  const int wr = w >> 1, wc = w & 1;
  __shared__ __attribute__((aligned(16))) short As[64][40];
  __shared__ __attribute__((aligned(16))) short Bs[64][40];
  f32x4 acc[2][2] = {};

  const int ar = tid >> 2, akc = (tid & 3) * 8;
  const int br = tid >> 3, bnc = (tid & 7) * 8;
  const bool arv = (m0 + ar < M);
  const int rbase = wr * 32 + (lane & 15);
  const int cbase = wc * 32 + (lane & 15);
  const int kb = (lane >> 4) * 8;

  for (int k0 = 0; k0 < K; k0 += 32) {
    float4 a0 = make_float4(0.f, 0.f, 0.f, 0.f), a1 = a0;
    bf16x8 ah = {};
    if (ABF16) {
      if (arv) ah = *(const bf16x8*)(Ah + (size_t)(m0 + ar) * lda + k0 + akc);
    } else if (arv) {
      a0 = *(const float4*)(Af + (size_t)(m0 + ar) * lda + k0 + akc);
      a1 = *(const float4*)(Af + (size_t)(m0 + ar) * lda + k0 + akc + 4);
    }
    float4 b0, b1;
    if (TRANSB) {
      b0 = *(const float4*)(B + (size_t)(n0 + ar) * ldb + k0 + akc);
      b1 = *(const float4*)(B + (size_t)(n0 + ar) * ldb + k0 + akc + 4);
    } else {
      b0 = *(const float4*)(B + (size_t)(k0 + br) * ldb + n0 + bnc);
      b1 = *(const float4*)(B + (size_t)(k0 + br) * ldb + n0 + bnc + 4);
    }
    __syncthreads();
    {
      if (ABF16) {
        *(bf16x8*)&As[ar][akc] = ah;
      } else {
        bf16x8 av;
        av[0] = f2bf(a0.x); av[1] = f2bf(a0.y); av[2] = f2bf(a0.z); av[3] = f2bf(a0.w);
        av[4] = f2bf(a1.x); av[5] = f2bf(a1.y); av[6] = f2bf(a1.z); av[7] = f2bf(a1.w);
        *(bf16x8*)&As[ar][akc] = av;
      }
      if (TRANSB) {
        bf16x8 bv;
        bv[0] = f2bf(b0.x); bv[1] = f2bf(b0.y); bv[2] = f2bf(b0.z); bv[3] = f2bf(b0.w);
        bv[4] = f2bf(b1.x); bv[5] = f2bf(b1.y); bv[6] = f2bf(b1.z); bv[7] = f2bf(b1.w);
        *(bf16x8*)&Bs[ar][akc] = bv;
      } else {
        Bs[bnc + 0][br] = f2bf(b0.x); Bs[bnc + 1][br] = f2bf(b0.y);
        Bs[bnc + 2][br] = f2bf(b0.z); Bs[bnc + 3][br] = f2bf(b0.w);
        Bs[bnc + 4][br] = f2bf(b1.x); Bs[bnc + 5][br] = f2bf(b1.y);
        Bs[bnc + 6][br] = f2bf(b1.z); Bs[bnc + 7][br] = f2bf(b1.w);
      }
    }
    __syncthreads();
    bf16x8 af0 = *(const bf16x8*)&As[rbase][kb];
    bf16x8 af1 = *(const bf16x8*)&As[rbase + 16][kb];
    bf16x8 bf0 = *(const bf16x8*)&Bs[cbase][kb];
    bf16x8 bf1 = *(const bf16x8*)&Bs[cbase + 16][kb];
    acc[0][0] = __builtin_amdgcn_mfma_f32_16x16x32_bf16(af0, bf0, acc[0][0], 0, 0, 0);
    acc[0][1] = __builtin_amdgcn_mfma_f32_16x16x32_bf16(af0, bf1, acc[0][1], 0, 0, 0);
    acc[1][0] = __builtin_amdgcn_mfma_f32_16x16x32_bf16(af1, bf0, acc[1][0], 0, 0, 0);
    acc[1][1] = __builtin_amdgcn_mfma_f32_16x16x32_bf16(af1, bf1, acc[1][1], 0, 0, 0);
  }

  const size_t cb = (size_t)blockIdx.z * (size_t)bsC;
#pragma unroll
  for (int mi = 0; mi < 2; ++mi)
#pragma unroll
    for (int ni = 0; ni < 2; ++ni)
#pragma unroll
      for (int r = 0; r < 4; ++r) {
        const int row = m0 + wr * 32 + mi * 16 + (lane >> 4) * 4 + r;
        const int col = n0 + wc * 32 + ni * 16 + (lane & 15);
        if (row < M) {
          float v = acc[mi][ni][r];
          if (ADDD) v += D[(size_t)row * ldd + col];
          if (OUTBF16)
            ((__hip_bfloat16*)Cv)[cb + (size_t)row * ldc + col] = __float2bfloat16(v);
          else
            ((float*)Cv)[cb + (size_t)row * ldc + col] = v;
        }
      }
}

// ---------------------------------------------------------------------------
// bf16 MFMA GEMM with LayerNorm fused on A (round-9, unchanged).
// ---------------------------------------------------------------------------
__global__ __launch_bounds__(256) void gemm_mfma_lnA_k(
    const float* __restrict__ A, long long lda,
    const float* __restrict__ g, const float* __restrict__ b,
    const float* __restrict__ B, int ldb,
    float* __restrict__ C, int ldc,
    int M, int N, int K)
{
  const int m0 = blockIdx.y * 64, n0 = blockIdx.x * 64;
  const int tid = threadIdx.x;
  const int w = tid >> 6, lane = tid & 63;
  const int wr = w >> 1, wc = w & 1;
  __shared__ __attribute__((aligned(16))) short As[64][40];
  __shared__ __attribute__((aligned(16))) short Bs[64][40];
  __shared__ __attribute__((aligned(16))) float g_s[512], b_s[512];
  __shared__ float mean_s[64], rstd_s[64];
  f32x4 acc[2][2] = {};

  if (tid < 128) ((float4*)g_s)[tid] = ((const float4*)g)[tid];
  else ((float4*)b_s)[tid - 128] = ((const float4*)b)[tid - 128];

  {
    const int r = tid >> 2, p = tid & 3;
    float s = 0.f, ss = 0.f;
    if (m0 + r < M) {
      const float4* src = (const float4*)(A + (size_t)(m0 + r) * lda + p * 128);
#pragma unroll 8
      for (int i = 0; i < 32; ++i) {
        const float4 v = src[i];
        s += v.x + v.y + v.z + v.w;
        ss += v.x * v.x + v.y * v.y + v.z * v.z + v.w * v.w;
      }
    }
    s += __shfl_xor(s, 1);  s += __shfl_xor(s, 2);
    ss += __shfl_xor(ss, 1); ss += __shfl_xor(ss, 2);
    if (p == 0) {
      const float mean = s * (1.f / 512.f);
      mean_s[r] = mean;
      rstd_s[r] = rsqrtf(ss * (1.f / 512.f) - mean * mean + 1e-5f);
    }
  }
  __syncthreads();

  const int ar = tid >> 2, akc = (tid & 3) * 8;
  const int br = tid >> 3, bnc = (tid & 7) * 8;
  const bool arv = (m0 + ar < M);
  const int rbase = wr * 32 + (lane & 15);
  const int cbase = wc * 32 + (lane & 15);
  const int kb = (lane >> 4) * 8;

  for (int k0 = 0; k0 < K; k0 += 32) {
    float4 a0 = make_float4(0.f, 0.f, 0.f, 0.f), a1 = a0;
    if (arv) {
      a0 = *(const float4*)(A + (size_t)(m0 + ar) * lda + k0 + akc);
      a1 = *(const float4*)(A + (size_t)(m0 + ar) * lda + k0 + akc + 4);
    }
    const float4 b0 = *(const float4*)(B + (size_t)(k0 + br) * ldb + n0 + bnc);
    const float4 b1 = *(const float4*)(B + (size_t)(k0 + br) * ldb + n0 + bnc + 4);
    __syncthreads();
    {
      const float mn = mean_s[ar], rs = rstd_s[ar];
      const int kc = k0 + akc;
      bf16x8 av;
      av[0] = f2bf((a0.x - mn) * rs * g_s[kc + 0] + b_s[kc + 0]);
      av[1] = f2bf((a0.y - mn) * rs * g_s[kc + 1] + b_s[kc + 1]);
      av[2] = f2bf((a0.z - mn) * rs * g_s[kc + 2] + b_s[kc + 2]);
      av[3] = f2bf((a0.w - mn) * rs * g_s[kc + 3] + b_s[kc + 3]);
      av[4] = f2bf((a1.x - mn) * rs * g_s[kc + 4] + b_s[kc + 4]);
      av[5] = f2bf((a1.y - mn) * rs * g_s[kc + 5] + b_s[kc + 5]);
      av[6] = f2bf((a1.z - mn) * rs * g_s[kc + 6] + b_s[kc + 6]);
      av[7] = f2bf((a1.w - mn) * rs * g_s[kc + 7] + b_s[kc + 7]);
      *(bf16x8*)&As[ar][akc] = av;
      Bs[bnc + 0][br] = f2bf(b0.x); Bs[bnc + 1][br] = f2bf(b0.y);
      Bs[bnc + 2][br] = f2bf(b0.z); Bs[bnc + 3][br] = f2bf(b0.w);
      Bs[bnc + 4][br] = f2bf(b1.x); Bs[bnc + 5][br] = f2bf(b1.y);
      Bs[bnc + 6][br] = f2bf(b1.z); Bs[bnc + 7][br] = f2bf(b1.w);
    }
    __syncthreads();
    bf16x8 af0 = *(const bf16x8*)&As[rbase][kb];
    bf16x8 af1 = *(const bf16x8*)&As[rbase + 16][kb];
    bf16x8 bf0 = *(const bf16x8*)&Bs[cbase][kb];
    bf16x8 bf1 = *(const bf16x8*)&Bs[cbase + 16][kb];
    acc[0][0] = __builtin_amdgcn_mfma_f32_16x16x32_bf16(af0, bf0, acc[0][0], 0, 0, 0);
    acc[0][1] = __builtin_amdgcn_mfma_f32_16x16x32_bf16(af0, bf1, acc[0][1], 0, 0, 0);
    acc[1][0] = __builtin_amdgcn_mfma_f32_16x16x32_bf16(af1, bf0, acc[1][0], 0, 0, 0);
    acc[1][1] = __builtin_amdgcn_mfma_f32_16x16x32_bf16(af1, bf1, acc[1][1], 0, 0, 0);
  }

#pragma unroll
  for (int mi = 0; mi < 2; ++mi)
#pragma unroll
    for (int ni = 0; ni < 2; ++ni)
#pragma unroll
      for (int r = 0; r < 4; ++r) {
        const int row = m0 + wr * 32 + mi * 16 + (lane >> 4) * 4 + r;
        const int col = n0 + wc * 32 + ni * 16 + (lane & 15);
        if (row < M) C[(size_t)row * ldc + col] = acc[mi][ni][r];
      }
}

// ---------------------------------------------------------------------------
// Logits GEMM with fused L2 norms (round-9, unchanged).
// ---------------------------------------------------------------------------
__global__ __launch_bounds__(256) void logits_k(
    const float* __restrict__ A, int lda,
    const float* __restrict__ B, int ldb,
    float* __restrict__ C, int ldc,
    const float* __restrict__ alpha_ptr,
    int M, int N, int K)
{
  const int m0 = blockIdx.y * 32, n0 = blockIdx.x * 64;
  const int tid = threadIdx.x;
  __shared__ __attribute__((aligned(16))) float As[2][16][36];
  __shared__ __attribute__((aligned(16))) float Bs[2][16][68];
  __shared__ float nA[32], nB[64];
  float acc[2][4] = {};
  float ssA = 0.f, ssB = 0.f;
  const int ty = tid >> 4, tx = tid & 15;
  const int am = tid >> 3, ak = (tid & 7) * 2;
  const int bm = tid >> 2, bt = (tid & 3) * 4;
  const bool aval = (m0 + am < M);
  const bool bval = (n0 + bm < N);

  float2 av; float4 bv;
  auto gload = [&](int k0) {
    av = make_float2(0.f, 0.f);
    bv = make_float4(0.f, 0.f, 0.f, 0.f);
    if (aval) av = *(const float2*)(A + (size_t)(m0 + am) * lda + (k0 + ak));
    if (bval) bv = *(const float4*)(B + (size_t)(n0 + bm) * ldb + (k0 + bt));
    ssA += av.x * av.x + av.y * av.y;
    ssB += bv.x * bv.x + bv.y * bv.y + bv.z * bv.z + bv.w * bv.w;
  };
  auto sstore = [&](int buf) {
    As[buf][ak][am] = av.x; As[buf][ak + 1][am] = av.y;
    Bs[buf][bt + 0][bm] = bv.x; Bs[buf][bt + 1][bm] = bv.y;
    Bs[buf][bt + 2][bm] = bv.z; Bs[buf][bt + 3][bm] = bv.w;
  };

  const int nIt = K >> 4;
  gload(0); sstore(0);
  for (int it = 0; it < nIt; ++it) {
    __syncthreads();
    if (it + 1 < nIt) gload((it + 1) << 4);
    const int buf = it & 1;
#pragma unroll
    for (int kk = 0; kk < 16; ++kk) {
      const float2 a  = *(const float2*)&As[buf][kk][ty * 2];
      const float4 bq = *(const float4*)&Bs[buf][kk][tx * 4];
      acc[0][0] += a.x * bq.x; acc[0][1] += a.x * bq.y; acc[0][2] += a.x * bq.z; acc[0][3] += a.x * bq.w;
      acc[1][0] += a.y * bq.x; acc[1][1] += a.y * bq.y; acc[1][2] += a.y * bq.z; acc[1][3] += a.y * bq.w;
    }
    if (it + 1 < nIt) sstore((it + 1) & 1);
  }

  ssA += __shfl_xor(ssA, 1); ssA += __shfl_xor(ssA, 2); ssA += __shfl_xor(ssA, 4);
  if ((tid & 7) == 0) nA[am] = rsqrtf(ssA);
  ssB += __shfl_xor(ssB, 1); ssB += __shfl_xor(ssB, 2);
  if ((tid & 3) == 0) nB[bm] = rsqrtf(ssB);
  __syncthreads();

  const float alpha = __expf(alpha_ptr[0]);
#pragma unroll
  for (int i = 0; i < 2; ++i) {
    const int m = m0 + ty * 2 + i;
    if (m >= M) continue;
    const float fa = alpha * nA[ty * 2 + i];
#pragma unroll
    for (int j = 0; j < 4; ++j) {
      const int nn = n0 + tx * 4 + j;
      if (nn < N) C[(size_t)m * ldc + nn] = acc[i][j] * fa * nB[tx * 4 + j];
    }
  }
}

// ---------------------------------------------------------------------------
// FUSED sweep v6: v5 + (a) wt read as bf16, u written as bf16 (b) float4 row
// ownership j = lane*4 + 256*i (c) prefetch depth 2 (3 pairs in flight).
// ---------------------------------------------------------------------------
__global__ __launch_bounds__(256) void fused_sweep_kernel(
    const float* __restrict__ ctx, const float* __restrict__ cls,
    const float* __restrict__ g, const float* __restrict__ b,
    const __hip_bfloat16* __restrict__ wt, __hip_bfloat16* __restrict__ u_out)
{
  const int n = blockIdx.x, tid = threadIdx.x;
  const int w = tid >> 6, lane = tid & 63;
  __shared__ __attribute__((aligned(16))) float gw_s[8][512];
  __shared__ __attribute__((aligned(16))) float g_s[512], b_s[512];
  __shared__ __attribute__((aligned(16))) float hctx[5][512];
  __shared__ float sc_s[8][80];
  __shared__ float sc2_s[8][5];
  __shared__ float ah_s[8][5];
  __shared__ float wstatB[4][8], wstatL[4][8];
  __shared__ float attr_s[5];
  __shared__ float Sgw_l[8], bw_l[8];
  __shared__ float Bt_s[8], Lt_s[8], inv_s[8];
  __shared__ float e2_s[8][5];
  __shared__ __attribute__((aligned(16))) float es_s[4][2][8];

  {
    const uint4* wsrc = (const uint4*)(wt + (size_t)n * 4096);  // 8 bf16 per uint4
    float4* gwf = (float4*)&gw_s[0][0];
    for (int i = tid; i < 512; i += 256) {
      const uint4 v = wsrc[i];
      gwf[i * 2]     = make_float4(bf2f(v.x & 0xffffu), bf2f(v.x >> 16),
                                   bf2f(v.y & 0xffffu), bf2f(v.y >> 16));
      gwf[i * 2 + 1] = make_float4(bf2f(v.z & 0xffffu), bf2f(v.z >> 16),
                                   bf2f(v.w & 0xffffu), bf2f(v.w >> 16));
    }
    const float4* csrc = (const float4*)(ctx + (size_t)n * 2560);
    float4* cdst = (float4*)&hctx[0][0];
    for (int i = tid; i < 640; i += 256) cdst[i] = csrc[i];
    if (tid < 128) ((float4*)g_s)[tid] = ((const float4*)g)[tid];
    else ((float4*)b_s)[tid - 128] = ((const float4*)b)[tid - 128];
  }
  __syncthreads();

  for (int hh = w; hh < 8; hh += 4) {
    float s1 = 0.f, s2 = 0.f;
#pragma unroll
    for (int i = 0; i < 8; ++i) {
      const int j = lane + 64 * i;
      const float wv = gw_s[hh][j];
      const float gv = wv * g_s[j];
      s1 += gv; s2 += wv * b_s[j];
      gw_s[hh][j] = gv;
    }
    s1 = wsum(s1); s2 = wsum(s2);
    if (lane == 0) { Sgw_l[hh] = s1; bw_l[hh] = s2; }
  }
  __syncthreads();
  const float sg_r  = Sgw_l[lane & 7];
  const float bw8_r = bw_l[lane & 7] * 0.125f;
  const int j0 = lane * 4, j1 = lane * 4 + 256;

  // ---- stage A: 5 unscaled ctx rows -> pass-1 scores
  for (int k = w; k < 5; k += 4) {
    float4 x0 = *(const float4*)&hctx[k][j0];
    float4 x1 = *(const float4*)&hctx[k][j1];
    float s  = x0.x + x0.y + x0.z + x0.w + x1.x + x1.y + x1.z + x1.w;
    float ss = x0.x * x0.x + x0.y * x0.y + x0.z * x0.z + x0.w * x0.w
             + x1.x * x1.x + x1.y * x1.y + x1.z * x1.z + x1.w * x1.w;
    float v8[8] = {};
#pragma unroll
    for (int hh = 0; hh < 8; ++hh) {
      const float4 w0 = *(const float4*)&gw_s[hh][j0];
      const float4 w1 = *(const float4*)&gw_s[hh][j1];
      v8[hh] = x0.x * w0.x + x0.y * w0.y + x0.z * w0.z + x0.w * w0.w
             + x1.x * w1.x + x1.y * w1.y + x1.z * w1.z + x1.w * w1.w;
    }
    s = wsum(s); ss = wsum(ss);
    const float mean = s * (1.f / 512.f);
    const float rstd = rsqrtf(ss * (1.f / 512.f) - mean * mean + 1e-5f);
    const float z = fold8(v8, lane);
    const float zf = rstd * 0.125f * (z - mean * sg_r) + bw8_r;
    if (lane < 8) sc_s[lane][k] = zf;
  }

  // ---- stage B: 72 cls rows, 9 pairs/wave, prefetch depth 2
  float A[8][8];
#pragma unroll
  for (int hh = 0; hh < 8; ++hh)
#pragma unroll
    for (int i = 0; i < 8; ++i) A[hh][i] = 0.f;
  float B8[8] = {}, L8[8] = {};

  const float* base = cls + (size_t)n * 72 * 512;
  float4 xa0, xa1, xb0, xb1, ya0, ya1, yb0, yb1;
  {
    const float* sA = base + (size_t)w * 512;
    const float* sB = base + (size_t)(w + 4) * 512;
    xa0 = *(const float4*)(sA + j0); xa1 = *(const float4*)(sA + j1);
    xb0 = *(const float4*)(sB + j0); xb1 = *(const float4*)(sB + j1);
    const float* sA1 = base + (size_t)(w + 8) * 512;
    const float* sB1 = base + (size_t)(w + 12) * 512;
    ya0 = *(const float4*)(sA1 + j0); ya1 = *(const float4*)(sA1 + j1);
    yb0 = *(const float4*)(sB1 + j0); yb1 = *(const float4*)(sB1 + j1);
  }
  for (int p = 0; p < 9; ++p) {
    float4 za0, za1, zb0, zb1;
    const bool more2 = (p + 2 < 9);
    if (more2) {
      const float* sA = base + (size_t)(w + 8 * (p + 2)) * 512;
      const float* sB = base + (size_t)(w + 4 + 8 * (p + 2)) * 512;
      za0 = *(const float4*)(sA + j0); za1 = *(const float4*)(sA + j1);
      zb0 = *(const float4*)(sB + j0); zb1 = *(const float4*)(sB + j1);
    }
    float sa = xa0.x + xa0.y + xa0.z + xa0.w + xa1.x + xa1.y + xa1.z + xa1.w;
    float ssa = xa0.x * xa0.x + xa0.y * xa0.y + xa0.z * xa0.z + xa0.w * xa0.w
              + xa1.x * xa1.x + xa1.y * xa1.y + xa1.z * xa1.z + xa1.w * xa1.w;
    float sb = xb0.x + xb0.y + xb0.z + xb0.w + xb1.x + xb1.y + xb1.z + xb1.w;
    float ssb = xb0.x * xb0.x + xb0.y * xb0.y + xb0.z * xb0.z + xb0.w * xb0.w
              + xb1.x * xb1.x + xb1.y * xb1.y + xb1.z * xb1.z + xb1.w * xb1.w;
    float v8a[8], v8b[8];
#pragma unroll
    for (int hh = 0; hh < 8; ++hh) {
      const float4 w0 = *(const float4*)&gw_s[hh][j0];
      const float4 w1 = *(const float4*)&gw_s[hh][j1];
      v8a[hh] = xa0.x * w0.x + xa0.y * w0.y + xa0.z * w0.z + xa0.w * w0.w
              + xa1.x * w1.x + xa1.y * w1.y + xa1.z * w1.z + xa1.w * w1.w;
      v8b[hh] = xb0.x * w0.x + xb0.y * w0.y + xb0.z * w0.z + xb0.w * w0.w
              + xb1.x * w1.x + xb1.y * w1.y + xb1.z * w1.z + xb1.w * w1.w;
    }
    sa = wsum(sa); ssa = wsum(ssa); sb = wsum(sb); ssb = wsum(ssb);
    const float meanA = sa * (1.f / 512.f);
    const float rstdA = rsqrtf(ssa * (1.f / 512.f) - meanA * meanA + 1e-5f);
    const float meanB = sb * (1.f / 512.f);
    const float rstdB = rsqrtf(ssb * (1.f / 512.f) - meanB * meanB + 1e-5f);
    const float za = fold8(v8a, lane);
    const float zb = fold8(v8b, lane);
    const float zfa = rstdA * 0.125f * (za - meanA * sg_r) + bw8_r;
    const float zfb = rstdB * 0.125f * (zb - meanB * sg_r) + bw8_r;
    const int kA = 5 + w + 8 * p;
    if (lane < 8) {
      sc_s[lane][kA] = zfa; sc_s[lane][kA + 4] = zfb;
      es_s[w][0][lane] = __expf(zfa);
      es_s[w][1][lane] = __expf(zfb);
    }
    __builtin_amdgcn_wave_barrier();
    const float4 ea0 = *(const float4*)&es_s[w][0][0];
    const float4 ea1 = *(const float4*)&es_s[w][0][4];
    const float4 eb0 = *(const float4*)&es_s[w][1][0];
    const float4 eb1 = *(const float4*)&es_s[w][1][4];
    const float esa[8] = {ea0.x, ea0.y, ea0.z, ea0.w, ea1.x, ea1.y, ea1.z, ea1.w};
    const float esb[8] = {eb0.x, eb0.y, eb0.z, eb0.w, eb1.x, eb1.y, eb1.z, eb1.w};
#pragma unroll
    for (int hh = 0; hh < 8; ++hh) {
      const float erA = esa[hh] * rstdA;
      const float erB = esb[hh] * rstdB;
      A[hh][0] += erA * xa0.x; A[hh][1] += erA * xa0.y;
      A[hh][2] += erA * xa0.z; A[hh][3] += erA * xa0.w;
      A[hh][4] += erA * xa1.x; A[hh][5] += erA * xa1.y;
      A[hh][6] += erA * xa1.z; A[hh][7] += erA * xa1.w;
      B8[hh] += erA * meanA;
      L8[hh] += esa[hh];
      A[hh][0] += erB * xb0.x; A[hh][1] += erB * xb0.y;
      A[hh][2] += erB * xb0.z; A[hh][3] += erB * xb0.w;
      A[hh][4] += erB * xb1.x; A[hh][5] += erB * xb1.y;
      A[hh][6] += erB * xb1.z; A[hh][7] += erB * xb1.w;
      B8[hh] += erB * meanB;
      L8[hh] += esb[hh];
    }
    xa0 = ya0; xa1 = ya1; xb0 = yb0; xb1 = yb1;
    if (more2) { ya0 = za0; ya1 = za1; yb0 = zb0; yb1 = zb1; }
  }
  if (lane == 0)
#pragma unroll
    for (int hh = 0; hh < 8; ++hh) {
      wstatB[w][hh] = B8[hh]; wstatL[w][hh] = L8[hh];
    }
  __syncthreads();

  // ---- pass-1 softmax over 77 -> head-mean of first 5 -> attr
  for (int hh = w; hh < 8; hh += 4) {
    const float v0 = sc_s[hh][lane];
    const float v1 = (lane + 64 < 77) ? sc_s[hh][lane + 64] : -1e30f;
    const float mx = wmaxr(fmaxf(v0, v1));
    const float e0 = __expf(v0 - mx);
    const float e1 = (lane + 64 < 77) ? __expf(v1 - mx) : 0.f;
    const float S = wsum(e0 + e1);
    if (lane < 5) ah_s[hh][lane] = e0 / S;
  }
  __syncthreads();
  if (tid == 0) {
    float m[5], mx = -1e30f;
#pragma unroll
    for (int p = 0; p < 5; ++p) {
      float acc = 0.f;
      for (int hh = 0; hh < 8; ++hh) acc += ah_s[hh][p];
      m[p] = acc * 0.125f;
      mx = fmaxf(mx, m[p]);
    }
    float e[5], S = 0.f;
#pragma unroll
    for (int p = 0; p < 5; ++p) { e[p] = __expf(m[p] - mx); S += e[p]; }
#pragma unroll
    for (int p = 0; p < 5; ++p) attr_s[p] = e[p] / S;
  }
  __syncthreads();

  // ---- stage C: scaled ctx rows -> h2 (into hctx) + scores sc2
  for (int k = w; k < 5; k += 4) {
    const float c = attr_s[k];
    float4 x0 = *(const float4*)&hctx[k][j0];
    float4 x1 = *(const float4*)&hctx[k][j1];
    x0.x *= c; x0.y *= c; x0.z *= c; x0.w *= c;
    x1.x *= c; x1.y *= c; x1.z *= c; x1.w *= c;
    float s  = x0.x + x0.y + x0.z + x0.w + x1.x + x1.y + x1.z + x1.w;
    float ss = x0.x * x0.x + x0.y * x0.y + x0.z * x0.z + x0.w * x0.w
             + x1.x * x1.x + x1.y * x1.y + x1.z * x1.z + x1.w * x1.w;
    float v8[8];
#pragma unroll
    for (int hh = 0; hh < 8; ++hh) {
      const float4 w0 = *(const float4*)&gw_s[hh][j0];
      const float4 w1 = *(const float4*)&gw_s[hh][j1];
      v8[hh] = x0.x * w0.x + x0.y * w0.y + x0.z * w0.z + x0.w * w0.w
             + x1.x * w1.x + x1.y * w1.y + x1.z * w1.z + x1.w * w1.w;
    }
    s = wsum(s); ss = wsum(ss);
    const float mean = s * (1.f / 512.f);
    const float rstd = rsqrtf(ss * (1.f / 512.f) - mean * mean + 1e-5f);
    {
      const float4 gg0 = *(const float4*)&g_s[j0];
      const float4 bb0 = *(const float4*)&b_s[j0];
      const float4 gg1 = *(const float4*)&g_s[j1];
      const float4 bb1 = *(const float4*)&b_s[j1];
      *(float4*)&hctx[k][j0] = make_float4(
          (x0.x - mean) * rstd * gg0.x + bb0.x, (x0.y - mean) * rstd * gg0.y + bb0.y,
          (x0.z - mean) * rstd * gg0.z + bb0.z, (x0.w - mean) * rstd * gg0.w + bb0.w);
      *(float4*)&hctx[k][j1] = make_float4(
          (x1.x - mean) * rstd * gg1.x + bb1.x, (x1.y - mean) * rstd * gg1.y + bb1.y,
          (x1.z - mean) * rstd * gg1.z + bb1.z, (x1.w - mean) * rstd * gg1.w + bb1.w);
    }
    const float z = fold8(v8, lane);
    const float zf = rstd * 0.125f * (z - mean * sg_r) + bw8_r;
    if (lane < 8) sc2_s[lane][k] = zf;
  }
  __syncthreads();

  // ---- cross-wave A combine into gw_s region (float4)
  for (int wv = 0; wv < 4; ++wv) {
    if (w == wv) {
#pragma unroll
      for (int hh = 0; hh < 8; ++hh) {
        float4* p0 = (float4*)&gw_s[hh][j0];
        float4* p1 = (float4*)&gw_s[hh][j1];
        const float4 a0 = make_float4(A[hh][0], A[hh][1], A[hh][2], A[hh][3]);
        const float4 a1 = make_float4(A[hh][4], A[hh][5], A[hh][6], A[hh][7]);
        if (wv == 0) { *p0 = a0; *p1 = a1; }
        else {
          float4 v0 = *p0, v1 = *p1;
          v0.x += a0.x; v0.y += a0.y; v0.z += a0.z; v0.w += a0.w;
          v1.x += a1.x; v1.y += a1.y; v1.z += a1.z; v1.w += a1.w;
          *p0 = v0; *p1 = v1;
        }
      }
    }
    __syncthreads();
  }

  if (tid < 8) {
    float Bt = 0.f, Lt = 0.f;
    for (int wv = 0; wv < 4; ++wv) { Bt += wstatB[wv][tid]; Lt += wstatL[wv][tid]; }
    float den = Lt;
#pragma unroll
    for (int k = 0; k < 5; ++k) {
      const float e = __expf(sc2_s[tid][k]);
      e2_s[tid][k] = e; den += e;
    }
    Bt_s[tid] = Bt; Lt_s[tid] = Lt; inv_s[tid] = 1.f / den;
  }
  __syncthreads();

  // ---- u[hh][j] (bf16) = ((g*(A-B) + b*L + sum_k e2*h2) / den)
  __hip_bfloat16* dst = u_out + (size_t)n * 4096;
  for (int bidx = tid * 4; bidx < 4096; bidx += 1024) {
    const int hh = bidx >> 9, j = bidx & 511;
    const float4 a4 = *(const float4*)&gw_s[hh][j];
    const float4 g4 = *(const float4*)&g_s[j];
    const float4 b4 = *(const float4*)&b_s[j];
    const float Bt = Bt_s[hh], Lt = Lt_s[hh];
    float v0 = (a4.x - Bt) * g4.x + Lt * b4.x;
    float v1 = (a4.y - Bt) * g4.y + Lt * b4.y;
    float v2 = (a4.z - Bt) * g4.z + Lt * b4.z;
    float v3 = (a4.w - Bt) * g4.w + Lt * b4.w;
#pragma unroll
    for (int k = 0; k < 5; ++k) {
      const float4 h4 = *(const float4*)&hctx[k][j];
      const float e = e2_s[hh][k];
      v0 += e * h4.x; v1 += e * h4.y; v2 += e * h4.z; v3 += e * h4.w;
    }
    const float iv = inv_s[hh];
    s16x4 o;
    o[0] = f2bf(v0 * iv); o[1] = f2bf(v1 * iv);
    o[2] = f2bf(v2 * iv); o[3] = f2bf(v3 * iv);
    *(s16x4*)&dst[bidx] = o;
  }
}

// ---------------------------------------------------------------------------
extern "C" void kernel_launch(void* const* d_in, const int* in_sizes, int n_in,
                              void* d_out, int out_size, void* d_ws, size_t ws_size,
                              hipStream_t stream)
{
  const float* images = (const float*)d_in[0];
  const float* W_img  = (const float*)d_in[1];
  const float* ctx    = (const float*)d_in[2];
  const float* cls    = (const float*)d_in[3];
  const float* ln_g   = (const float*)d_in[4];
  const float* ln_b   = (const float*)d_in[5];
  const float* Wq     = (const float*)d_in[6];
  const float* Wk     = (const float*)d_in[7];
  const float* Wv     = (const float*)d_in[8];
  const float* Wo     = (const float*)d_in[9];
  const float* tproj  = (const float*)d_in[10];
  const float* lscale = (const float*)d_in[11];

  // Layout: wtu (bf16, 1000x4096 = 8.19 MB -> 2,048,000 f32-slots), then f32
  // buffers. txt aliases the (dead-after-O-GEMM) wtu region as f32.
  __hip_bfloat16* wtu = (__hip_bfloat16*)d_ws;
  float* fws  = (float*)d_ws;
  float* img  = fws + 2048000;
  float* hlO  = img + 131072;       // O
  float* qo2  = hlO + 512000;       // q -> out2
  float* txt  = fws;                // alias over dead u
  (void)in_sizes; (void)n_in; (void)out_size; (void)ws_size;

  // 1) image embedding (bf16 MFMA), unnormalized (logits_k normalizes)
  gemm_mfma_k<0,0,0,0><<<dim3(8,4,1),256,0,stream>>>(images,768,0, W_img,512,0,
      img,512,0, nullptr,0, 256,512,768);

  // 2) q = LN(cls_last) @ Wq  (LN fused into staging)
  gemm_mfma_lnA_k<<<dim3(8,16),256,0,stream>>>(cls + 71*512, 72*512,
      ln_g, ln_b, Wq,512, qo2,512, 1000,512,512);

  // 3) wt = per-head q @ Wk^T  -> bf16 (halves write + sweep read traffic)
  gemm_mfma_k<1,0,0,1><<<dim3(8,16,8),256,0,stream>>>(qo2,512,64, Wk,512,64,
      wtu,4096,512, nullptr,0, 1000,512,64);

  // 4+5) fused pass1+pass2 sweep -> u bf16 (in place over wt)
  fused_sweep_kernel<<<1000,256,0,stream>>>(ctx, cls, ln_g, ln_b, wtu, wtu);

  // 6) O = per-head u @ Wv  (A read directly as bf16)
  gemm_mfma_k<0,0,1,0><<<dim3(1,16,8),256,0,stream>>>(wtu,4096,512, Wv,512,64,
      hlO,512,64, nullptr,0, 1000,64,512);

  // 7) out2 = cls_last + O @ Wo ; txt = out2 @ text_proj  (bf16 MFMA)
  gemm_mfma_k<0,1,0,0><<<dim3(8,16,1),256,0,stream>>>(hlO,512,0, Wo,512,0,
      qo2,512,0, cls + 71*512, 72*512, 1000,512,512);
  gemm_mfma_k<0,0,0,0><<<dim3(8,16,1),256,0,stream>>>(qo2,512,0, tproj,512,0,
      txt,512,0, nullptr,0, 1000,512,512);

  // 8) logits = exp(ls) * (img/|img|) @ (txt/|txt|)^T  (norms fused, f32)
  logits_k<<<dim3(16,8),256,0,stream>>>(img,512, txt,512,
      (float*)d_out,1000, lscale, 256,1000,512);
}

// Round 11
// 162.481 us; speedup vs baseline: 2.3952x; 1.1613x over previous
//
#include <hip/hip_runtime.h>
#include <hip/hip_bf16.h>

#define DEV static __device__ __forceinline__

typedef __attribute__((ext_vector_type(8))) short bf16x8;
typedef __attribute__((ext_vector_type(4))) short s16x4;
typedef __attribute__((ext_vector_type(4))) float f32x4;

DEV float wsum(float v) {
  v += __shfl_xor(v, 1);  v += __shfl_xor(v, 2);  v += __shfl_xor(v, 4);
  v += __shfl_xor(v, 8);  v += __shfl_xor(v, 16); v += __shfl_xor(v, 32);
  return v;
}
DEV float wmaxr(float v) {
  v = fmaxf(v, __shfl_xor(v, 1));  v = fmaxf(v, __shfl_xor(v, 2));
  v = fmaxf(v, __shfl_xor(v, 4));  v = fmaxf(v, __shfl_xor(v, 8));
  v = fmaxf(v, __shfl_xor(v, 16)); v = fmaxf(v, __shfl_xor(v, 32));
  return v;
}
DEV short f2bf(float x) {
  __hip_bfloat16 h = __float2bfloat16(x);
  return *reinterpret_cast<short*>(&h);
}
DEV float bf2f(unsigned int u) {
  const unsigned int x = u << 16;
  return __uint_as_float(x);
}
DEV float bfs2f(short s) {   // short (bf16 bits) -> float
  const unsigned int x = ((unsigned int)(unsigned short)s) << 16;
  return __uint_as_float(x);
}

// Fold-reduce 8 per-lane values across 64 lanes -> full sum of head (lane&7).
DEV float fold8(const float v[8], int lane) {
  float w4[4];
#pragma unroll
  for (int j = 0; j < 4; ++j) {
    const float mine  = (lane & 1) ? v[2 * j + 1] : v[2 * j];
    const float other = (lane & 1) ? v[2 * j]     : v[2 * j + 1];
    w4[j] = mine + __shfl_xor(other, 1);
  }
  float u2[2];
#pragma unroll
  for (int j = 0; j < 2; ++j) {
    const float mine  = (lane & 2) ? w4[2 * j + 1] : w4[2 * j];
    const float other = (lane & 2) ? w4[2 * j]     : w4[2 * j + 1];
    u2[j] = mine + __shfl_xor(other, 2);
  }
  const float mine  = (lane & 4) ? u2[1] : u2[0];
  const float other = (lane & 4) ? u2[0] : u2[1];
  float z = mine + __shfl_xor(other, 4);
  z += __shfl_xor(z, 8); z += __shfl_xor(z, 16); z += __shfl_xor(z, 32);
  return z;
}

// ---------------------------------------------------------------------------
// Unified bf16 MFMA GEMM, depth-2 register prefetch (2 named ping/pong sets,
// K unrolled x2 -> K must be a multiple of 64: all call sites are 64/512/768).
// C = A@B (+D). 64x64 tile, 4 waves, BK=32. Layout HW-validated rounds 7-10.
// ---------------------------------------------------------------------------
template <int TRANSB, int ADDD, int ABF16, int OUTBF16>
__global__ __launch_bounds__(256) void gemm_mfma_k(
    const void* __restrict__ Av, int lda, long long bsA,
    const float* __restrict__ B, int ldb, long long bsB,
    void* __restrict__ Cv, int ldc, long long bsC,
    const float* __restrict__ D, long long ldd,
    int M, int N, int K)
{
  const float* Af = (const float*)Av + (ABF16 ? 0 : (size_t)blockIdx.z * bsA);
  const short* Ah = (const short*)Av + (ABF16 ? (size_t)blockIdx.z * bsA : 0);
  B += (size_t)blockIdx.z * bsB;
  const int m0 = blockIdx.y * 64, n0 = blockIdx.x * 64;
  const int tid = threadIdx.x;
  const int w = tid >> 6, lane = tid & 63;
  const int wr = w >> 1, wc = w & 1;
  __shared__ __attribute__((aligned(16))) short As[64][40];
  __shared__ __attribute__((aligned(16))) short Bs[64][40];
  f32x4 acc[2][2] = {};

  const int ar = tid >> 2, akc = (tid & 3) * 8;
  const int br = tid >> 3, bnc = (tid & 7) * 8;
  const bool arv = (m0 + ar < M);
  const int rbase = wr * 32 + (lane & 15);
  const int cbase = wc * 32 + (lane & 15);
  const int kb = (lane >> 4) * 8;

  auto gload = [&](int k0, float4& a0, float4& a1, bf16x8& ah,
                   float4& b0, float4& b1) {
    if (ABF16) {
      ah = bf16x8{};
      if (arv) ah = *(const bf16x8*)(Ah + (size_t)(m0 + ar) * lda + k0 + akc);
    } else {
      a0 = make_float4(0.f, 0.f, 0.f, 0.f); a1 = a0;
      if (arv) {
        a0 = *(const float4*)(Af + (size_t)(m0 + ar) * lda + k0 + akc);
        a1 = *(const float4*)(Af + (size_t)(m0 + ar) * lda + k0 + akc + 4);
      }
    }
    if (TRANSB) {
      b0 = *(const float4*)(B + (size_t)(n0 + ar) * ldb + k0 + akc);
      b1 = *(const float4*)(B + (size_t)(n0 + ar) * ldb + k0 + akc + 4);
    } else {
      b0 = *(const float4*)(B + (size_t)(k0 + br) * ldb + n0 + bnc);
      b1 = *(const float4*)(B + (size_t)(k0 + br) * ldb + n0 + bnc + 4);
    }
  };
  auto stage = [&](const float4& a0, const float4& a1, const bf16x8& ah,
                   const float4& b0, const float4& b1) {
    if (ABF16) {
      *(bf16x8*)&As[ar][akc] = ah;
    } else {
      bf16x8 av;
      av[0] = f2bf(a0.x); av[1] = f2bf(a0.y); av[2] = f2bf(a0.z); av[3] = f2bf(a0.w);
      av[4] = f2bf(a1.x); av[5] = f2bf(a1.y); av[6] = f2bf(a1.z); av[7] = f2bf(a1.w);
      *(bf16x8*)&As[ar][akc] = av;
    }
    if (TRANSB) {
      bf16x8 bv;
      bv[0] = f2bf(b0.x); bv[1] = f2bf(b0.y); bv[2] = f2bf(b0.z); bv[3] = f2bf(b0.w);
      bv[4] = f2bf(b1.x); bv[5] = f2bf(b1.y); bv[6] = f2bf(b1.z); bv[7] = f2bf(b1.w);
      *(bf16x8*)&Bs[ar][akc] = bv;
    } else {
      Bs[bnc + 0][br] = f2bf(b0.x); Bs[bnc + 1][br] = f2bf(b0.y);
      Bs[bnc + 2][br] = f2bf(b0.z); Bs[bnc + 3][br] = f2bf(b0.w);
      Bs[bnc + 4][br] = f2bf(b1.x); Bs[bnc + 5][br] = f2bf(b1.y);
      Bs[bnc + 6][br] = f2bf(b1.z); Bs[bnc + 7][br] = f2bf(b1.w);
    }
  };
  auto compute = [&]() {
    bf16x8 af0 = *(const bf16x8*)&As[rbase][kb];
    bf16x8 af1 = *(const bf16x8*)&As[rbase + 16][kb];
    bf16x8 bf0 = *(const bf16x8*)&Bs[cbase][kb];
    bf16x8 bf1 = *(const bf16x8*)&Bs[cbase + 16][kb];
    acc[0][0] = __builtin_amdgcn_mfma_f32_16x16x32_bf16(af0, bf0, acc[0][0], 0, 0, 0);
    acc[0][1] = __builtin_amdgcn_mfma_f32_16x16x32_bf16(af0, bf1, acc[0][1], 0, 0, 0);
    acc[1][0] = __builtin_amdgcn_mfma_f32_16x16x32_bf16(af1, bf0, acc[1][0], 0, 0, 0);
    acc[1][1] = __builtin_amdgcn_mfma_f32_16x16x32_bf16(af1, bf1, acc[1][1], 0, 0, 0);
  };

  float4 a0A, a1A, b0A, b1A, a0B, a1B, b0B, b1B;
  bf16x8 ahA = {}, ahB = {};
  gload(0, a0A, a1A, ahA, b0A, b1A);
  gload(32, a0B, a1B, ahB, b0B, b1B);
  for (int k0 = 0; k0 < K; k0 += 64) {
    __syncthreads();
    stage(a0A, a1A, ahA, b0A, b1A);
    if (k0 + 64 < K) gload(k0 + 64, a0A, a1A, ahA, b0A, b1A);
    __syncthreads();
    compute();
    __syncthreads();
    stage(a0B, a1B, ahB, b0B, b1B);
    if (k0 + 96 < K) gload(k0 + 96, a0B, a1B, ahB, b0B, b1B);
    __syncthreads();
    compute();
  }

  const size_t cb = (size_t)blockIdx.z * (size_t)bsC;
#pragma unroll
  for (int mi = 0; mi < 2; ++mi)
#pragma unroll
    for (int ni = 0; ni < 2; ++ni)
#pragma unroll
      for (int r = 0; r < 4; ++r) {
        const int row = m0 + wr * 32 + mi * 16 + (lane >> 4) * 4 + r;
        const int col = n0 + wc * 32 + ni * 16 + (lane & 15);
        if (row < M) {
          float v = acc[mi][ni][r];
          if (ADDD) v += D[(size_t)row * ldd + col];
          if (OUTBF16)
            ((__hip_bfloat16*)Cv)[cb + (size_t)row * ldc + col] = __float2bfloat16(v);
          else
            ((float*)Cv)[cb + (size_t)row * ldc + col] = v;
        }
      }
}

// ---------------------------------------------------------------------------
// bf16 MFMA GEMM with LayerNorm fused on A, depth-2 register prefetch.
// ---------------------------------------------------------------------------
__global__ __launch_bounds__(256) void gemm_mfma_lnA_k(
    const float* __restrict__ A, long long lda,
    const float* __restrict__ g, const float* __restrict__ b,
    const float* __restrict__ B, int ldb,
    float* __restrict__ C, int ldc,
    int M, int N, int K)
{
  const int m0 = blockIdx.y * 64, n0 = blockIdx.x * 64;
  const int tid = threadIdx.x;
  const int w = tid >> 6, lane = tid & 63;
  const int wr = w >> 1, wc = w & 1;
  __shared__ __attribute__((aligned(16))) short As[64][40];
  __shared__ __attribute__((aligned(16))) short Bs[64][40];
  __shared__ __attribute__((aligned(16))) float g_s[512], b_s[512];
  __shared__ float mean_s[64], rstd_s[64];
  f32x4 acc[2][2] = {};

  if (tid < 128) ((float4*)g_s)[tid] = ((const float4*)g)[tid];
  else ((float4*)b_s)[tid - 128] = ((const float4*)b)[tid - 128];

  {
    const int r = tid >> 2, p = tid & 3;
    float s = 0.f, ss = 0.f;
    if (m0 + r < M) {
      const float4* src = (const float4*)(A + (size_t)(m0 + r) * lda + p * 128);
#pragma unroll 8
      for (int i = 0; i < 32; ++i) {
        const float4 v = src[i];
        s += v.x + v.y + v.z + v.w;
        ss += v.x * v.x + v.y * v.y + v.z * v.z + v.w * v.w;
      }
    }
    s += __shfl_xor(s, 1);  s += __shfl_xor(s, 2);
    ss += __shfl_xor(ss, 1); ss += __shfl_xor(ss, 2);
    if (p == 0) {
      const float mean = s * (1.f / 512.f);
      mean_s[r] = mean;
      rstd_s[r] = rsqrtf(ss * (1.f / 512.f) - mean * mean + 1e-5f);
    }
  }
  __syncthreads();

  const int ar = tid >> 2, akc = (tid & 3) * 8;
  const int br = tid >> 3, bnc = (tid & 7) * 8;
  const bool arv = (m0 + ar < M);
  const int rbase = wr * 32 + (lane & 15);
  const int cbase = wc * 32 + (lane & 15);
  const int kb = (lane >> 4) * 8;

  auto gload = [&](int k0, float4& a0, float4& a1, float4& b0, float4& b1) {
    a0 = make_float4(0.f, 0.f, 0.f, 0.f); a1 = a0;
    if (arv) {
      a0 = *(const float4*)(A + (size_t)(m0 + ar) * lda + k0 + akc);
      a1 = *(const float4*)(A + (size_t)(m0 + ar) * lda + k0 + akc + 4);
    }
    b0 = *(const float4*)(B + (size_t)(k0 + br) * ldb + n0 + bnc);
    b1 = *(const float4*)(B + (size_t)(k0 + br) * ldb + n0 + bnc + 4);
  };
  auto stage = [&](int k0, const float4& a0, const float4& a1,
                   const float4& b0, const float4& b1) {
    const float mn = mean_s[ar], rs = rstd_s[ar];
    const int kc = k0 + akc;
    bf16x8 av;
    av[0] = f2bf((a0.x - mn) * rs * g_s[kc + 0] + b_s[kc + 0]);
    av[1] = f2bf((a0.y - mn) * rs * g_s[kc + 1] + b_s[kc + 1]);
    av[2] = f2bf((a0.z - mn) * rs * g_s[kc + 2] + b_s[kc + 2]);
    av[3] = f2bf((a0.w - mn) * rs * g_s[kc + 3] + b_s[kc + 3]);
    av[4] = f2bf((a1.x - mn) * rs * g_s[kc + 4] + b_s[kc + 4]);
    av[5] = f2bf((a1.y - mn) * rs * g_s[kc + 5] + b_s[kc + 5]);
    av[6] = f2bf((a1.z - mn) * rs * g_s[kc + 6] + b_s[kc + 6]);
    av[7] = f2bf((a1.w - mn) * rs * g_s[kc + 7] + b_s[kc + 7]);
    *(bf16x8*)&As[ar][akc] = av;
    Bs[bnc + 0][br] = f2bf(b0.x); Bs[bnc + 1][br] = f2bf(b0.y);
    Bs[bnc + 2][br] = f2bf(b0.z); Bs[bnc + 3][br] = f2bf(b0.w);
    Bs[bnc + 4][br] = f2bf(b1.x); Bs[bnc + 5][br] = f2bf(b1.y);
    Bs[bnc + 6][br] = f2bf(b1.z); Bs[bnc + 7][br] = f2bf(b1.w);
  };
  auto compute = [&]() {
    bf16x8 af0 = *(const bf16x8*)&As[rbase][kb];
    bf16x8 af1 = *(const bf16x8*)&As[rbase + 16][kb];
    bf16x8 bf0 = *(const bf16x8*)&Bs[cbase][kb];
    bf16x8 bf1 = *(const bf16x8*)&Bs[cbase + 16][kb];
    acc[0][0] = __builtin_amdgcn_mfma_f32_16x16x32_bf16(af0, bf0, acc[0][0], 0, 0, 0);
    acc[0][1] = __builtin_amdgcn_mfma_f32_16x16x32_bf16(af0, bf1, acc[0][1], 0, 0, 0);
    acc[1][0] = __builtin_amdgcn_mfma_f32_16x16x32_bf16(af1, bf0, acc[1][0], 0, 0, 0);
    acc[1][1] = __builtin_amdgcn_mfma_f32_16x16x32_bf16(af1, bf1, acc[1][1], 0, 0, 0);
  };

  float4 a0A, a1A, b0A, b1A, a0B, a1B, b0B, b1B;
  gload(0, a0A, a1A, b0A, b1A);
  gload(32, a0B, a1B, b0B, b1B);
  for (int k0 = 0; k0 < K; k0 += 64) {
    __syncthreads();
    stage(k0, a0A, a1A, b0A, b1A);
    if (k0 + 64 < K) gload(k0 + 64, a0A, a1A, b0A, b1A);
    __syncthreads();
    compute();
    __syncthreads();
    stage(k0 + 32, a0B, a1B, b0B, b1B);
    if (k0 + 96 < K) gload(k0 + 96, a0B, a1B, b0B, b1B);
    __syncthreads();
    compute();
  }

#pragma unroll
  for (int mi = 0; mi < 2; ++mi)
#pragma unroll
    for (int ni = 0; ni < 2; ++ni)
#pragma unroll
      for (int r = 0; r < 4; ++r) {
        const int row = m0 + wr * 32 + mi * 16 + (lane >> 4) * 4 + r;
        const int col = n0 + wc * 32 + ni * 16 + (lane & 15);
        if (row < M) C[(size_t)row * ldc + col] = acc[mi][ni][r];
      }
}

// ---------------------------------------------------------------------------
// Logits GEMM with fused L2 norms (round-9, unchanged — already prefetched).
// ---------------------------------------------------------------------------
__global__ __launch_bounds__(256) void logits_k(
    const float* __restrict__ A, int lda,
    const float* __restrict__ B, int ldb,
    float* __restrict__ C, int ldc,
    const float* __restrict__ alpha_ptr,
    int M, int N, int K)
{
  const int m0 = blockIdx.y * 32, n0 = blockIdx.x * 64;
  const int tid = threadIdx.x;
  __shared__ __attribute__((aligned(16))) float As[2][16][36];
  __shared__ __attribute__((aligned(16))) float Bs[2][16][68];
  __shared__ float nA[32], nB[64];
  float acc[2][4] = {};
  float ssA = 0.f, ssB = 0.f;
  const int ty = tid >> 4, tx = tid & 15;
  const int am = tid >> 3, ak = (tid & 7) * 2;
  const int bm = tid >> 2, bt = (tid & 3) * 4;
  const bool aval = (m0 + am < M);
  const bool bval = (n0 + bm < N);

  float2 av; float4 bv;
  auto gload = [&](int k0) {
    av = make_float2(0.f, 0.f);
    bv = make_float4(0.f, 0.f, 0.f, 0.f);
    if (aval) av = *(const float2*)(A + (size_t)(m0 + am) * lda + (k0 + ak));
    if (bval) bv = *(const float4*)(B + (size_t)(n0 + bm) * ldb + (k0 + bt));
    ssA += av.x * av.x + av.y * av.y;
    ssB += bv.x * bv.x + bv.y * bv.y + bv.z * bv.z + bv.w * bv.w;
  };
  auto sstore = [&](int buf) {
    As[buf][ak][am] = av.x; As[buf][ak + 1][am] = av.y;
    Bs[buf][bt + 0][bm] = bv.x; Bs[buf][bt + 1][bm] = bv.y;
    Bs[buf][bt + 2][bm] = bv.z; Bs[buf][bt + 3][bm] = bv.w;
  };

  const int nIt = K >> 4;
  gload(0); sstore(0);
  for (int it = 0; it < nIt; ++it) {
    __syncthreads();
    if (it + 1 < nIt) gload((it + 1) << 4);
    const int buf = it & 1;
#pragma unroll
    for (int kk = 0; kk < 16; ++kk) {
      const float2 a  = *(const float2*)&As[buf][kk][ty * 2];
      const float4 bq = *(const float4*)&Bs[buf][kk][tx * 4];
      acc[0][0] += a.x * bq.x; acc[0][1] += a.x * bq.y; acc[0][2] += a.x * bq.z; acc[0][3] += a.x * bq.w;
      acc[1][0] += a.y * bq.x; acc[1][1] += a.y * bq.y; acc[1][2] += a.y * bq.z; acc[1][3] += a.y * bq.w;
    }
    if (it + 1 < nIt) sstore((it + 1) & 1);
  }

  ssA += __shfl_xor(ssA, 1); ssA += __shfl_xor(ssA, 2); ssA += __shfl_xor(ssA, 4);
  if ((tid & 7) == 0) nA[am] = rsqrtf(ssA);
  ssB += __shfl_xor(ssB, 1); ssB += __shfl_xor(ssB, 2);
  if ((tid & 3) == 0) nB[bm] = rsqrtf(ssB);
  __syncthreads();

  const float alpha = __expf(alpha_ptr[0]);
#pragma unroll
  for (int i = 0; i < 2; ++i) {
    const int m = m0 + ty * 2 + i;
    if (m >= M) continue;
    const float fa = alpha * nA[ty * 2 + i];
#pragma unroll
    for (int j = 0; j < 4; ++j) {
      const int nn = n0 + tx * 4 + j;
      if (nn < N) C[(size_t)m * ldc + nn] = acc[i][j] * fa * nB[tx * 4 + j];
    }
  }
}

// ---------------------------------------------------------------------------
// FUSED sweep v7: v6 with LDS diet (34.8 -> ~29 KB => 5 blocks/CU):
// ctx no longer mirrored in LDS (stages A/C read global, L3-hot); h2 stored
// as bf16 (epilogue-only consumer; u is bf16 anyway).
// ---------------------------------------------------------------------------
__global__ __launch_bounds__(256) void fused_sweep_kernel(
    const float* __restrict__ ctx, const float* __restrict__ cls,
    const float* __restrict__ g, const float* __restrict__ b,
    const __hip_bfloat16* __restrict__ wt, __hip_bfloat16* __restrict__ u_out)
{
  const int n = blockIdx.x, tid = threadIdx.x;
  const int w = tid >> 6, lane = tid & 63;
  __shared__ __attribute__((aligned(16))) float gw_s[8][512];
  __shared__ __attribute__((aligned(16))) float g_s[512], b_s[512];
  __shared__ __attribute__((aligned(16))) short h2_s[5][512];   // bf16 h2
  __shared__ float sc_s[8][80];
  __shared__ float sc2_s[8][5];
  __shared__ float ah_s[8][5];
  __shared__ float wstatB[4][8], wstatL[4][8];
  __shared__ float attr_s[5];
  __shared__ float Sgw_l[8], bw_l[8];
  __shared__ float Bt_s[8], Lt_s[8], inv_s[8];
  __shared__ float e2_s[8][5];
  __shared__ __attribute__((aligned(16))) float es_s[4][2][8];

  {
    const uint4* wsrc = (const uint4*)(wt + (size_t)n * 4096);  // 8 bf16 per uint4
    float4* gwf = (float4*)&gw_s[0][0];
    for (int i = tid; i < 512; i += 256) {
      const uint4 v = wsrc[i];
      gwf[i * 2]     = make_float4(bf2f(v.x & 0xffffu), bf2f(v.x >> 16),
                                   bf2f(v.y & 0xffffu), bf2f(v.y >> 16));
      gwf[i * 2 + 1] = make_float4(bf2f(v.z & 0xffffu), bf2f(v.z >> 16),
                                   bf2f(v.w & 0xffffu), bf2f(v.w >> 16));
    }
    if (tid < 128) ((float4*)g_s)[tid] = ((const float4*)g)[tid];
    else ((float4*)b_s)[tid - 128] = ((const float4*)b)[tid - 128];
  }
  __syncthreads();

  for (int hh = w; hh < 8; hh += 4) {
    float s1 = 0.f, s2 = 0.f;
#pragma unroll
    for (int i = 0; i < 8; ++i) {
      const int j = lane + 64 * i;
      const float wv = gw_s[hh][j];
      const float gv = wv * g_s[j];
      s1 += gv; s2 += wv * b_s[j];
      gw_s[hh][j] = gv;
    }
    s1 = wsum(s1); s2 = wsum(s2);
    if (lane == 0) { Sgw_l[hh] = s1; bw_l[hh] = s2; }
  }
  __syncthreads();
  const float sg_r  = Sgw_l[lane & 7];
  const float bw8_r = bw_l[lane & 7] * 0.125f;
  const int j0 = lane * 4, j1 = lane * 4 + 256;

  // ---- stage A: 5 unscaled ctx rows (global reads) -> pass-1 scores
  for (int k = w; k < 5; k += 4) {
    const float* src = ctx + ((size_t)n * 5 + k) * 512;
    const float4 x0 = *(const float4*)(src + j0);
    const float4 x1 = *(const float4*)(src + j1);
    float s  = x0.x + x0.y + x0.z + x0.w + x1.x + x1.y + x1.z + x1.w;
    float ss = x0.x * x0.x + x0.y * x0.y + x0.z * x0.z + x0.w * x0.w
             + x1.x * x1.x + x1.y * x1.y + x1.z * x1.z + x1.w * x1.w;
    float v8[8] = {};
#pragma unroll
    for (int hh = 0; hh < 8; ++hh) {
      const float4 w0 = *(const float4*)&gw_s[hh][j0];
      const float4 w1 = *(const float4*)&gw_s[hh][j1];
      v8[hh] = x0.x * w0.x + x0.y * w0.y + x0.z * w0.z + x0.w * w0.w
             + x1.x * w1.x + x1.y * w1.y + x1.z * w1.z + x1.w * w1.w;
    }
    s = wsum(s); ss = wsum(ss);
    const float mean = s * (1.f / 512.f);
    const float rstd = rsqrtf(ss * (1.f / 512.f) - mean * mean + 1e-5f);
    const float z = fold8(v8, lane);
    const float zf = rstd * 0.125f * (z - mean * sg_r) + bw8_r;
    if (lane < 8) sc_s[lane][k] = zf;
  }

  // ---- stage B: 72 cls rows, 9 pairs/wave, prefetch depth 2 (unchanged v6)
  float A[8][8];
#pragma unroll
  for (int hh = 0; hh < 8; ++hh)
#pragma unroll
    for (int i = 0; i < 8; ++i) A[hh][i] = 0.f;
  float B8[8] = {}, L8[8] = {};

  const float* base = cls + (size_t)n * 72 * 512;
  float4 xa0, xa1, xb0, xb1, ya0, ya1, yb0, yb1;
  {
    const float* sA = base + (size_t)w * 512;
    const float* sB = base + (size_t)(w + 4) * 512;
    xa0 = *(const float4*)(sA + j0); xa1 = *(const float4*)(sA + j1);
    xb0 = *(const float4*)(sB + j0); xb1 = *(const float4*)(sB + j1);
    const float* sA1 = base + (size_t)(w + 8) * 512;
    const float* sB1 = base + (size_t)(w + 12) * 512;
    ya0 = *(const float4*)(sA1 + j0); ya1 = *(const float4*)(sA1 + j1);
    yb0 = *(const float4*)(sB1 + j0); yb1 = *(const float4*)(sB1 + j1);
  }
  for (int p = 0; p < 9; ++p) {
    float4 za0, za1, zb0, zb1;
    const bool more2 = (p + 2 < 9);
    if (more2) {
      const float* sA = base + (size_t)(w + 8 * (p + 2)) * 512;
      const float* sB = base + (size_t)(w + 4 + 8 * (p + 2)) * 512;
      za0 = *(const float4*)(sA + j0); za1 = *(const float4*)(sA + j1);
      zb0 = *(const float4*)(sB + j0); zb1 = *(const float4*)(sB + j1);
    }
    float sa = xa0.x + xa0.y + xa0.z + xa0.w + xa1.x + xa1.y + xa1.z + xa1.w;
    float ssa = xa0.x * xa0.x + xa0.y * xa0.y + xa0.z * xa0.z + xa0.w * xa0.w
              + xa1.x * xa1.x + xa1.y * xa1.y + xa1.z * xa1.z + xa1.w * xa1.w;
    float sb = xb0.x + xb0.y + xb0.z + xb0.w + xb1.x + xb1.y + xb1.z + xb1.w;
    float ssb = xb0.x * xb0.x + xb0.y * xb0.y + xb0.z * xb0.z + xb0.w * xb0.w
              + xb1.x * xb1.x + xb1.y * xb1.y + xb1.z * xb1.z + xb1.w * xb1.w;
    float v8a[8], v8b[8];
#pragma unroll
    for (int hh = 0; hh < 8; ++hh) {
      const float4 w0 = *(const float4*)&gw_s[hh][j0];
      const float4 w1 = *(const float4*)&gw_s[hh][j1];
      v8a[hh] = xa0.x * w0.x + xa0.y * w0.y + xa0.z * w0.z + xa0.w * w0.w
              + xa1.x * w1.x + xa1.y * w1.y + xa1.z * w1.z + xa1.w * w1.w;
      v8b[hh] = xb0.x * w0.x + xb0.y * w0.y + xb0.z * w0.z + xb0.w * w0.w
              + xb1.x * w1.x + xb1.y * w1.y + xb1.z * w1.z + xb1.w * w1.w;
    }
    sa = wsum(sa); ssa = wsum(ssa); sb = wsum(sb); ssb = wsum(ssb);
    const float meanA = sa * (1.f / 512.f);
    const float rstdA = rsqrtf(ssa * (1.f / 512.f) - meanA * meanA + 1e-5f);
    const float meanB = sb * (1.f / 512.f);
    const float rstdB = rsqrtf(ssb * (1.f / 512.f) - meanB * meanB + 1e-5f);
    const float za = fold8(v8a, lane);
    const float zb = fold8(v8b, lane);
    const float zfa = rstdA * 0.125f * (za - meanA * sg_r) + bw8_r;
    const float zfb = rstdB * 0.125f * (zb - meanB * sg_r) + bw8_r;
    const int kA = 5 + w + 8 * p;
    if (lane < 8) {
      sc_s[lane][kA] = zfa; sc_s[lane][kA + 4] = zfb;
      es_s[w][0][lane] = __expf(zfa);
      es_s[w][1][lane] = __expf(zfb);
    }
    __builtin_amdgcn_wave_barrier();
    const float4 ea0 = *(const float4*)&es_s[w][0][0];
    const float4 ea1 = *(const float4*)&es_s[w][0][4];
    const float4 eb0 = *(const float4*)&es_s[w][1][0];
    const float4 eb1 = *(const float4*)&es_s[w][1][4];
    const float esa[8] = {ea0.x, ea0.y, ea0.z, ea0.w, ea1.x, ea1.y, ea1.z, ea1.w};
    const float esb[8] = {eb0.x, eb0.y, eb0.z, eb0.w, eb1.x, eb1.y, eb1.z, eb1.w};
#pragma unroll
    for (int hh = 0; hh < 8; ++hh) {
      const float erA = esa[hh] * rstdA;
      const float erB = esb[hh] * rstdB;
      A[hh][0] += erA * xa0.x; A[hh][1] += erA * xa0.y;
      A[hh][2] += erA * xa0.z; A[hh][3] += erA * xa0.w;
      A[hh][4] += erA * xa1.x; A[hh][5] += erA * xa1.y;
      A[hh][6] += erA * xa1.z; A[hh][7] += erA * xa1.w;
      B8[hh] += erA * meanA;
      L8[hh] += esa[hh];
      A[hh][0] += erB * xb0.x; A[hh][1] += erB * xb0.y;
      A[hh][2] += erB * xb0.z; A[hh][3] += erB * xb0.w;
      A[hh][4] += erB * xb1.x; A[hh][5] += erB * xb1.y;
      A[hh][6] += erB * xb1.z; A[hh][7] += erB * xb1.w;
      B8[hh] += erB * meanB;
      L8[hh] += esb[hh];
    }
    xa0 = ya0; xa1 = ya1; xb0 = yb0; xb1 = yb1;
    if (more2) { ya0 = za0; ya1 = za1; yb0 = zb0; yb1 = zb1; }
  }
  if (lane == 0)
#pragma unroll
    for (int hh = 0; hh < 8; ++hh) {
      wstatB[w][hh] = B8[hh]; wstatL[w][hh] = L8[hh];
    }
  __syncthreads();

  // ---- pass-1 softmax over 77 -> head-mean of first 5 -> attr
  for (int hh = w; hh < 8; hh += 4) {
    const float v0 = sc_s[hh][lane];
    const float v1 = (lane + 64 < 77) ? sc_s[hh][lane + 64] : -1e30f;
    const float mx = wmaxr(fmaxf(v0, v1));
    const float e0 = __expf(v0 - mx);
    const float e1 = (lane + 64 < 77) ? __expf(v1 - mx) : 0.f;
    const float S = wsum(e0 + e1);
    if (lane < 5) ah_s[hh][lane] = e0 / S;
  }
  __syncthreads();
  if (tid == 0) {
    float m[5], mx = -1e30f;
#pragma unroll
    for (int p = 0; p < 5; ++p) {
      float acc = 0.f;
      for (int hh = 0; hh < 8; ++hh) acc += ah_s[hh][p];
      m[p] = acc * 0.125f;
      mx = fmaxf(mx, m[p]);
    }
    float e[5], S = 0.f;
#pragma unroll
    for (int p = 0; p < 5; ++p) { e[p] = __expf(m[p] - mx); S += e[p]; }
#pragma unroll
    for (int p = 0; p < 5; ++p) attr_s[p] = e[p] / S;
  }
  __syncthreads();

  // ---- stage C: scaled ctx rows (global reads) -> h2 (bf16 LDS) + sc2
  for (int k = w; k < 5; k += 4) {
    const float c = attr_s[k];
    const float* src = ctx + ((size_t)n * 5 + k) * 512;
    float4 x0 = *(const float4*)(src + j0);
    float4 x1 = *(const float4*)(src + j1);
    x0.x *= c; x0.y *= c; x0.z *= c; x0.w *= c;
    x1.x *= c; x1.y *= c; x1.z *= c; x1.w *= c;
    float s  = x0.x + x0.y + x0.z + x0.w + x1.x + x1.y + x1.z + x1.w;
    float ss = x0.x * x0.x + x0.y * x0.y + x0.z * x0.z + x0.w * x0.w
             + x1.x * x1.x + x1.y * x1.y + x1.z * x1.z + x1.w * x1.w;
    float v8[8];
#pragma unroll
    for (int hh = 0; hh < 8; ++hh) {
      const float4 w0 = *(const float4*)&gw_s[hh][j0];
      const float4 w1 = *(const float4*)&gw_s[hh][j1];
      v8[hh] = x0.x * w0.x + x0.y * w0.y + x0.z * w0.z + x0.w * w0.w
             + x1.x * w1.x + x1.y * w1.y + x1.z * w1.z + x1.w * w1.w;
    }
    s = wsum(s); ss = wsum(ss);
    const float mean = s * (1.f / 512.f);
    const float rstd = rsqrtf(ss * (1.f / 512.f) - mean * mean + 1e-5f);
    {
      const float4 gg0 = *(const float4*)&g_s[j0];
      const float4 bb0 = *(const float4*)&b_s[j0];
      const float4 gg1 = *(const float4*)&g_s[j1];
      const float4 bb1 = *(const float4*)&b_s[j1];
      s16x4 o0, o1;
      o0[0] = f2bf((x0.x - mean) * rstd * gg0.x + bb0.x);
      o0[1] = f2bf((x0.y - mean) * rstd * gg0.y + bb0.y);
      o0[2] = f2bf((x0.z - mean) * rstd * gg0.z + bb0.z);
      o0[3] = f2bf((x0.w - mean) * rstd * gg0.w + bb0.w);
      o1[0] = f2bf((x1.x - mean) * rstd * gg1.x + bb1.x);
      o1[1] = f2bf((x1.y - mean) * rstd * gg1.y + bb1.y);
      o1[2] = f2bf((x1.z - mean) * rstd * gg1.z + bb1.z);
      o1[3] = f2bf((x1.w - mean) * rstd * gg1.w + bb1.w);
      *(s16x4*)&h2_s[k][j0] = o0;
      *(s16x4*)&h2_s[k][j1] = o1;
    }
    const float z = fold8(v8, lane);
    const float zf = rstd * 0.125f * (z - mean * sg_r) + bw8_r;
    if (lane < 8) sc2_s[lane][k] = zf;
  }
  __syncthreads();

  // ---- cross-wave A combine into gw_s region (float4)
  for (int wv = 0; wv < 4; ++wv) {
    if (w == wv) {
#pragma unroll
      for (int hh = 0; hh < 8; ++hh) {
        float4* p0 = (float4*)&gw_s[hh][j0];
        float4* p1 = (float4*)&gw_s[hh][j1];
        const float4 a0 = make_float4(A[hh][0], A[hh][1], A[hh][2], A[hh][3]);
        const float4 a1 = make_float4(A[hh][4], A[hh][5], A[hh][6], A[hh][7]);
        if (wv == 0) { *p0 = a0; *p1 = a1; }
        else {
          float4 v0 = *p0, v1 = *p1;
          v0.x += a0.x; v0.y += a0.y; v0.z += a0.z; v0.w += a0.w;
          v1.x += a1.x; v1.y += a1.y; v1.z += a1.z; v1.w += a1.w;
          *p0 = v0; *p1 = v1;
        }
      }
    }
    __syncthreads();
  }

  if (tid < 8) {
    float Bt = 0.f, Lt = 0.f;
    for (int wv = 0; wv < 4; ++wv) { Bt += wstatB[wv][tid]; Lt += wstatL[wv][tid]; }
    float den = Lt;
#pragma unroll
    for (int k = 0; k < 5; ++k) {
      const float e = __expf(sc2_s[tid][k]);
      e2_s[tid][k] = e; den += e;
    }
    Bt_s[tid] = Bt; Lt_s[tid] = Lt; inv_s[tid] = 1.f / den;
  }
  __syncthreads();

  // ---- u[hh][j] (bf16) = ((g*(A-B) + b*L + sum_k e2*h2) / den)
  __hip_bfloat16* dst = u_out + (size_t)n * 4096;
  for (int bidx = tid * 4; bidx < 4096; bidx += 1024) {
    const int hh = bidx >> 9, j = bidx & 511;
    const float4 a4 = *(const float4*)&gw_s[hh][j];
    const float4 g4 = *(const float4*)&g_s[j];
    const float4 b4 = *(const float4*)&b_s[j];
    const float Bt = Bt_s[hh], Lt = Lt_s[hh];
    float v0 = (a4.x - Bt) * g4.x + Lt * b4.x;
    float v1 = (a4.y - Bt) * g4.y + Lt * b4.y;
    float v2 = (a4.z - Bt) * g4.z + Lt * b4.z;
    float v3 = (a4.w - Bt) * g4.w + Lt * b4.w;
#pragma unroll
    for (int k = 0; k < 5; ++k) {
      const s16x4 hq = *(const s16x4*)&h2_s[k][j];
      const float e = e2_s[hh][k];
      v0 += e * bfs2f(hq[0]); v1 += e * bfs2f(hq[1]);
      v2 += e * bfs2f(hq[2]); v3 += e * bfs2f(hq[3]);
    }
    const float iv = inv_s[hh];
    s16x4 o;
    o[0] = f2bf(v0 * iv); o[1] = f2bf(v1 * iv);
    o[2] = f2bf(v2 * iv); o[3] = f2bf(v3 * iv);
    *(s16x4*)&dst[bidx] = o;
  }
}

// ---------------------------------------------------------------------------
extern "C" void kernel_launch(void* const* d_in, const int* in_sizes, int n_in,
                              void* d_out, int out_size, void* d_ws, size_t ws_size,
                              hipStream_t stream)
{
  const float* images = (const float*)d_in[0];
  const float* W_img  = (const float*)d_in[1];
  const float* ctx    = (const float*)d_in[2];
  const float* cls    = (const float*)d_in[3];
  const float* ln_g   = (const float*)d_in[4];
  const float* ln_b   = (const float*)d_in[5];
  const float* Wq     = (const float*)d_in[6];
  const float* Wk     = (const float*)d_in[7];
  const float* Wv     = (const float*)d_in[8];
  const float* Wo     = (const float*)d_in[9];
  const float* tproj  = (const float*)d_in[10];
  const float* lscale = (const float*)d_in[11];

  __hip_bfloat16* wtu = (__hip_bfloat16*)d_ws;  // wt -> u (bf16, in place)
  float* fws  = (float*)d_ws;
  float* img  = fws + 2048000;
  float* hlO  = img + 131072;       // O
  float* qo2  = hlO + 512000;       // q -> out2
  float* txt  = fws;                // alias over dead u region
  (void)in_sizes; (void)n_in; (void)out_size; (void)ws_size;

  // 1) image embedding (bf16 MFMA), unnormalized (logits_k normalizes)
  gemm_mfma_k<0,0,0,0><<<dim3(8,4,1),256,0,stream>>>(images,768,0, W_img,512,0,
      img,512,0, nullptr,0, 256,512,768);

  // 2) q = LN(cls_last) @ Wq  (LN fused into staging)
  gemm_mfma_lnA_k<<<dim3(8,16),256,0,stream>>>(cls + 71*512, 72*512,
      ln_g, ln_b, Wq,512, qo2,512, 1000,512,512);

  // 3) wt = per-head q @ Wk^T  -> bf16
  gemm_mfma_k<1,0,0,1><<<dim3(8,16,8),256,0,stream>>>(qo2,512,64, Wk,512,64,
      wtu,4096,512, nullptr,0, 1000,512,64);

  // 4+5) fused pass1+pass2 sweep -> u bf16 (in place over wt)
  fused_sweep_kernel<<<1000,256,0,stream>>>(ctx, cls, ln_g, ln_b, wtu, wtu);

  // 6) O = per-head u @ Wv  (A read directly as bf16)
  gemm_mfma_k<0,0,1,0><<<dim3(1,16,8),256,0,stream>>>(wtu,4096,512, Wv,512,64,
      hlO,512,64, nullptr,0, 1000,64,512);

  // 7) out2 = cls_last + O @ Wo ; txt = out2 @ text_proj  (bf16 MFMA)
  gemm_mfma_k<0,1,0,0><<<dim3(8,16,1),256,0,stream>>>(hlO,512,0, Wo,512,0,
      qo2,512,0, cls + 71*512, 72*512, 1000,512,512);
  gemm_mfma_k<0,0,0,0><<<dim3(8,16,1),256,0,stream>>>(qo2,512,0, tproj,512,0,
      txt,512,0, nullptr,0, 1000,512,512);

  // 8) logits = exp(ls) * (img/|img|) @ (txt/|txt|)^T  (norms fused, f32)
  logits_k<<<dim3(16,8),256,0,stream>>>(img,512, txt,512,
      (float*)d_out,1000, lscale, 256,1000,512);
}

// Round 12
// 153.983 us; speedup vs baseline: 2.5273x; 1.0552x over previous
//
#include <hip/hip_runtime.h>
#include <hip/hip_bf16.h>

#define DEV static __device__ __forceinline__

typedef __attribute__((ext_vector_type(8))) short bf16x8;
typedef __attribute__((ext_vector_type(4))) short s16x4;
typedef __attribute__((ext_vector_type(4))) float f32x4;

DEV float wsum(float v) {
  v += __shfl_xor(v, 1);  v += __shfl_xor(v, 2);  v += __shfl_xor(v, 4);
  v += __shfl_xor(v, 8);  v += __shfl_xor(v, 16); v += __shfl_xor(v, 32);
  return v;
}
DEV float wmaxr(float v) {
  v = fmaxf(v, __shfl_xor(v, 1));  v = fmaxf(v, __shfl_xor(v, 2));
  v = fmaxf(v, __shfl_xor(v, 4));  v = fmaxf(v, __shfl_xor(v, 8));
  v = fmaxf(v, __shfl_xor(v, 16)); v = fmaxf(v, __shfl_xor(v, 32));
  return v;
}
DEV short f2bf(float x) {
  __hip_bfloat16 h = __float2bfloat16(x);
  return *reinterpret_cast<short*>(&h);
}
DEV float bf2f(unsigned int u) {
  const unsigned int x = u << 16;
  return __uint_as_float(x);
}
DEV float bfs2f(short s) {   // short (bf16 bits) -> float
  const unsigned int x = ((unsigned int)(unsigned short)s) << 16;
  return __uint_as_float(x);
}

// Fold-reduce 8 per-lane values across 64 lanes -> full sum of head (lane&7).
DEV float fold8(const float v[8], int lane) {
  float w4[4];
#pragma unroll
  for (int j = 0; j < 4; ++j) {
    const float mine  = (lane & 1) ? v[2 * j + 1] : v[2 * j];
    const float other = (lane & 1) ? v[2 * j]     : v[2 * j + 1];
    w4[j] = mine + __shfl_xor(other, 1);
  }
  float u2[2];
#pragma unroll
  for (int j = 0; j < 2; ++j) {
    const float mine  = (lane & 2) ? w4[2 * j + 1] : w4[2 * j];
    const float other = (lane & 2) ? w4[2 * j]     : w4[2 * j + 1];
    u2[j] = mine + __shfl_xor(other, 2);
  }
  const float mine  = (lane & 4) ? u2[1] : u2[0];
  const float other = (lane & 4) ? u2[0] : u2[1];
  float z = mine + __shfl_xor(other, 4);
  z += __shfl_xor(z, 8); z += __shfl_xor(z, 16); z += __shfl_xor(z, 32);
  return z;
}

// ---------------------------------------------------------------------------
// Unified bf16 MFMA GEMM: depth-2 register prefetch + LDS DOUBLE BUFFER.
// One __syncthreads per 32-K step (was 2): stage(buf b) and compute(buf b^1)
// share the inter-barrier window. Hazard audit: stage(b,i) vs compute(b,i-2)
// separated by bar(i-1); compute(b,i) reads after bar(i).
// K must be a multiple of 64 (call sites: 64/512/768).
// ---------------------------------------------------------------------------
template <int TRANSB, int ADDD, int ABF16, int OUTBF16>
__global__ __launch_bounds__(256) void gemm_mfma_k(
    const void* __restrict__ Av, int lda, long long bsA,
    const float* __restrict__ B, int ldb, long long bsB,
    void* __restrict__ Cv, int ldc, long long bsC,
    const float* __restrict__ D, long long ldd,
    int M, int N, int K)
{
  const float* Af = (const float*)Av + (ABF16 ? 0 : (size_t)blockIdx.z * bsA);
  const short* Ah = (const short*)Av + (ABF16 ? (size_t)blockIdx.z * bsA : 0);
  B += (size_t)blockIdx.z * bsB;
  const int m0 = blockIdx.y * 64, n0 = blockIdx.x * 64;
  const int tid = threadIdx.x;
  const int w = tid >> 6, lane = tid & 63;
  const int wr = w >> 1, wc = w & 1;
  __shared__ __attribute__((aligned(16))) short As[2][64][40];
  __shared__ __attribute__((aligned(16))) short Bs[2][64][40];
  f32x4 acc[2][2] = {};

  const int ar = tid >> 2, akc = (tid & 3) * 8;
  const int br = tid >> 3, bnc = (tid & 7) * 8;
  const bool arv = (m0 + ar < M);
  const int rbase = wr * 32 + (lane & 15);
  const int cbase = wc * 32 + (lane & 15);
  const int kb = (lane >> 4) * 8;

  auto gload = [&](int k0, float4& a0, float4& a1, bf16x8& ah,
                   float4& b0, float4& b1) {
    if (ABF16) {
      ah = bf16x8{};
      if (arv) ah = *(const bf16x8*)(Ah + (size_t)(m0 + ar) * lda + k0 + akc);
    } else {
      a0 = make_float4(0.f, 0.f, 0.f, 0.f); a1 = a0;
      if (arv) {
        a0 = *(const float4*)(Af + (size_t)(m0 + ar) * lda + k0 + akc);
        a1 = *(const float4*)(Af + (size_t)(m0 + ar) * lda + k0 + akc + 4);
      }
    }
    if (TRANSB) {
      b0 = *(const float4*)(B + (size_t)(n0 + ar) * ldb + k0 + akc);
      b1 = *(const float4*)(B + (size_t)(n0 + ar) * ldb + k0 + akc + 4);
    } else {
      b0 = *(const float4*)(B + (size_t)(k0 + br) * ldb + n0 + bnc);
      b1 = *(const float4*)(B + (size_t)(k0 + br) * ldb + n0 + bnc + 4);
    }
  };
  auto stage = [&](int buf, const float4& a0, const float4& a1, const bf16x8& ah,
                   const float4& b0, const float4& b1) {
    if (ABF16) {
      *(bf16x8*)&As[buf][ar][akc] = ah;
    } else {
      bf16x8 av;
      av[0] = f2bf(a0.x); av[1] = f2bf(a0.y); av[2] = f2bf(a0.z); av[3] = f2bf(a0.w);
      av[4] = f2bf(a1.x); av[5] = f2bf(a1.y); av[6] = f2bf(a1.z); av[7] = f2bf(a1.w);
      *(bf16x8*)&As[buf][ar][akc] = av;
    }
    if (TRANSB) {
      bf16x8 bv;
      bv[0] = f2bf(b0.x); bv[1] = f2bf(b0.y); bv[2] = f2bf(b0.z); bv[3] = f2bf(b0.w);
      bv[4] = f2bf(b1.x); bv[5] = f2bf(b1.y); bv[6] = f2bf(b1.z); bv[7] = f2bf(b1.w);
      *(bf16x8*)&Bs[buf][ar][akc] = bv;
    } else {
      Bs[buf][bnc + 0][br] = f2bf(b0.x); Bs[buf][bnc + 1][br] = f2bf(b0.y);
      Bs[buf][bnc + 2][br] = f2bf(b0.z); Bs[buf][bnc + 3][br] = f2bf(b0.w);
      Bs[buf][bnc + 4][br] = f2bf(b1.x); Bs[buf][bnc + 5][br] = f2bf(b1.y);
      Bs[buf][bnc + 6][br] = f2bf(b1.z); Bs[buf][bnc + 7][br] = f2bf(b1.w);
    }
  };
  auto compute = [&](int buf) {
    bf16x8 af0 = *(const bf16x8*)&As[buf][rbase][kb];
    bf16x8 af1 = *(const bf16x8*)&As[buf][rbase + 16][kb];
    bf16x8 bf0 = *(const bf16x8*)&Bs[buf][cbase][kb];
    bf16x8 bf1 = *(const bf16x8*)&Bs[buf][cbase + 16][kb];
    acc[0][0] = __builtin_amdgcn_mfma_f32_16x16x32_bf16(af0, bf0, acc[0][0], 0, 0, 0);
    acc[0][1] = __builtin_amdgcn_mfma_f32_16x16x32_bf16(af0, bf1, acc[0][1], 0, 0, 0);
    acc[1][0] = __builtin_amdgcn_mfma_f32_16x16x32_bf16(af1, bf0, acc[1][0], 0, 0, 0);
    acc[1][1] = __builtin_amdgcn_mfma_f32_16x16x32_bf16(af1, bf1, acc[1][1], 0, 0, 0);
  };

  float4 a0A, a1A, b0A, b1A, a0B, a1B, b0B, b1B;
  bf16x8 ahA = {}, ahB = {};
  gload(0, a0A, a1A, ahA, b0A, b1A);
  gload(32, a0B, a1B, ahB, b0B, b1B);
  for (int k0 = 0; k0 < K; k0 += 64) {
    // step even: buffer 0, reg set A
    stage(0, a0A, a1A, ahA, b0A, b1A);
    if (k0 + 64 < K) gload(k0 + 64, a0A, a1A, ahA, b0A, b1A);
    __syncthreads();
    compute(0);
    // step odd: buffer 1, reg set B
    stage(1, a0B, a1B, ahB, b0B, b1B);
    if (k0 + 96 < K) gload(k0 + 96, a0B, a1B, ahB, b0B, b1B);
    __syncthreads();
    compute(1);
  }

  const size_t cb = (size_t)blockIdx.z * (size_t)bsC;
#pragma unroll
  for (int mi = 0; mi < 2; ++mi)
#pragma unroll
    for (int ni = 0; ni < 2; ++ni)
#pragma unroll
      for (int r = 0; r < 4; ++r) {
        const int row = m0 + wr * 32 + mi * 16 + (lane >> 4) * 4 + r;
        const int col = n0 + wc * 32 + ni * 16 + (lane & 15);
        if (row < M) {
          float v = acc[mi][ni][r];
          if (ADDD) v += D[(size_t)row * ldd + col];
          if (OUTBF16)
            ((__hip_bfloat16*)Cv)[cb + (size_t)row * ldc + col] = __float2bfloat16(v);
          else
            ((float*)Cv)[cb + (size_t)row * ldc + col] = v;
        }
      }
}

// ---------------------------------------------------------------------------
// bf16 MFMA GEMM with LayerNorm fused on A, depth-2 prefetch + LDS dbuf.
// ---------------------------------------------------------------------------
__global__ __launch_bounds__(256) void gemm_mfma_lnA_k(
    const float* __restrict__ A, long long lda,
    const float* __restrict__ g, const float* __restrict__ b,
    const float* __restrict__ B, int ldb,
    float* __restrict__ C, int ldc,
    int M, int N, int K)
{
  const int m0 = blockIdx.y * 64, n0 = blockIdx.x * 64;
  const int tid = threadIdx.x;
  const int w = tid >> 6, lane = tid & 63;
  const int wr = w >> 1, wc = w & 1;
  __shared__ __attribute__((aligned(16))) short As[2][64][40];
  __shared__ __attribute__((aligned(16))) short Bs[2][64][40];
  __shared__ __attribute__((aligned(16))) float g_s[512], b_s[512];
  __shared__ float mean_s[64], rstd_s[64];
  f32x4 acc[2][2] = {};

  if (tid < 128) ((float4*)g_s)[tid] = ((const float4*)g)[tid];
  else ((float4*)b_s)[tid - 128] = ((const float4*)b)[tid - 128];

  {
    const int r = tid >> 2, p = tid & 3;
    float s = 0.f, ss = 0.f;
    if (m0 + r < M) {
      const float4* src = (const float4*)(A + (size_t)(m0 + r) * lda + p * 128);
#pragma unroll 8
      for (int i = 0; i < 32; ++i) {
        const float4 v = src[i];
        s += v.x + v.y + v.z + v.w;
        ss += v.x * v.x + v.y * v.y + v.z * v.z + v.w * v.w;
      }
    }
    s += __shfl_xor(s, 1);  s += __shfl_xor(s, 2);
    ss += __shfl_xor(ss, 1); ss += __shfl_xor(ss, 2);
    if (p == 0) {
      const float mean = s * (1.f / 512.f);
      mean_s[r] = mean;
      rstd_s[r] = rsqrtf(ss * (1.f / 512.f) - mean * mean + 1e-5f);
    }
  }
  __syncthreads();

  const int ar = tid >> 2, akc = (tid & 3) * 8;
  const int br = tid >> 3, bnc = (tid & 7) * 8;
  const bool arv = (m0 + ar < M);
  const int rbase = wr * 32 + (lane & 15);
  const int cbase = wc * 32 + (lane & 15);
  const int kb = (lane >> 4) * 8;

  auto gload = [&](int k0, float4& a0, float4& a1, float4& b0, float4& b1) {
    a0 = make_float4(0.f, 0.f, 0.f, 0.f); a1 = a0;
    if (arv) {
      a0 = *(const float4*)(A + (size_t)(m0 + ar) * lda + k0 + akc);
      a1 = *(const float4*)(A + (size_t)(m0 + ar) * lda + k0 + akc + 4);
    }
    b0 = *(const float4*)(B + (size_t)(k0 + br) * ldb + n0 + bnc);
    b1 = *(const float4*)(B + (size_t)(k0 + br) * ldb + n0 + bnc + 4);
  };
  auto stage = [&](int buf, int k0, const float4& a0, const float4& a1,
                   const float4& b0, const float4& b1) {
    const float mn = mean_s[ar], rs = rstd_s[ar];
    const int kc = k0 + akc;
    bf16x8 av;
    av[0] = f2bf((a0.x - mn) * rs * g_s[kc + 0] + b_s[kc + 0]);
    av[1] = f2bf((a0.y - mn) * rs * g_s[kc + 1] + b_s[kc + 1]);
    av[2] = f2bf((a0.z - mn) * rs * g_s[kc + 2] + b_s[kc + 2]);
    av[3] = f2bf((a0.w - mn) * rs * g_s[kc + 3] + b_s[kc + 3]);
    av[4] = f2bf((a1.x - mn) * rs * g_s[kc + 4] + b_s[kc + 4]);
    av[5] = f2bf((a1.y - mn) * rs * g_s[kc + 5] + b_s[kc + 5]);
    av[6] = f2bf((a1.z - mn) * rs * g_s[kc + 6] + b_s[kc + 6]);
    av[7] = f2bf((a1.w - mn) * rs * g_s[kc + 7] + b_s[kc + 7]);
    *(bf16x8*)&As[buf][ar][akc] = av;
    Bs[buf][bnc + 0][br] = f2bf(b0.x); Bs[buf][bnc + 1][br] = f2bf(b0.y);
    Bs[buf][bnc + 2][br] = f2bf(b0.z); Bs[buf][bnc + 3][br] = f2bf(b0.w);
    Bs[buf][bnc + 4][br] = f2bf(b1.x); Bs[buf][bnc + 5][br] = f2bf(b1.y);
    Bs[buf][bnc + 6][br] = f2bf(b1.z); Bs[buf][bnc + 7][br] = f2bf(b1.w);
  };
  auto compute = [&](int buf) {
    bf16x8 af0 = *(const bf16x8*)&As[buf][rbase][kb];
    bf16x8 af1 = *(const bf16x8*)&As[buf][rbase + 16][kb];
    bf16x8 bf0 = *(const bf16x8*)&Bs[buf][cbase][kb];
    bf16x8 bf1 = *(const bf16x8*)&Bs[buf][cbase + 16][kb];
    acc[0][0] = __builtin_amdgcn_mfma_f32_16x16x32_bf16(af0, bf0, acc[0][0], 0, 0, 0);
    acc[0][1] = __builtin_amdgcn_mfma_f32_16x16x32_bf16(af0, bf1, acc[0][1], 0, 0, 0);
    acc[1][0] = __builtin_amdgcn_mfma_f32_16x16x32_bf16(af1, bf0, acc[1][0], 0, 0, 0);
    acc[1][1] = __builtin_amdgcn_mfma_f32_16x16x32_bf16(af1, bf1, acc[1][1], 0, 0, 0);
  };

  float4 a0A, a1A, b0A, b1A, a0B, a1B, b0B, b1B;
  gload(0, a0A, a1A, b0A, b1A);
  gload(32, a0B, a1B, b0B, b1B);
  for (int k0 = 0; k0 < K; k0 += 64) {
    stage(0, k0, a0A, a1A, b0A, b1A);
    if (k0 + 64 < K) gload(k0 + 64, a0A, a1A, b0A, b1A);
    __syncthreads();
    compute(0);
    stage(1, k0 + 32, a0B, a1B, b0B, b1B);
    if (k0 + 96 < K) gload(k0 + 96, a0B, a1B, b0B, b1B);
    __syncthreads();
    compute(1);
  }

#pragma unroll
  for (int mi = 0; mi < 2; ++mi)
#pragma unroll
    for (int ni = 0; ni < 2; ++ni)
#pragma unroll
      for (int r = 0; r < 4; ++r) {
        const int row = m0 + wr * 32 + mi * 16 + (lane >> 4) * 4 + r;
        const int col = n0 + wc * 32 + ni * 16 + (lane & 15);
        if (row < M) C[(size_t)row * ldc + col] = acc[mi][ni][r];
      }
}

// ---------------------------------------------------------------------------
// Logits GEMM with fused L2 norms (unchanged — already double-buffered).
// ---------------------------------------------------------------------------
__global__ __launch_bounds__(256) void logits_k(
    const float* __restrict__ A, int lda,
    const float* __restrict__ B, int ldb,
    float* __restrict__ C, int ldc,
    const float* __restrict__ alpha_ptr,
    int M, int N, int K)
{
  const int m0 = blockIdx.y * 32, n0 = blockIdx.x * 64;
  const int tid = threadIdx.x;
  __shared__ __attribute__((aligned(16))) float As[2][16][36];
  __shared__ __attribute__((aligned(16))) float Bs[2][16][68];
  __shared__ float nA[32], nB[64];
  float acc[2][4] = {};
  float ssA = 0.f, ssB = 0.f;
  const int ty = tid >> 4, tx = tid & 15;
  const int am = tid >> 3, ak = (tid & 7) * 2;
  const int bm = tid >> 2, bt = (tid & 3) * 4;
  const bool aval = (m0 + am < M);
  const bool bval = (n0 + bm < N);

  float2 av; float4 bv;
  auto gload = [&](int k0) {
    av = make_float2(0.f, 0.f);
    bv = make_float4(0.f, 0.f, 0.f, 0.f);
    if (aval) av = *(const float2*)(A + (size_t)(m0 + am) * lda + (k0 + ak));
    if (bval) bv = *(const float4*)(B + (size_t)(n0 + bm) * ldb + (k0 + bt));
    ssA += av.x * av.x + av.y * av.y;
    ssB += bv.x * bv.x + bv.y * bv.y + bv.z * bv.z + bv.w * bv.w;
  };
  auto sstore = [&](int buf) {
    As[buf][ak][am] = av.x; As[buf][ak + 1][am] = av.y;
    Bs[buf][bt + 0][bm] = bv.x; Bs[buf][bt + 1][bm] = bv.y;
    Bs[buf][bt + 2][bm] = bv.z; Bs[buf][bt + 3][bm] = bv.w;
  };

  const int nIt = K >> 4;
  gload(0); sstore(0);
  for (int it = 0; it < nIt; ++it) {
    __syncthreads();
    if (it + 1 < nIt) gload((it + 1) << 4);
    const int buf = it & 1;
#pragma unroll
    for (int kk = 0; kk < 16; ++kk) {
      const float2 a  = *(const float2*)&As[buf][kk][ty * 2];
      const float4 bq = *(const float4*)&Bs[buf][kk][tx * 4];
      acc[0][0] += a.x * bq.x; acc[0][1] += a.x * bq.y; acc[0][2] += a.x * bq.z; acc[0][3] += a.x * bq.w;
      acc[1][0] += a.y * bq.x; acc[1][1] += a.y * bq.y; acc[1][2] += a.y * bq.z; acc[1][3] += a.y * bq.w;
    }
    if (it + 1 < nIt) sstore((it + 1) & 1);
  }

  ssA += __shfl_xor(ssA, 1); ssA += __shfl_xor(ssA, 2); ssA += __shfl_xor(ssA, 4);
  if ((tid & 7) == 0) nA[am] = rsqrtf(ssA);
  ssB += __shfl_xor(ssB, 1); ssB += __shfl_xor(ssB, 2);
  if ((tid & 3) == 0) nB[bm] = rsqrtf(ssB);
  __syncthreads();

  const float alpha = __expf(alpha_ptr[0]);
#pragma unroll
  for (int i = 0; i < 2; ++i) {
    const int m = m0 + ty * 2 + i;
    if (m >= M) continue;
    const float fa = alpha * nA[ty * 2 + i];
#pragma unroll
    for (int j = 0; j < 4; ++j) {
      const int nn = n0 + tx * 4 + j;
      if (nn < N) C[(size_t)m * ldc + nn] = acc[i][j] * fa * nB[tx * 4 + j];
    }
  }
}

// ---------------------------------------------------------------------------
// FUSED sweep v7 (unchanged from round 11 — 90 us, frozen after 6 nulls;
// VALU-work floor ~31 us requires MFMA restructure, not micro-opts).
// ---------------------------------------------------------------------------
__global__ __launch_bounds__(256) void fused_sweep_kernel(
    const float* __restrict__ ctx, const float* __restrict__ cls,
    const float* __restrict__ g, const float* __restrict__ b,
    const __hip_bfloat16* __restrict__ wt, __hip_bfloat16* __restrict__ u_out)
{
  const int n = blockIdx.x, tid = threadIdx.x;
  const int w = tid >> 6, lane = tid & 63;
  __shared__ __attribute__((aligned(16))) float gw_s[8][512];
  __shared__ __attribute__((aligned(16))) float g_s[512], b_s[512];
  __shared__ __attribute__((aligned(16))) short h2_s[5][512];   // bf16 h2
  __shared__ float sc_s[8][80];
  __shared__ float sc2_s[8][5];
  __shared__ float ah_s[8][5];
  __shared__ float wstatB[4][8], wstatL[4][8];
  __shared__ float attr_s[5];
  __shared__ float Sgw_l[8], bw_l[8];
  __shared__ float Bt_s[8], Lt_s[8], inv_s[8];
  __shared__ float e2_s[8][5];
  __shared__ __attribute__((aligned(16))) float es_s[4][2][8];

  {
    const uint4* wsrc = (const uint4*)(wt + (size_t)n * 4096);  // 8 bf16 per uint4
    float4* gwf = (float4*)&gw_s[0][0];
    for (int i = tid; i < 512; i += 256) {
      const uint4 v = wsrc[i];
      gwf[i * 2]     = make_float4(bf2f(v.x & 0xffffu), bf2f(v.x >> 16),
                                   bf2f(v.y & 0xffffu), bf2f(v.y >> 16));
      gwf[i * 2 + 1] = make_float4(bf2f(v.z & 0xffffu), bf2f(v.z >> 16),
                                   bf2f(v.w & 0xffffu), bf2f(v.w >> 16));
    }
    if (tid < 128) ((float4*)g_s)[tid] = ((const float4*)g)[tid];
    else ((float4*)b_s)[tid - 128] = ((const float4*)b)[tid - 128];
  }
  __syncthreads();

  for (int hh = w; hh < 8; hh += 4) {
    float s1 = 0.f, s2 = 0.f;
#pragma unroll
    for (int i = 0; i < 8; ++i) {
      const int j = lane + 64 * i;
      const float wv = gw_s[hh][j];
      const float gv = wv * g_s[j];
      s1 += gv; s2 += wv * b_s[j];
      gw_s[hh][j] = gv;
    }
    s1 = wsum(s1); s2 = wsum(s2);
    if (lane == 0) { Sgw_l[hh] = s1; bw_l[hh] = s2; }
  }
  __syncthreads();
  const float sg_r  = Sgw_l[lane & 7];
  const float bw8_r = bw_l[lane & 7] * 0.125f;
  const int j0 = lane * 4, j1 = lane * 4 + 256;

  // ---- stage A: 5 unscaled ctx rows (global reads) -> pass-1 scores
  for (int k = w; k < 5; k += 4) {
    const float* src = ctx + ((size_t)n * 5 + k) * 512;
    const float4 x0 = *(const float4*)(src + j0);
    const float4 x1 = *(const float4*)(src + j1);
    float s  = x0.x + x0.y + x0.z + x0.w + x1.x + x1.y + x1.z + x1.w;
    float ss = x0.x * x0.x + x0.y * x0.y + x0.z * x0.z + x0.w * x0.w
             + x1.x * x1.x + x1.y * x1.y + x1.z * x1.z + x1.w * x1.w;
    float v8[8] = {};
#pragma unroll
    for (int hh = 0; hh < 8; ++hh) {
      const float4 w0 = *(const float4*)&gw_s[hh][j0];
      const float4 w1 = *(const float4*)&gw_s[hh][j1];
      v8[hh] = x0.x * w0.x + x0.y * w0.y + x0.z * w0.z + x0.w * w0.w
             + x1.x * w1.x + x1.y * w1.y + x1.z * w1.z + x1.w * w1.w;
    }
    s = wsum(s); ss = wsum(ss);
    const float mean = s * (1.f / 512.f);
    const float rstd = rsqrtf(ss * (1.f / 512.f) - mean * mean + 1e-5f);
    const float z = fold8(v8, lane);
    const float zf = rstd * 0.125f * (z - mean * sg_r) + bw8_r;
    if (lane < 8) sc_s[lane][k] = zf;
  }

  // ---- stage B: 72 cls rows, 9 pairs/wave, prefetch depth 2
  float A[8][8];
#pragma unroll
  for (int hh = 0; hh < 8; ++hh)
#pragma unroll
    for (int i = 0; i < 8; ++i) A[hh][i] = 0.f;
  float B8[8] = {}, L8[8] = {};

  const float* base = cls + (size_t)n * 72 * 512;
  float4 xa0, xa1, xb0, xb1, ya0, ya1, yb0, yb1;
  {
    const float* sA = base + (size_t)w * 512;
    const float* sB = base + (size_t)(w + 4) * 512;
    xa0 = *(const float4*)(sA + j0); xa1 = *(const float4*)(sA + j1);
    xb0 = *(const float4*)(sB + j0); xb1 = *(const float4*)(sB + j1);
    const float* sA1 = base + (size_t)(w + 8) * 512;
    const float* sB1 = base + (size_t)(w + 12) * 512;
    ya0 = *(const float4*)(sA1 + j0); ya1 = *(const float4*)(sA1 + j1);
    yb0 = *(const float4*)(sB1 + j0); yb1 = *(const float4*)(sB1 + j1);
  }
  for (int p = 0; p < 9; ++p) {
    float4 za0, za1, zb0, zb1;
    const bool more2 = (p + 2 < 9);
    if (more2) {
      const float* sA = base + (size_t)(w + 8 * (p + 2)) * 512;
      const float* sB = base + (size_t)(w + 4 + 8 * (p + 2)) * 512;
      za0 = *(const float4*)(sA + j0); za1 = *(const float4*)(sA + j1);
      zb0 = *(const float4*)(sB + j0); zb1 = *(const float4*)(sB + j1);
    }
    float sa = xa0.x + xa0.y + xa0.z + xa0.w + xa1.x + xa1.y + xa1.z + xa1.w;
    float ssa = xa0.x * xa0.x + xa0.y * xa0.y + xa0.z * xa0.z + xa0.w * xa0.w
              + xa1.x * xa1.x + xa1.y * xa1.y + xa1.z * xa1.z + xa1.w * xa1.w;
    float sb = xb0.x + xb0.y + xb0.z + xb0.w + xb1.x + xb1.y + xb1.z + xb1.w;
    float ssb = xb0.x * xb0.x + xb0.y * xb0.y + xb0.z * xb0.z + xb0.w * xb0.w
              + xb1.x * xb1.x + xb1.y * xb1.y + xb1.z * xb1.z + xb1.w * xb1.w;
    float v8a[8], v8b[8];
#pragma unroll
    for (int hh = 0; hh < 8; ++hh) {
      const float4 w0 = *(const float4*)&gw_s[hh][j0];
      const float4 w1 = *(const float4*)&gw_s[hh][j1];
      v8a[hh] = xa0.x * w0.x + xa0.y * w0.y + xa0.z * w0.z + xa0.w * w0.w
              + xa1.x * w1.x + xa1.y * w1.y + xa1.z * w1.z + xa1.w * w1.w;
      v8b[hh] = xb0.x * w0.x + xb0.y * w0.y + xb0.z * w0.z + xb0.w * w0.w
              + xb1.x * w1.x + xb1.y * w1.y + xb1.z * w1.z + xb1.w * w1.w;
    }
    sa = wsum(sa); ssa = wsum(ssa); sb = wsum(sb); ssb = wsum(ssb);
    const float meanA = sa * (1.f / 512.f);
    const float rstdA = rsqrtf(ssa * (1.f / 512.f) - meanA * meanA + 1e-5f);
    const float meanB = sb * (1.f / 512.f);
    const float rstdB = rsqrtf(ssb * (1.f / 512.f) - meanB * meanB + 1e-5f);
    const float za = fold8(v8a, lane);
    const float zb = fold8(v8b, lane);
    const float zfa = rstdA * 0.125f * (za - meanA * sg_r) + bw8_r;
    const float zfb = rstdB * 0.125f * (zb - meanB * sg_r) + bw8_r;
    const int kA = 5 + w + 8 * p;
    if (lane < 8) {
      sc_s[lane][kA] = zfa; sc_s[lane][kA + 4] = zfb;
      es_s[w][0][lane] = __expf(zfa);
      es_s[w][1][lane] = __expf(zfb);
    }
    __builtin_amdgcn_wave_barrier();
    const float4 ea0 = *(const float4*)&es_s[w][0][0];
    const float4 ea1 = *(const float4*)&es_s[w][0][4];
    const float4 eb0 = *(const float4*)&es_s[w][1][0];
    const float4 eb1 = *(const float4*)&es_s[w][1][4];
    const float esa[8] = {ea0.x, ea0.y, ea0.z, ea0.w, ea1.x, ea1.y, ea1.z, ea1.w};
    const float esb[8] = {eb0.x, eb0.y, eb0.z, eb0.w, eb1.x, eb1.y, eb1.z, eb1.w};
#pragma unroll
    for (int hh = 0; hh < 8; ++hh) {
      const float erA = esa[hh] * rstdA;
      const float erB = esb[hh] * rstdB;
      A[hh][0] += erA * xa0.x; A[hh][1] += erA * xa0.y;
      A[hh][2] += erA * xa0.z; A[hh][3] += erA * xa0.w;
      A[hh][4] += erA * xa1.x; A[hh][5] += erA * xa1.y;
      A[hh][6] += erA * xa1.z; A[hh][7] += erA * xa1.w;
      B8[hh] += erA * meanA;
      L8[hh] += esa[hh];
      A[hh][0] += erB * xb0.x; A[hh][1] += erB * xb0.y;
      A[hh][2] += erB * xb0.z; A[hh][3] += erB * xb0.w;
      A[hh][4] += erB * xb1.x; A[hh][5] += erB * xb1.y;
      A[hh][6] += erB * xb1.z; A[hh][7] += erB * xb1.w;
      B8[hh] += erB * meanB;
      L8[hh] += esb[hh];
    }
    xa0 = ya0; xa1 = ya1; xb0 = yb0; xb1 = yb1;
    if (more2) { ya0 = za0; ya1 = za1; yb0 = zb0; yb1 = zb1; }
  }
  if (lane == 0)
#pragma unroll
    for (int hh = 0; hh < 8; ++hh) {
      wstatB[w][hh] = B8[hh]; wstatL[w][hh] = L8[hh];
    }
  __syncthreads();

  // ---- pass-1 softmax over 77 -> head-mean of first 5 -> attr
  for (int hh = w; hh < 8; hh += 4) {
    const float v0 = sc_s[hh][lane];
    const float v1 = (lane + 64 < 77) ? sc_s[hh][lane + 64] : -1e30f;
    const float mx = wmaxr(fmaxf(v0, v1));
    const float e0 = __expf(v0 - mx);
    const float e1 = (lane + 64 < 77) ? __expf(v1 - mx) : 0.f;
    const float S = wsum(e0 + e1);
    if (lane < 5) ah_s[hh][lane] = e0 / S;
  }
  __syncthreads();
  if (tid == 0) {
    float m[5], mx = -1e30f;
#pragma unroll
    for (int p = 0; p < 5; ++p) {
      float acc = 0.f;
      for (int hh = 0; hh < 8; ++hh) acc += ah_s[hh][p];
      m[p] = acc * 0.125f;
      mx = fmaxf(mx, m[p]);
    }
    float e[5], S = 0.f;
#pragma unroll
    for (int p = 0; p < 5; ++p) { e[p] = __expf(m[p] - mx); S += e[p]; }
#pragma unroll
    for (int p = 0; p < 5; ++p) attr_s[p] = e[p] / S;
  }
  __syncthreads();

  // ---- stage C: scaled ctx rows (global reads) -> h2 (bf16 LDS) + sc2
  for (int k = w; k < 5; k += 4) {
    const float c = attr_s[k];
    const float* src = ctx + ((size_t)n * 5 + k) * 512;
    float4 x0 = *(const float4*)(src + j0);
    float4 x1 = *(const float4*)(src + j1);
    x0.x *= c; x0.y *= c; x0.z *= c; x0.w *= c;
    x1.x *= c; x1.y *= c; x1.z *= c; x1.w *= c;
    float s  = x0.x + x0.y + x0.z + x0.w + x1.x + x1.y + x1.z + x1.w;
    float ss = x0.x * x0.x + x0.y * x0.y + x0.z * x0.z + x0.w * x0.w
             + x1.x * x1.x + x1.y * x1.y + x1.z * x1.z + x1.w * x1.w;
    float v8[8];
#pragma unroll
    for (int hh = 0; hh < 8; ++hh) {
      const float4 w0 = *(const float4*)&gw_s[hh][j0];
      const float4 w1 = *(const float4*)&gw_s[hh][j1];
      v8[hh] = x0.x * w0.x + x0.y * w0.y + x0.z * w0.z + x0.w * w0.w
             + x1.x * w1.x + x1.y * w1.y + x1.z * w1.z + x1.w * w1.w;
    }
    s = wsum(s); ss = wsum(ss);
    const float mean = s * (1.f / 512.f);
    const float rstd = rsqrtf(ss * (1.f / 512.f) - mean * mean + 1e-5f);
    {
      const float4 gg0 = *(const float4*)&g_s[j0];
      const float4 bb0 = *(const float4*)&b_s[j0];
      const float4 gg1 = *(const float4*)&g_s[j1];
      const float4 bb1 = *(const float4*)&b_s[j1];
      s16x4 o0, o1;
      o0[0] = f2bf((x0.x - mean) * rstd * gg0.x + bb0.x);
      o0[1] = f2bf((x0.y - mean) * rstd * gg0.y + bb0.y);
      o0[2] = f2bf((x0.z - mean) * rstd * gg0.z + bb0.z);
      o0[3] = f2bf((x0.w - mean) * rstd * gg0.w + bb0.w);
      o1[0] = f2bf((x1.x - mean) * rstd * gg1.x + bb1.x);
      o1[1] = f2bf((x1.y - mean) * rstd * gg1.y + bb1.y);
      o1[2] = f2bf((x1.z - mean) * rstd * gg1.z + bb1.z);
      o1[3] = f2bf((x1.w - mean) * rstd * gg1.w + bb1.w);
      *(s16x4*)&h2_s[k][j0] = o0;
      *(s16x4*)&h2_s[k][j1] = o1;
    }
    const float z = fold8(v8, lane);
    const float zf = rstd * 0.125f * (z - mean * sg_r) + bw8_r;
    if (lane < 8) sc2_s[lane][k] = zf;
  }
  __syncthreads();

  // ---- cross-wave A combine into gw_s region (float4)
  for (int wv = 0; wv < 4; ++wv) {
    if (w == wv) {
#pragma unroll
      for (int hh = 0; hh < 8; ++hh) {
        float4* p0 = (float4*)&gw_s[hh][j0];
        float4* p1 = (float4*)&gw_s[hh][j1];
        const float4 a0 = make_float4(A[hh][0], A[hh][1], A[hh][2], A[hh][3]);
        const float4 a1 = make_float4(A[hh][4], A[hh][5], A[hh][6], A[hh][7]);
        if (wv == 0) { *p0 = a0; *p1 = a1; }
        else {
          float4 v0 = *p0, v1 = *p1;
          v0.x += a0.x; v0.y += a0.y; v0.z += a0.z; v0.w += a0.w;
          v1.x += a1.x; v1.y += a1.y; v1.z += a1.z; v1.w += a1.w;
          *p0 = v0; *p1 = v1;
        }
      }
    }
    __syncthreads();
  }

  if (tid < 8) {
    float Bt = 0.f, Lt = 0.f;
    for (int wv = 0; wv < 4; ++wv) { Bt += wstatB[wv][tid]; Lt += wstatL[wv][tid]; }
    float den = Lt;
#pragma unroll
    for (int k = 0; k < 5; ++k) {
      const float e = __expf(sc2_s[tid][k]);
      e2_s[tid][k] = e; den += e;
    }
    Bt_s[tid] = Bt; Lt_s[tid] = Lt; inv_s[tid] = 1.f / den;
  }
  __syncthreads();

  // ---- u[hh][j] (bf16) = ((g*(A-B) + b*L + sum_k e2*h2) / den)
  __hip_bfloat16* dst = u_out + (size_t)n * 4096;
  for (int bidx = tid * 4; bidx < 4096; bidx += 1024) {
    const int hh = bidx >> 9, j = bidx & 511;
    const float4 a4 = *(const float4*)&gw_s[hh][j];
    const float4 g4 = *(const float4*)&g_s[j];
    const float4 b4 = *(const float4*)&b_s[j];
    const float Bt = Bt_s[hh], Lt = Lt_s[hh];
    float v0 = (a4.x - Bt) * g4.x + Lt * b4.x;
    float v1 = (a4.y - Bt) * g4.y + Lt * b4.y;
    float v2 = (a4.z - Bt) * g4.z + Lt * b4.z;
    float v3 = (a4.w - Bt) * g4.w + Lt * b4.w;
#pragma unroll
    for (int k = 0; k < 5; ++k) {
      const s16x4 hq = *(const s16x4*)&h2_s[k][j];
      const float e = e2_s[hh][k];
      v0 += e * bfs2f(hq[0]); v1 += e * bfs2f(hq[1]);
      v2 += e * bfs2f(hq[2]); v3 += e * bfs2f(hq[3]);
    }
    const float iv = inv_s[hh];
    s16x4 o;
    o[0] = f2bf(v0 * iv); o[1] = f2bf(v1 * iv);
    o[2] = f2bf(v2 * iv); o[3] = f2bf(v3 * iv);
    *(s16x4*)&dst[bidx] = o;
  }
}

// ---------------------------------------------------------------------------
extern "C" void kernel_launch(void* const* d_in, const int* in_sizes, int n_in,
                              void* d_out, int out_size, void* d_ws, size_t ws_size,
                              hipStream_t stream)
{
  const float* images = (const float*)d_in[0];
  const float* W_img  = (const float*)d_in[1];
  const float* ctx    = (const float*)d_in[2];
  const float* cls    = (const float*)d_in[3];
  const float* ln_g   = (const float*)d_in[4];
  const float* ln_b   = (const float*)d_in[5];
  const float* Wq     = (const float*)d_in[6];
  const float* Wk     = (const float*)d_in[7];
  const float* Wv     = (const float*)d_in[8];
  const float* Wo     = (const float*)d_in[9];
  const float* tproj  = (const float*)d_in[10];
  const float* lscale = (const float*)d_in[11];

  __hip_bfloat16* wtu = (__hip_bfloat16*)d_ws;  // wt -> u (bf16, in place)
  float* fws  = (float*)d_ws;
  float* img  = fws + 2048000;
  float* hlO  = img + 131072;       // O
  float* qo2  = hlO + 512000;       // q -> out2
  float* txt  = fws;                // alias over dead u region
  (void)in_sizes; (void)n_in; (void)out_size; (void)ws_size;

  // 1) image embedding (bf16 MFMA), unnormalized (logits_k normalizes)
  gemm_mfma_k<0,0,0,0><<<dim3(8,4,1),256,0,stream>>>(images,768,0, W_img,512,0,
      img,512,0, nullptr,0, 256,512,768);

  // 2) q = LN(cls_last) @ Wq  (LN fused into staging)
  gemm_mfma_lnA_k<<<dim3(8,16),256,0,stream>>>(cls + 71*512, 72*512,
      ln_g, ln_b, Wq,512, qo2,512, 1000,512,512);

  // 3) wt = per-head q @ Wk^T  -> bf16
  gemm_mfma_k<1,0,0,1><<<dim3(8,16,8),256,0,stream>>>(qo2,512,64, Wk,512,64,
      wtu,4096,512, nullptr,0, 1000,512,64);

  // 4+5) fused pass1+pass2 sweep -> u bf16 (in place over wt)
  fused_sweep_kernel<<<1000,256,0,stream>>>(ctx, cls, ln_g, ln_b, wtu, wtu);

  // 6) O = per-head u @ Wv  (A read directly as bf16)
  gemm_mfma_k<0,0,1,0><<<dim3(1,16,8),256,0,stream>>>(wtu,4096,512, Wv,512,64,
      hlO,512,64, nullptr,0, 1000,64,512);

  // 7) out2 = cls_last + O @ Wo ; txt = out2 @ text_proj  (bf16 MFMA)
  gemm_mfma_k<0,1,0,0><<<dim3(8,16,1),256,0,stream>>>(hlO,512,0, Wo,512,0,
      qo2,512,0, cls + 71*512, 72*512, 1000,512,512);
  gemm_mfma_k<0,0,0,0><<<dim3(8,16,1),256,0,stream>>>(qo2,512,0, tproj,512,0,
      txt,512,0, nullptr,0, 1000,512,512);

  // 8) logits = exp(ls) * (img/|img|) @ (txt/|txt|)^T  (norms fused, f32)
  logits_k<<<dim3(16,8),256,0,stream>>>(img,512, txt,512,
      (float*)d_out,1000, lscale, 256,1000,512);
}

// Round 13
// 153.383 us; speedup vs baseline: 2.5372x; 1.0039x over previous
//
#include <hip/hip_runtime.h>
#include <hip/hip_bf16.h>

#define DEV static __device__ __forceinline__

typedef __attribute__((ext_vector_type(8))) short bf16x8;
typedef __attribute__((ext_vector_type(4))) short s16x4;
typedef __attribute__((ext_vector_type(4))) float f32x4;
typedef __attribute__((ext_vector_type(2))) float f32x2;

DEV float wsum(float v) {
  v += __shfl_xor(v, 1);  v += __shfl_xor(v, 2);  v += __shfl_xor(v, 4);
  v += __shfl_xor(v, 8);  v += __shfl_xor(v, 16); v += __shfl_xor(v, 32);
  return v;
}
DEV float wmaxr(float v) {
  v = fmaxf(v, __shfl_xor(v, 1));  v = fmaxf(v, __shfl_xor(v, 2));
  v = fmaxf(v, __shfl_xor(v, 4));  v = fmaxf(v, __shfl_xor(v, 8));
  v = fmaxf(v, __shfl_xor(v, 16)); v = fmaxf(v, __shfl_xor(v, 32));
  return v;
}
DEV short f2bf(float x) {
  __hip_bfloat16 h = __float2bfloat16(x);
  return *reinterpret_cast<short*>(&h);
}
DEV float bf2f(unsigned int u) {
  const unsigned int x = u << 16;
  return __uint_as_float(x);
}
DEV float bfs2f(short s) {
  const unsigned int x = ((unsigned int)(unsigned short)s) << 16;
  return __uint_as_float(x);
}
DEV void split4(const float4& v, f32x2& lo, f32x2& hi) {
  lo = f32x2{v.x, v.y}; hi = f32x2{v.z, v.w};
}

// Fold-reduce 8 per-lane values across 64 lanes -> full sum of head (lane&7).
DEV float fold8(const float v[8], int lane) {
  float w4[4];
#pragma unroll
  for (int j = 0; j < 4; ++j) {
    const float mine  = (lane & 1) ? v[2 * j + 1] : v[2 * j];
    const float other = (lane & 1) ? v[2 * j]     : v[2 * j + 1];
    w4[j] = mine + __shfl_xor(other, 1);
  }
  float u2[2];
#pragma unroll
  for (int j = 0; j < 2; ++j) {
    const float mine  = (lane & 2) ? w4[2 * j + 1] : w4[2 * j];
    const float other = (lane & 2) ? w4[2 * j]     : w4[2 * j + 1];
    u2[j] = mine + __shfl_xor(other, 2);
  }
  const float mine  = (lane & 4) ? u2[1] : u2[0];
  const float other = (lane & 4) ? u2[0] : u2[1];
  float z = mine + __shfl_xor(other, 4);
  z += __shfl_xor(z, 8); z += __shfl_xor(z, 16); z += __shfl_xor(z, 32);
  return z;
}

// ---------------------------------------------------------------------------
// Unified bf16 MFMA GEMM: depth-2 register prefetch + LDS double buffer.
// (unchanged from round 12 — HW-validated)
// ---------------------------------------------------------------------------
template <int TRANSB, int ADDD, int ABF16, int OUTBF16>
__global__ __launch_bounds__(256) void gemm_mfma_k(
    const void* __restrict__ Av, int lda, long long bsA,
    const float* __restrict__ B, int ldb, long long bsB,
    void* __restrict__ Cv, int ldc, long long bsC,
    const float* __restrict__ D, long long ldd,
    int M, int N, int K)
{
  const float* Af = (const float*)Av + (ABF16 ? 0 : (size_t)blockIdx.z * bsA);
  const short* Ah = (const short*)Av + (ABF16 ? (size_t)blockIdx.z * bsA : 0);
  B += (size_t)blockIdx.z * bsB;
  const int m0 = blockIdx.y * 64, n0 = blockIdx.x * 64;
  const int tid = threadIdx.x;
  const int w = tid >> 6, lane = tid & 63;
  const int wr = w >> 1, wc = w & 1;
  __shared__ __attribute__((aligned(16))) short As[2][64][40];
  __shared__ __attribute__((aligned(16))) short Bs[2][64][40];
  f32x4 acc[2][2] = {};

  const int ar = tid >> 2, akc = (tid & 3) * 8;
  const int br = tid >> 3, bnc = (tid & 7) * 8;
  const bool arv = (m0 + ar < M);
  const int rbase = wr * 32 + (lane & 15);
  const int cbase = wc * 32 + (lane & 15);
  const int kb = (lane >> 4) * 8;

  auto gload = [&](int k0, float4& a0, float4& a1, bf16x8& ah,
                   float4& b0, float4& b1) {
    if (ABF16) {
      ah = bf16x8{};
      if (arv) ah = *(const bf16x8*)(Ah + (size_t)(m0 + ar) * lda + k0 + akc);
    } else {
      a0 = make_float4(0.f, 0.f, 0.f, 0.f); a1 = a0;
      if (arv) {
        a0 = *(const float4*)(Af + (size_t)(m0 + ar) * lda + k0 + akc);
        a1 = *(const float4*)(Af + (size_t)(m0 + ar) * lda + k0 + akc + 4);
      }
    }
    if (TRANSB) {
      b0 = *(const float4*)(B + (size_t)(n0 + ar) * ldb + k0 + akc);
      b1 = *(const float4*)(B + (size_t)(n0 + ar) * ldb + k0 + akc + 4);
    } else {
      b0 = *(const float4*)(B + (size_t)(k0 + br) * ldb + n0 + bnc);
      b1 = *(const float4*)(B + (size_t)(k0 + br) * ldb + n0 + bnc + 4);
    }
  };
  auto stage = [&](int buf, const float4& a0, const float4& a1, const bf16x8& ah,
                   const float4& b0, const float4& b1) {
    if (ABF16) {
      *(bf16x8*)&As[buf][ar][akc] = ah;
    } else {
      bf16x8 av;
      av[0] = f2bf(a0.x); av[1] = f2bf(a0.y); av[2] = f2bf(a0.z); av[3] = f2bf(a0.w);
      av[4] = f2bf(a1.x); av[5] = f2bf(a1.y); av[6] = f2bf(a1.z); av[7] = f2bf(a1.w);
      *(bf16x8*)&As[buf][ar][akc] = av;
    }
    if (TRANSB) {
      bf16x8 bv;
      bv[0] = f2bf(b0.x); bv[1] = f2bf(b0.y); bv[2] = f2bf(b0.z); bv[3] = f2bf(b0.w);
      bv[4] = f2bf(b1.x); bv[5] = f2bf(b1.y); bv[6] = f2bf(b1.z); bv[7] = f2bf(b1.w);
      *(bf16x8*)&Bs[buf][ar][akc] = bv;
    } else {
      Bs[buf][bnc + 0][br] = f2bf(b0.x); Bs[buf][bnc + 1][br] = f2bf(b0.y);
      Bs[buf][bnc + 2][br] = f2bf(b0.z); Bs[buf][bnc + 3][br] = f2bf(b0.w);
      Bs[buf][bnc + 4][br] = f2bf(b1.x); Bs[buf][bnc + 5][br] = f2bf(b1.y);
      Bs[buf][bnc + 6][br] = f2bf(b1.z); Bs[buf][bnc + 7][br] = f2bf(b1.w);
    }
  };
  auto compute = [&](int buf) {
    bf16x8 af0 = *(const bf16x8*)&As[buf][rbase][kb];
    bf16x8 af1 = *(const bf16x8*)&As[buf][rbase + 16][kb];
    bf16x8 bf0 = *(const bf16x8*)&Bs[buf][cbase][kb];
    bf16x8 bf1 = *(const bf16x8*)&Bs[buf][cbase + 16][kb];
    acc[0][0] = __builtin_amdgcn_mfma_f32_16x16x32_bf16(af0, bf0, acc[0][0], 0, 0, 0);
    acc[0][1] = __builtin_amdgcn_mfma_f32_16x16x32_bf16(af0, bf1, acc[0][1], 0, 0, 0);
    acc[1][0] = __builtin_amdgcn_mfma_f32_16x16x32_bf16(af1, bf0, acc[1][0], 0, 0, 0);
    acc[1][1] = __builtin_amdgcn_mfma_f32_16x16x32_bf16(af1, bf1, acc[1][1], 0, 0, 0);
  };

  float4 a0A, a1A, b0A, b1A, a0B, a1B, b0B, b1B;
  bf16x8 ahA = {}, ahB = {};
  gload(0, a0A, a1A, ahA, b0A, b1A);
  gload(32, a0B, a1B, ahB, b0B, b1B);
  for (int k0 = 0; k0 < K; k0 += 64) {
    stage(0, a0A, a1A, ahA, b0A, b1A);
    if (k0 + 64 < K) gload(k0 + 64, a0A, a1A, ahA, b0A, b1A);
    __syncthreads();
    compute(0);
    stage(1, a0B, a1B, ahB, b0B, b1B);
    if (k0 + 96 < K) gload(k0 + 96, a0B, a1B, ahB, b0B, b1B);
    __syncthreads();
    compute(1);
  }

  const size_t cb = (size_t)blockIdx.z * (size_t)bsC;
#pragma unroll
  for (int mi = 0; mi < 2; ++mi)
#pragma unroll
    for (int ni = 0; ni < 2; ++ni)
#pragma unroll
      for (int r = 0; r < 4; ++r) {
        const int row = m0 + wr * 32 + mi * 16 + (lane >> 4) * 4 + r;
        const int col = n0 + wc * 32 + ni * 16 + (lane & 15);
        if (row < M) {
          float v = acc[mi][ni][r];
          if (ADDD) v += D[(size_t)row * ldd + col];
          if (OUTBF16)
            ((__hip_bfloat16*)Cv)[cb + (size_t)row * ldc + col] = __float2bfloat16(v);
          else
            ((float*)Cv)[cb + (size_t)row * ldc + col] = v;
        }
      }
}

// ---------------------------------------------------------------------------
// bf16 MFMA GEMM with LayerNorm fused on A (unchanged from round 12).
// ---------------------------------------------------------------------------
__global__ __launch_bounds__(256) void gemm_mfma_lnA_k(
    const float* __restrict__ A, long long lda,
    const float* __restrict__ g, const float* __restrict__ b,
    const float* __restrict__ B, int ldb,
    float* __restrict__ C, int ldc,
    int M, int N, int K)
{
  const int m0 = blockIdx.y * 64, n0 = blockIdx.x * 64;
  const int tid = threadIdx.x;
  const int w = tid >> 6, lane = tid & 63;
  const int wr = w >> 1, wc = w & 1;
  __shared__ __attribute__((aligned(16))) short As[2][64][40];
  __shared__ __attribute__((aligned(16))) short Bs[2][64][40];
  __shared__ __attribute__((aligned(16))) float g_s[512], b_s[512];
  __shared__ float mean_s[64], rstd_s[64];
  f32x4 acc[2][2] = {};

  if (tid < 128) ((float4*)g_s)[tid] = ((const float4*)g)[tid];
  else ((float4*)b_s)[tid - 128] = ((const float4*)b)[tid - 128];

  {
    const int r = tid >> 2, p = tid & 3;
    float s = 0.f, ss = 0.f;
    if (m0 + r < M) {
      const float4* src = (const float4*)(A + (size_t)(m0 + r) * lda + p * 128);
#pragma unroll 8
      for (int i = 0; i < 32; ++i) {
        const float4 v = src[i];
        s += v.x + v.y + v.z + v.w;
        ss += v.x * v.x + v.y * v.y + v.z * v.z + v.w * v.w;
      }
    }
    s += __shfl_xor(s, 1);  s += __shfl_xor(s, 2);
    ss += __shfl_xor(ss, 1); ss += __shfl_xor(ss, 2);
    if (p == 0) {
      const float mean = s * (1.f / 512.f);
      mean_s[r] = mean;
      rstd_s[r] = rsqrtf(ss * (1.f / 512.f) - mean * mean + 1e-5f);
    }
  }
  __syncthreads();

  const int ar = tid >> 2, akc = (tid & 3) * 8;
  const int br = tid >> 3, bnc = (tid & 7) * 8;
  const bool arv = (m0 + ar < M);
  const int rbase = wr * 32 + (lane & 15);
  const int cbase = wc * 32 + (lane & 15);
  const int kb = (lane >> 4) * 8;

  auto gload = [&](int k0, float4& a0, float4& a1, float4& b0, float4& b1) {
    a0 = make_float4(0.f, 0.f, 0.f, 0.f); a1 = a0;
    if (arv) {
      a0 = *(const float4*)(A + (size_t)(m0 + ar) * lda + k0 + akc);
      a1 = *(const float4*)(A + (size_t)(m0 + ar) * lda + k0 + akc + 4);
    }
    b0 = *(const float4*)(B + (size_t)(k0 + br) * ldb + n0 + bnc);
    b1 = *(const float4*)(B + (size_t)(k0 + br) * ldb + n0 + bnc + 4);
  };
  auto stage = [&](int buf, int k0, const float4& a0, const float4& a1,
                   const float4& b0, const float4& b1) {
    const float mn = mean_s[ar], rs = rstd_s[ar];
    const int kc = k0 + akc;
    bf16x8 av;
    av[0] = f2bf((a0.x - mn) * rs * g_s[kc + 0] + b_s[kc + 0]);
    av[1] = f2bf((a0.y - mn) * rs * g_s[kc + 1] + b_s[kc + 1]);
    av[2] = f2bf((a0.z - mn) * rs * g_s[kc + 2] + b_s[kc + 2]);
    av[3] = f2bf((a0.w - mn) * rs * g_s[kc + 3] + b_s[kc + 3]);
    av[4] = f2bf((a1.x - mn) * rs * g_s[kc + 4] + b_s[kc + 4]);
    av[5] = f2bf((a1.y - mn) * rs * g_s[kc + 5] + b_s[kc + 5]);
    av[6] = f2bf((a1.z - mn) * rs * g_s[kc + 6] + b_s[kc + 6]);
    av[7] = f2bf((a1.w - mn) * rs * g_s[kc + 7] + b_s[kc + 7]);
    *(bf16x8*)&As[buf][ar][akc] = av;
    Bs[buf][bnc + 0][br] = f2bf(b0.x); Bs[buf][bnc + 1][br] = f2bf(b0.y);
    Bs[buf][bnc + 2][br] = f2bf(b0.z); Bs[buf][bnc + 3][br] = f2bf(b0.w);
    Bs[buf][bnc + 4][br] = f2bf(b1.x); Bs[buf][bnc + 5][br] = f2bf(b1.y);
    Bs[buf][bnc + 6][br] = f2bf(b1.z); Bs[buf][bnc + 7][br] = f2bf(b1.w);
  };
  auto compute = [&](int buf) {
    bf16x8 af0 = *(const bf16x8*)&As[buf][rbase][kb];
    bf16x8 af1 = *(const bf16x8*)&As[buf][rbase + 16][kb];
    bf16x8 bf0 = *(const bf16x8*)&Bs[buf][cbase][kb];
    bf16x8 bf1 = *(const bf16x8*)&Bs[buf][cbase + 16][kb];
    acc[0][0] = __builtin_amdgcn_mfma_f32_16x16x32_bf16(af0, bf0, acc[0][0], 0, 0, 0);
    acc[0][1] = __builtin_amdgcn_mfma_f32_16x16x32_bf16(af0, bf1, acc[0][1], 0, 0, 0);
    acc[1][0] = __builtin_amdgcn_mfma_f32_16x16x32_bf16(af1, bf0, acc[1][0], 0, 0, 0);
    acc[1][1] = __builtin_amdgcn_mfma_f32_16x16x32_bf16(af1, bf1, acc[1][1], 0, 0, 0);
  };

  float4 a0A, a1A, b0A, b1A, a0B, a1B, b0B, b1B;
  gload(0, a0A, a1A, b0A, b1A);
  gload(32, a0B, a1B, b0B, b1B);
  for (int k0 = 0; k0 < K; k0 += 64) {
    stage(0, k0, a0A, a1A, b0A, b1A);
    if (k0 + 64 < K) gload(k0 + 64, a0A, a1A, b0A, b1A);
    __syncthreads();
    compute(0);
    stage(1, k0 + 32, a0B, a1B, b0B, b1B);
    if (k0 + 96 < K) gload(k0 + 96, a0B, a1B, b0B, b1B);
    __syncthreads();
    compute(1);
  }

#pragma unroll
  for (int mi = 0; mi < 2; ++mi)
#pragma unroll
    for (int ni = 0; ni < 2; ++ni)
#pragma unroll
      for (int r = 0; r < 4; ++r) {
        const int row = m0 + wr * 32 + mi * 16 + (lane >> 4) * 4 + r;
        const int col = n0 + wc * 32 + ni * 16 + (lane & 15);
        if (row < M) C[(size_t)row * ldc + col] = acc[mi][ni][r];
      }
}

// ---------------------------------------------------------------------------
// Logits GEMM with fused L2 norms (unchanged).
// ---------------------------------------------------------------------------
__global__ __launch_bounds__(256) void logits_k(
    const float* __restrict__ A, int lda,
    const float* __restrict__ B, int ldb,
    float* __restrict__ C, int ldc,
    const float* __restrict__ alpha_ptr,
    int M, int N, int K)
{
  const int m0 = blockIdx.y * 32, n0 = blockIdx.x * 64;
  const int tid = threadIdx.x;
  __shared__ __attribute__((aligned(16))) float As[2][16][36];
  __shared__ __attribute__((aligned(16))) float Bs[2][16][68];
  __shared__ float nA[32], nB[64];
  float acc[2][4] = {};
  float ssA = 0.f, ssB = 0.f;
  const int ty = tid >> 4, tx = tid & 15;
  const int am = tid >> 3, ak = (tid & 7) * 2;
  const int bm = tid >> 2, bt = (tid & 3) * 4;
  const bool aval = (m0 + am < M);
  const bool bval = (n0 + bm < N);

  float2 av; float4 bv;
  auto gload = [&](int k0) {
    av = make_float2(0.f, 0.f);
    bv = make_float4(0.f, 0.f, 0.f, 0.f);
    if (aval) av = *(const float2*)(A + (size_t)(m0 + am) * lda + (k0 + ak));
    if (bval) bv = *(const float4*)(B + (size_t)(n0 + bm) * ldb + (k0 + bt));
    ssA += av.x * av.x + av.y * av.y;
    ssB += bv.x * bv.x + bv.y * bv.y + bv.z * bv.z + bv.w * bv.w;
  };
  auto sstore = [&](int buf) {
    As[buf][ak][am] = av.x; As[buf][ak + 1][am] = av.y;
    Bs[buf][bt + 0][bm] = bv.x; Bs[buf][bt + 1][bm] = bv.y;
    Bs[buf][bt + 2][bm] = bv.z; Bs[buf][bt + 3][bm] = bv.w;
  };

  const int nIt = K >> 4;
  gload(0); sstore(0);
  for (int it = 0; it < nIt; ++it) {
    __syncthreads();
    if (it + 1 < nIt) gload((it + 1) << 4);
    const int buf = it & 1;
#pragma unroll
    for (int kk = 0; kk < 16; ++kk) {
      const float2 a  = *(const float2*)&As[buf][kk][ty * 2];
      const float4 bq = *(const float4*)&Bs[buf][kk][tx * 4];
      acc[0][0] += a.x * bq.x; acc[0][1] += a.x * bq.y; acc[0][2] += a.x * bq.z; acc[0][3] += a.x * bq.w;
      acc[1][0] += a.y * bq.x; acc[1][1] += a.y * bq.y; acc[1][2] += a.y * bq.z; acc[1][3] += a.y * bq.w;
    }
    if (it + 1 < nIt) sstore((it + 1) & 1);
  }

  ssA += __shfl_xor(ssA, 1); ssA += __shfl_xor(ssA, 2); ssA += __shfl_xor(ssA, 4);
  if ((tid & 7) == 0) nA[am] = rsqrtf(ssA);
  ssB += __shfl_xor(ssB, 1); ssB += __shfl_xor(ssB, 2);
  if ((tid & 3) == 0) nB[bm] = rsqrtf(ssB);
  __syncthreads();

  const float alpha = __expf(alpha_ptr[0]);
#pragma unroll
  for (int i = 0; i < 2; ++i) {
    const int m = m0 + ty * 2 + i;
    if (m >= M) continue;
    const float fa = alpha * nA[ty * 2 + i];
#pragma unroll
    for (int j = 0; j < 4; ++j) {
      const int nn = n0 + tx * 4 + j;
      if (nn < N) C[(size_t)m * ldc + nn] = acc[i][j] * fa * nB[tx * 4 + j];
    }
  }
}

// ---------------------------------------------------------------------------
// FUSED sweep v8: v7 with sums/dots/accumulate rewritten as f32x2 ext-vector
// math -> compiler selects v_pk_fma_f32 (dual f32/instr), cutting ~25% of
// the per-pair instruction count. Reduction order change is lane-pair-local.
// ---------------------------------------------------------------------------
__global__ __launch_bounds__(256) void fused_sweep_kernel(
    const float* __restrict__ ctx, const float* __restrict__ cls,
    const float* __restrict__ g, const float* __restrict__ b,
    const __hip_bfloat16* __restrict__ wt, __hip_bfloat16* __restrict__ u_out)
{
  const int n = blockIdx.x, tid = threadIdx.x;
  const int w = tid >> 6, lane = tid & 63;
  __shared__ __attribute__((aligned(16))) float gw_s[8][512];
  __shared__ __attribute__((aligned(16))) float g_s[512], b_s[512];
  __shared__ __attribute__((aligned(16))) short h2_s[5][512];   // bf16 h2
  __shared__ float sc_s[8][80];
  __shared__ float sc2_s[8][5];
  __shared__ float ah_s[8][5];
  __shared__ float wstatB[4][8], wstatL[4][8];
  __shared__ float attr_s[5];
  __shared__ float Sgw_l[8], bw_l[8];
  __shared__ float Bt_s[8], Lt_s[8], inv_s[8];
  __shared__ float e2_s[8][5];
  __shared__ __attribute__((aligned(16))) float es_s[4][2][8];

  {
    const uint4* wsrc = (const uint4*)(wt + (size_t)n * 4096);
    float4* gwf = (float4*)&gw_s[0][0];
    for (int i = tid; i < 512; i += 256) {
      const uint4 v = wsrc[i];
      gwf[i * 2]     = make_float4(bf2f(v.x & 0xffffu), bf2f(v.x >> 16),
                                   bf2f(v.y & 0xffffu), bf2f(v.y >> 16));
      gwf[i * 2 + 1] = make_float4(bf2f(v.z & 0xffffu), bf2f(v.z >> 16),
                                   bf2f(v.w & 0xffffu), bf2f(v.w >> 16));
    }
    if (tid < 128) ((float4*)g_s)[tid] = ((const float4*)g)[tid];
    else ((float4*)b_s)[tid - 128] = ((const float4*)b)[tid - 128];
  }
  __syncthreads();

  for (int hh = w; hh < 8; hh += 4) {
    float s1 = 0.f, s2 = 0.f;
#pragma unroll
    for (int i = 0; i < 8; ++i) {
      const int j = lane + 64 * i;
      const float wv = gw_s[hh][j];
      const float gv = wv * g_s[j];
      s1 += gv; s2 += wv * b_s[j];
      gw_s[hh][j] = gv;
    }
    s1 = wsum(s1); s2 = wsum(s2);
    if (lane == 0) { Sgw_l[hh] = s1; bw_l[hh] = s2; }
  }
  __syncthreads();
  const float sg_r  = Sgw_l[lane & 7];
  const float bw8_r = bw_l[lane & 7] * 0.125f;
  const int j0 = lane * 4, j1 = lane * 4 + 256;

  // ---- stage A: 5 unscaled ctx rows (global reads) -> pass-1 scores
  for (int k = w; k < 5; k += 4) {
    const float* src = ctx + ((size_t)n * 5 + k) * 512;
    const float4 x0 = *(const float4*)(src + j0);
    const float4 x1 = *(const float4*)(src + j1);
    f32x2 q[4];
    split4(x0, q[0], q[1]); split4(x1, q[2], q[3]);
    f32x2 s2v = q[0] + q[1] + q[2] + q[3];
    f32x2 ss2 = q[0] * q[0] + q[1] * q[1] + q[2] * q[2] + q[3] * q[3];
    float s  = s2v[0] + s2v[1];
    float ss = ss2[0] + ss2[1];
    float v8[8];
#pragma unroll
    for (int hh = 0; hh < 8; ++hh) {
      const float4 w0 = *(const float4*)&gw_s[hh][j0];
      const float4 w1 = *(const float4*)&gw_s[hh][j1];
      f32x2 g0, g1, g2, g3;
      split4(w0, g0, g1); split4(w1, g2, g3);
      f32x2 d = q[0] * g0 + q[1] * g1 + q[2] * g2 + q[3] * g3;
      v8[hh] = d[0] + d[1];
    }
    s = wsum(s); ss = wsum(ss);
    const float mean = s * (1.f / 512.f);
    const float rstd = rsqrtf(ss * (1.f / 512.f) - mean * mean + 1e-5f);
    const float z = fold8(v8, lane);
    const float zf = rstd * 0.125f * (z - mean * sg_r) + bw8_r;
    if (lane < 8) sc_s[lane][k] = zf;
  }

  // ---- stage B: 72 cls rows, 9 pairs/wave, prefetch depth 2, f32x2 math
  f32x2 A2[8][4];
#pragma unroll
  for (int hh = 0; hh < 8; ++hh)
#pragma unroll
    for (int i = 0; i < 4; ++i) A2[hh][i] = f32x2{0.f, 0.f};
  float B8[8] = {}, L8[8] = {};

  const float* base = cls + (size_t)n * 72 * 512;
  float4 xa0, xa1, xb0, xb1, ya0, ya1, yb0, yb1;
  {
    const float* sA = base + (size_t)w * 512;
    const float* sB = base + (size_t)(w + 4) * 512;
    xa0 = *(const float4*)(sA + j0); xa1 = *(const float4*)(sA + j1);
    xb0 = *(const float4*)(sB + j0); xb1 = *(const float4*)(sB + j1);
    const float* sA1 = base + (size_t)(w + 8) * 512;
    const float* sB1 = base + (size_t)(w + 12) * 512;
    ya0 = *(const float4*)(sA1 + j0); ya1 = *(const float4*)(sA1 + j1);
    yb0 = *(const float4*)(sB1 + j0); yb1 = *(const float4*)(sB1 + j1);
  }
  for (int p = 0; p < 9; ++p) {
    float4 za0, za1, zb0, zb1;
    const bool more2 = (p + 2 < 9);
    if (more2) {
      const float* sA = base + (size_t)(w + 8 * (p + 2)) * 512;
      const float* sB = base + (size_t)(w + 4 + 8 * (p + 2)) * 512;
      za0 = *(const float4*)(sA + j0); za1 = *(const float4*)(sA + j1);
      zb0 = *(const float4*)(sB + j0); zb1 = *(const float4*)(sB + j1);
    }
    f32x2 qa[4], qb[4];
    split4(xa0, qa[0], qa[1]); split4(xa1, qa[2], qa[3]);
    split4(xb0, qb[0], qb[1]); split4(xb1, qb[2], qb[3]);
    f32x2 sa2 = qa[0] + qa[1] + qa[2] + qa[3];
    f32x2 ssa2 = qa[0] * qa[0] + qa[1] * qa[1] + qa[2] * qa[2] + qa[3] * qa[3];
    f32x2 sb2 = qb[0] + qb[1] + qb[2] + qb[3];
    f32x2 ssb2 = qb[0] * qb[0] + qb[1] * qb[1] + qb[2] * qb[2] + qb[3] * qb[3];
    float sa = sa2[0] + sa2[1], ssa = ssa2[0] + ssa2[1];
    float sb = sb2[0] + sb2[1], ssb = ssb2[0] + ssb2[1];
    float v8a[8], v8b[8];
#pragma unroll
    for (int hh = 0; hh < 8; ++hh) {
      const float4 w0 = *(const float4*)&gw_s[hh][j0];
      const float4 w1 = *(const float4*)&gw_s[hh][j1];
      f32x2 g0, g1, g2, g3;
      split4(w0, g0, g1); split4(w1, g2, g3);
      f32x2 da = qa[0] * g0 + qa[1] * g1 + qa[2] * g2 + qa[3] * g3;
      f32x2 db = qb[0] * g0 + qb[1] * g1 + qb[2] * g2 + qb[3] * g3;
      v8a[hh] = da[0] + da[1];
      v8b[hh] = db[0] + db[1];
    }
    sa = wsum(sa); ssa = wsum(ssa); sb = wsum(sb); ssb = wsum(ssb);
    const float meanA = sa * (1.f / 512.f);
    const float rstdA = rsqrtf(ssa * (1.f / 512.f) - meanA * meanA + 1e-5f);
    const float meanB = sb * (1.f / 512.f);
    const float rstdB = rsqrtf(ssb * (1.f / 512.f) - meanB * meanB + 1e-5f);
    const float za = fold8(v8a, lane);
    const float zb = fold8(v8b, lane);
    const float zfa = rstdA * 0.125f * (za - meanA * sg_r) + bw8_r;
    const float zfb = rstdB * 0.125f * (zb - meanB * sg_r) + bw8_r;
    const int kA = 5 + w + 8 * p;
    if (lane < 8) {
      sc_s[lane][kA] = zfa; sc_s[lane][kA + 4] = zfb;
      es_s[w][0][lane] = __expf(zfa);
      es_s[w][1][lane] = __expf(zfb);
    }
    __builtin_amdgcn_wave_barrier();
    const float4 ea0 = *(const float4*)&es_s[w][0][0];
    const float4 ea1 = *(const float4*)&es_s[w][0][4];
    const float4 eb0 = *(const float4*)&es_s[w][1][0];
    const float4 eb1 = *(const float4*)&es_s[w][1][4];
    const float esa[8] = {ea0.x, ea0.y, ea0.z, ea0.w, ea1.x, ea1.y, ea1.z, ea1.w};
    const float esb[8] = {eb0.x, eb0.y, eb0.z, eb0.w, eb1.x, eb1.y, eb1.z, eb1.w};
#pragma unroll
    for (int hh = 0; hh < 8; ++hh) {
      const float erA = esa[hh] * rstdA;
      const float erB = esb[hh] * rstdB;
      const f32x2 eA = f32x2{erA, erA};
      const f32x2 eB = f32x2{erB, erB};
      A2[hh][0] += eA * qa[0]; A2[hh][1] += eA * qa[1];
      A2[hh][2] += eA * qa[2]; A2[hh][3] += eA * qa[3];
      A2[hh][0] += eB * qb[0]; A2[hh][1] += eB * qb[1];
      A2[hh][2] += eB * qb[2]; A2[hh][3] += eB * qb[3];
      B8[hh] += erA * meanA + erB * meanB;
      L8[hh] += esa[hh] + esb[hh];
    }
    xa0 = ya0; xa1 = ya1; xb0 = yb0; xb1 = yb1;
    if (more2) { ya0 = za0; ya1 = za1; yb0 = zb0; yb1 = zb1; }
  }
  if (lane == 0)
#pragma unroll
    for (int hh = 0; hh < 8; ++hh) {
      wstatB[w][hh] = B8[hh]; wstatL[w][hh] = L8[hh];
    }
  __syncthreads();

  // ---- pass-1 softmax over 77 -> head-mean of first 5 -> attr
  for (int hh = w; hh < 8; hh += 4) {
    const float v0 = sc_s[hh][lane];
    const float v1 = (lane + 64 < 77) ? sc_s[hh][lane + 64] : -1e30f;
    const float mx = wmaxr(fmaxf(v0, v1));
    const float e0 = __expf(v0 - mx);
    const float e1 = (lane + 64 < 77) ? __expf(v1 - mx) : 0.f;
    const float S = wsum(e0 + e1);
    if (lane < 5) ah_s[hh][lane] = e0 / S;
  }
  __syncthreads();
  if (tid == 0) {
    float m[5], mx = -1e30f;
#pragma unroll
    for (int p = 0; p < 5; ++p) {
      float acc = 0.f;
      for (int hh = 0; hh < 8; ++hh) acc += ah_s[hh][p];
      m[p] = acc * 0.125f;
      mx = fmaxf(mx, m[p]);
    }
    float e[5], S = 0.f;
#pragma unroll
    for (int p = 0; p < 5; ++p) { e[p] = __expf(m[p] - mx); S += e[p]; }
#pragma unroll
    for (int p = 0; p < 5; ++p) attr_s[p] = e[p] / S;
  }
  __syncthreads();

  // ---- stage C: scaled ctx rows (global reads) -> h2 (bf16 LDS) + sc2
  for (int k = w; k < 5; k += 4) {
    const float c = attr_s[k];
    const float* src = ctx + ((size_t)n * 5 + k) * 512;
    float4 x0 = *(const float4*)(src + j0);
    float4 x1 = *(const float4*)(src + j1);
    x0.x *= c; x0.y *= c; x0.z *= c; x0.w *= c;
    x1.x *= c; x1.y *= c; x1.z *= c; x1.w *= c;
    f32x2 q[4];
    split4(x0, q[0], q[1]); split4(x1, q[2], q[3]);
    f32x2 s2v = q[0] + q[1] + q[2] + q[3];
    f32x2 ss2 = q[0] * q[0] + q[1] * q[1] + q[2] * q[2] + q[3] * q[3];
    float s  = s2v[0] + s2v[1];
    float ss = ss2[0] + ss2[1];
    float v8[8];
#pragma unroll
    for (int hh = 0; hh < 8; ++hh) {
      const float4 w0 = *(const float4*)&gw_s[hh][j0];
      const float4 w1 = *(const float4*)&gw_s[hh][j1];
      f32x2 g0, g1, g2, g3;
      split4(w0, g0, g1); split4(w1, g2, g3);
      f32x2 d = q[0] * g0 + q[1] * g1 + q[2] * g2 + q[3] * g3;
      v8[hh] = d[0] + d[1];
    }
    s = wsum(s); ss = wsum(ss);
    const float mean = s * (1.f / 512.f);
    const float rstd = rsqrtf(ss * (1.f / 512.f) - mean * mean + 1e-5f);
    {
      const float4 gg0 = *(const float4*)&g_s[j0];
      const float4 bb0 = *(const float4*)&b_s[j0];
      const float4 gg1 = *(const float4*)&g_s[j1];
      const float4 bb1 = *(const float4*)&b_s[j1];
      s16x4 o0, o1;
      o0[0] = f2bf((x0.x - mean) * rstd * gg0.x + bb0.x);
      o0[1] = f2bf((x0.y - mean) * rstd * gg0.y + bb0.y);
      o0[2] = f2bf((x0.z - mean) * rstd * gg0.z + bb0.z);
      o0[3] = f2bf((x0.w - mean) * rstd * gg0.w + bb0.w);
      o1[0] = f2bf((x1.x - mean) * rstd * gg1.x + bb1.x);
      o1[1] = f2bf((x1.y - mean) * rstd * gg1.y + bb1.y);
      o1[2] = f2bf((x1.z - mean) * rstd * gg1.z + bb1.z);
      o1[3] = f2bf((x1.w - mean) * rstd * gg1.w + bb1.w);
      *(s16x4*)&h2_s[k][j0] = o0;
      *(s16x4*)&h2_s[k][j1] = o1;
    }
    const float z = fold8(v8, lane);
    const float zf = rstd * 0.125f * (z - mean * sg_r) + bw8_r;
    if (lane < 8) sc2_s[lane][k] = zf;
  }
  __syncthreads();

  // ---- cross-wave A combine into gw_s region (float4)
  for (int wv = 0; wv < 4; ++wv) {
    if (w == wv) {
#pragma unroll
      for (int hh = 0; hh < 8; ++hh) {
        float4* p0 = (float4*)&gw_s[hh][j0];
        float4* p1 = (float4*)&gw_s[hh][j1];
        const float4 a0 = make_float4(A2[hh][0][0], A2[hh][0][1],
                                      A2[hh][1][0], A2[hh][1][1]);
        const float4 a1 = make_float4(A2[hh][2][0], A2[hh][2][1],
                                      A2[hh][3][0], A2[hh][3][1]);
        if (wv == 0) { *p0 = a0; *p1 = a1; }
        else {
          float4 v0 = *p0, v1 = *p1;
          v0.x += a0.x; v0.y += a0.y; v0.z += a0.z; v0.w += a0.w;
          v1.x += a1.x; v1.y += a1.y; v1.z += a1.z; v1.w += a1.w;
          *p0 = v0; *p1 = v1;
        }
      }
    }
    __syncthreads();
  }

  if (tid < 8) {
    float Bt = 0.f, Lt = 0.f;
    for (int wv = 0; wv < 4; ++wv) { Bt += wstatB[wv][tid]; Lt += wstatL[wv][tid]; }
    float den = Lt;
#pragma unroll
    for (int k = 0; k < 5; ++k) {
      const float e = __expf(sc2_s[tid][k]);
      e2_s[tid][k] = e; den += e;
    }
    Bt_s[tid] = Bt; Lt_s[tid] = Lt; inv_s[tid] = 1.f / den;
  }
  __syncthreads();

  // ---- u[hh][j] (bf16) = ((g*(A-B) + b*L + sum_k e2*h2) / den)
  __hip_bfloat16* dst = u_out + (size_t)n * 4096;
  for (int bidx = tid * 4; bidx < 4096; bidx += 1024) {
    const int hh = bidx >> 9, j = bidx & 511;
    const float4 a4 = *(const float4*)&gw_s[hh][j];
    const float4 g4 = *(const float4*)&g_s[j];
    const float4 b4 = *(const float4*)&b_s[j];
    const float Bt = Bt_s[hh], Lt = Lt_s[hh];
    float v0 = (a4.x - Bt) * g4.x + Lt * b4.x;
    float v1 = (a4.y - Bt) * g4.y + Lt * b4.y;
    float v2 = (a4.z - Bt) * g4.z + Lt * b4.z;
    float v3 = (a4.w - Bt) * g4.w + Lt * b4.w;
#pragma unroll
    for (int k = 0; k < 5; ++k) {
      const s16x4 hq = *(const s16x4*)&h2_s[k][j];
      const float e = e2_s[hh][k];
      v0 += e * bfs2f(hq[0]); v1 += e * bfs2f(hq[1]);
      v2 += e * bfs2f(hq[2]); v3 += e * bfs2f(hq[3]);
    }
    const float iv = inv_s[hh];
    s16x4 o;
    o[0] = f2bf(v0 * iv); o[1] = f2bf(v1 * iv);
    o[2] = f2bf(v2 * iv); o[3] = f2bf(v3 * iv);
    *(s16x4*)&dst[bidx] = o;
  }
}

// ---------------------------------------------------------------------------
extern "C" void kernel_launch(void* const* d_in, const int* in_sizes, int n_in,
                              void* d_out, int out_size, void* d_ws, size_t ws_size,
                              hipStream_t stream)
{
  const float* images = (const float*)d_in[0];
  const float* W_img  = (const float*)d_in[1];
  const float* ctx    = (const float*)d_in[2];
  const float* cls    = (const float*)d_in[3];
  const float* ln_g   = (const float*)d_in[4];
  const float* ln_b   = (const float*)d_in[5];
  const float* Wq     = (const float*)d_in[6];
  const float* Wk     = (const float*)d_in[7];
  const float* Wv     = (const float*)d_in[8];
  const float* Wo     = (const float*)d_in[9];
  const float* tproj  = (const float*)d_in[10];
  const float* lscale = (const float*)d_in[11];

  __hip_bfloat16* wtu = (__hip_bfloat16*)d_ws;  // wt -> u (bf16, in place)
  float* fws  = (float*)d_ws;
  float* img  = fws + 2048000;
  float* hlO  = img + 131072;       // O
  float* qo2  = hlO + 512000;       // q -> out2
  float* txt  = fws;                // alias over dead u region
  (void)in_sizes; (void)n_in; (void)out_size; (void)ws_size;

  // 1) image embedding (bf16 MFMA), unnormalized (logits_k normalizes)
  gemm_mfma_k<0,0,0,0><<<dim3(8,4,1),256,0,stream>>>(images,768,0, W_img,512,0,
      img,512,0, nullptr,0, 256,512,768);

  // 2) q = LN(cls_last) @ Wq  (LN fused into staging)
  gemm_mfma_lnA_k<<<dim3(8,16),256,0,stream>>>(cls + 71*512, 72*512,
      ln_g, ln_b, Wq,512, qo2,512, 1000,512,512);

  // 3) wt = per-head q @ Wk^T  -> bf16
  gemm_mfma_k<1,0,0,1><<<dim3(8,16,8),256,0,stream>>>(qo2,512,64, Wk,512,64,
      wtu,4096,512, nullptr,0, 1000,512,64);

  // 4+5) fused pass1+pass2 sweep -> u bf16 (in place over wt)
  fused_sweep_kernel<<<1000,256,0,stream>>>(ctx, cls, ln_g, ln_b, wtu, wtu);

  // 6) O = per-head u @ Wv  (A read directly as bf16)
  gemm_mfma_k<0,0,1,0><<<dim3(1,16,8),256,0,stream>>>(wtu,4096,512, Wv,512,64,
      hlO,512,64, nullptr,0, 1000,64,512);

  // 7) out2 = cls_last + O @ Wo ; txt = out2 @ text_proj  (bf16 MFMA)
  gemm_mfma_k<0,1,0,0><<<dim3(8,16,1),256,0,stream>>>(hlO,512,0, Wo,512,0,
      qo2,512,0, cls + 71*512, 72*512, 1000,512,512);
  gemm_mfma_k<0,0,0,0><<<dim3(8,16,1),256,0,stream>>>(qo2,512,0, tproj,512,0,
      txt,512,0, nullptr,0, 1000,512,512);

  // 8) logits = exp(ls) * (img/|img|) @ (txt/|txt|)^T  (norms fused, f32)
  logits_k<<<dim3(16,8),256,0,stream>>>(img,512, txt,512,
      (float*)d_out,1000, lscale, 256,1000,512);
}